// Round 14
// baseline (379.674 us; speedup 1.0000x reference)
//
#include <hip/hip_runtime.h>
#include <hip/hip_bf16.h>
#include <stdint.h>
#include <stddef.h>

#define BB 2
#define NN 384
#define DD 768
#define HH 256
#define SS 64
#define NHH 8
#define DHH 96

typedef __attribute__((ext_vector_type(8))) short bf16x8;
typedef __attribute__((ext_vector_type(4))) float f32x4;

__device__ __forceinline__ float bits_f(unsigned short u){
  unsigned x = ((unsigned)u) << 16; float f; __builtin_memcpy(&f, &x, 4); return f;
}
__device__ __forceinline__ unsigned short f_bits(float a){
  unsigned x; __builtin_memcpy(&x, &a, 4);
  unsigned r = x + 0x7fffu + ((x >> 16) & 1u);
  return (unsigned short)(r >> 16);
}
__device__ __forceinline__ float lo_f(unsigned u){ unsigned x = u << 16; float f; __builtin_memcpy(&f,&x,4); return f; }
__device__ __forceinline__ float hi_f(unsigned u){ unsigned x = u & 0xffff0000u; float f; __builtin_memcpy(&f,&x,4); return f; }
// hardware RTNE pack: lo=bf16(a), hi=bf16(b) — same rounding as f_bits
__device__ __forceinline__ unsigned cvt_pk_bf16(float a, float b){
  unsigned r; asm("v_cvt_pk_bf16_f32 %0, %1, %2" : "=v"(r) : "v"(a), "v"(b));
  return r;
}

// Fragment layout helper: element (n,k), K-tiles per n-tile row = ktiles (= K/32).
// frag f = (n>>4)*ktiles + (k>>5); lane = ((k>>3)&3)*16 + (n&15); elem = k&7.
// short index = f*512 + lane*8 + elem. Consumers load frag*512 + (hw lane)*8 → 1KB burst.

// ================= prep: weights -> bf16 fragment layouts (LDS-tiled) =================
__global__ __launch_bounds__(256) void k_prep(
    const float* __restrict__ w2, const float* __restrict__ w1g,
    const float* __restrict__ wq, const float* __restrict__ wk,
    const float* __restrict__ wv, const float* __restrict__ wo,
    const float* __restrict__ aw1, const float* __restrict__ aw2,
    short* __restrict__ w2T, short* __restrict__ w2r,
    short* __restrict__ wqT, short* __restrict__ wkT, short* __restrict__ wvT,
    short* __restrict__ woT, short* __restrict__ w1t,
    short* __restrict__ agw1T, short* __restrict__ agw2T)
{
  __shared__ short tile[64*66];
  const int tid = threadIdx.x, blk = blockIdx.x;
  if (blk < 48){               // w2 [256,768] -> w2T [768,256] (row-major, k_geofin use)
    int t = blk;
    int r0 = (t/12)*64, c0 = (t%12)*64;
    int g = tid >> 6, c = tid & 63;
    #pragma unroll
    for (int i=0;i<16;++i){
      int r = i*4 + g;
      tile[r*66 + c] = (short)f_bits(w2[(size_t)(r0+r)*768 + c0 + c]);
    }
    __syncthreads();
    #pragma unroll
    for (int i=0;i<16;++i){
      int cc = i*4 + g, rr = c;
      w2T[(size_t)(c0+cc)*256 + r0 + rr] = tile[rr*66 + cc];
    }
    return;
  }
  if (blk < 816){              // w2r: row-major bf16 copy
    int idx = (blk-48)*256 + tid;
    w2r[idx] = (short)f_bits(w2[idx]);
    return;
  }
  if (blk < 1392){             // attn weights [768k,768n] -> fragment layout (ktiles=24)
    int t = blk - 816;
    int mat = t / 144, tt = t % 144;
    const float* W = (mat==0)?wq:(mat==1)?wk:(mat==2)?wv:wo;
    short* T = (mat==0)?wqT:(mat==1)?wkT:(mat==2)?wvT:woT;
    int r0 = (tt/12)*64, c0 = (tt%12)*64;   // r0 = k base, c0 = n base
    int g = tid >> 6, c = tid & 63;
    #pragma unroll
    for (int i=0;i<16;++i){
      int r = i*4 + g;
      tile[r*66 + c] = (short)f_bits(W[(size_t)(r0+r)*768 + c0 + c]);
    }
    __syncthreads();
    #pragma unroll
    for (int i=0;i<16;++i){
      int cc = i*4 + g, rr = c;
      int n = c0 + cc, k = r0 + rr;
      int f = (n>>4)*24 + (k>>5);
      int ln = ((k>>3)&3)*16 + (n&15);
      T[(size_t)f*512 + ln*8 + (k&7)] = tile[rr*66 + cc];
    }
    return;
  }
  if (blk < 1424){             // w1t [256c][32k], K padded
    int idx = (blk-1392)*256 + tid;
    int c = idx >> 5, kk = idx & 31;
    w1t[idx] = (kk < 9) ? (short)f_bits(w1g[kk*256 + c]) : (short)0;
    return;
  }
  if (blk < 1472){             // ag_w1 [768k,256n] -> fragment layout (ktiles=24)
    int t = blk - 1424;
    int r0 = (t/4)*64, c0 = (t%4)*64;       // r0 = k base (768), c0 = n base (256)
    int g = tid >> 6, c = tid & 63;
    #pragma unroll
    for (int i=0;i<16;++i){
      int r = i*4 + g;
      tile[r*66 + c] = (short)f_bits(aw1[(size_t)(r0+r)*256 + c0 + c]);
    }
    __syncthreads();
    #pragma unroll
    for (int i=0;i<16;++i){
      int cc = i*4 + g, rr = c;
      int n = c0 + cc, k = r0 + rr;
      int f = (n>>4)*24 + (k>>5);
      int ln = ((k>>3)&3)*16 + (n&15);
      agw1T[(size_t)f*512 + ln*8 + (k&7)] = tile[rr*66 + cc];
    }
    return;
  }
  {                            // ag_w2 [256k,768n] -> fragment layout (ktiles=8)
    int t = blk - 1472;
    int r0 = (t/12)*64, c0 = (t%12)*64;     // r0 = k base (256), c0 = n base (768)
    int g = tid >> 6, c = tid & 63;
    #pragma unroll
    for (int i=0;i<16;++i){
      int r = i*4 + g;
      tile[r*66 + c] = (short)f_bits(aw2[(size_t)(r0+r)*768 + c0 + c]);
    }
    __syncthreads();
    #pragma unroll
    for (int i=0;i<16;++i){
      int cc = i*4 + g, rr = c;
      int n = c0 + cc, k = r0 + rr;
      int f = (n>>4)*8 + (k>>5);
      int ln = ((k>>3)&3)*16 + (n&15);
      agw2T[(size_t)f*512 + ln*8 + (k&7)] = tile[rr*66 + cc];
    }
  }
}

// ================= Gram prep v2 — Gm written in MFMA-fragment layout (ktiles=8) =================
__global__ __launch_bounds__(256) void k_gprep(const short* __restrict__ w2r,
                                               const float* __restrict__ b2,
                                               const short* __restrict__ w1t,
                                               const float* __restrict__ b1,
                                               short* __restrict__ Gm, float* __restrict__ gscal,
                                               float* __restrict__ g1s){
  __shared__ float b2s[768];
  __shared__ float red[8];
  const int tid = threadIdx.x, blk = blockIdx.x;
  if (blk < 64){
    const int wave = tid >> 6, lane = tid & 63, quad = lane >> 4, l16 = lane & 15;
    const int id = blk*4 + wave, ti = id >> 4, tj = id & 15;
    f32x4 acc = (f32x4){0.f,0.f,0.f,0.f};
    for (int ks = 0; ks < 24; ++ks){
      bf16x8 af = *(const bf16x8*)&w2r[(size_t)(ti*16 + l16)*768 + ks*32 + quad*8];
      bf16x8 bf = *(const bf16x8*)&w2r[(size_t)(tj*16 + l16)*768 + ks*32 + quad*8];
      acc = __builtin_amdgcn_mfma_f32_16x16x32_bf16(af, bf, acc, 0,0,0);
    }
    // value at (n = ti*16 + quad*4 + r, k = tj*16 + l16)
    {
      int k = tj*16 + l16;
      int fbase = ti*8 + (k >> 5);
      int ksub = ((k >> 3) & 3);
      int e = k & 7;
      #pragma unroll
      for (int r = 0; r < 4; ++r){
        int ln = ksub*16 + (quad*4 + r);
        Gm[fbase*512 + ln*8 + e] = (short)f_bits(acc[r]);
      }
    }
  } else if (blk == 64){
    for (int c = tid; c < 768; c += 256) b2s[c] = b2[c];
    __syncthreads();
    float sa = 0.f, wa = 0.f;
    const uint4* wr = (const uint4*)(w2r + (size_t)tid*768);
    #pragma unroll 4
    for (int kk = 0; kk < 96; ++kk){
      uint4 ww = wr[kk];
      const float* bp = &b2s[kk*8];
      float x0=lo_f(ww.x), x1=hi_f(ww.x), x2=lo_f(ww.y), x3=hi_f(ww.y);
      float x4=lo_f(ww.z), x5=hi_f(ww.z), x6=lo_f(ww.w), x7=hi_f(ww.w);
      sa += (x0+x1)+(x2+x3)+(x4+x5)+(x6+x7);
      wa += bp[0]*x0 + bp[1]*x1 + bp[2]*x2 + bp[3]*x3
          + bp[4]*x4 + bp[5]*x5 + bp[6]*x6 + bp[7]*x7;
    }
    // ext rows in fragment layout: n=256 (sa), n=257 (wa), n=258..287 zero; k = tid
    {
      int e = tid & 7;
      int ksub = (tid >> 3) & 3;
      int f16 = 128 + (tid >> 5);            // tile 16 fragments
      Gm[f16*512 + (ksub*16 + 0)*8 + e] = (short)f_bits(sa);   // n=256
      Gm[f16*512 + (ksub*16 + 1)*8 + e] = (short)f_bits(wa);   // n=257
      #pragma unroll
      for (int rr = 258; rr < 288; ++rr){
        int ff = (rr >> 4)*8 + (tid >> 5);
        int ln = ksub*16 + (rr & 15);
        Gm[ff*512 + ln*8 + e] = 0;
      }
    }
    float pb = 0.f, pbb = 0.f;
    for (int c = tid; c < 768; c += 256){ float bb = b2s[c]; pb += bb; pbb += bb*bb; }
    for (int m = 32; m >= 1; m >>= 1){ pb += __shfl_xor(pb,m); pbb += __shfl_xor(pbb,m); }
    if ((tid & 63) == 0){ red[tid>>6] = pb; red[4+(tid>>6)] = pbb; }
    __syncthreads();
    if (tid == 0){ gscal[0] = red[0]+red[1]+red[2]+red[3]; gscal[1] = red[4]+red[5]+red[6]+red[7]; }
  } else {
    const unsigned short* w1u = (const unsigned short*)w1t;
    if (tid < 81){
      int i = tid / 9, j = tid % 9;
      float acc = 0.f;
      for (int c = 0; c < 256; ++c)
        acc += bits_f(w1u[c*32 + i]) * bits_f(w1u[c*32 + j]);
      g1s[18 + tid] = acc;
    } else if (tid < 90){
      int i = tid - 81;
      float sa = 0.f, sb = 0.f;
      for (int c = 0; c < 256; ++c){
        float x = bits_f(w1u[c*32 + i]);
        sa += x; sb += x * b1[c];
      }
      g1s[i] = sa; g1s[9 + i] = sb;
    } else if (tid == 90){
      float pb = 0.f, pbb = 0.f;
      for (int c = 0; c < 256; ++c){ float bb = b1[c]; pb += bb; pbb += bb*bb; }
      g1s[99] = pb; g1s[100] = pbb;
    }
  }
}

// ================= geometric encoder; WG=(pair,jt), 256 thr, 3 WG/CU =================
// Gm consumed in fragment layout: per-(ci,ks) load = contiguous 1KB wave burst.
// Disjoint partials: gv[(pair*6+jt)*258 + {0..255:V, 256:R, 257:T}]
__global__ __launch_bounds__(256, 3) void k_geo(
    const float* __restrict__ coord, const short* __restrict__ w1t,
    const float* __restrict__ b1g, const float* __restrict__ g1g, const float* __restrict__ be1g,
    const short* __restrict__ Gm, const float* __restrict__ gscal,
    const float* __restrict__ g1s, float* __restrict__ gv)
{
  __shared__ short relbf[64*36];
  __shared__ short h_bf[64*256];   // chunk-swizzled: phys_chunk=((col>>3)+row)&31
  __shared__ float rmean[64], rrstd[64];
  __shared__ float msum[64], wbsum[64], qsum[64];

  const int tid = threadIdx.x;
  const int pair = blockIdx.x % 768;
  const int jt   = blockIdx.x / 768;
  const int j0 = jt * 64;
  const int b = pair / NN;

  if (tid < 64){
    int j = j0 + tid;
    float cix = coord[pair*3+0], ciy = coord[pair*3+1], ciz = coord[pair*3+2];
    float dx = cix - coord[(b*NN+j)*3+0];
    float dy = ciy - coord[(b*NN+j)*3+1];
    float dz = ciz - coord[(b*NN+j)*3+2];
    float dist = sqrtf(dx*dx + dy*dy + dz*dz);
    float inv = 1.f / fmaxf(dist, 1e-12f);
    float x = dx*inv, y = dy*inv, z = dz*inv;
    float rv[9];
    rv[0]=dist; rv[1]=x; rv[2]=y; rv[3]=z; rv[4]=0.f; rv[5]=0.f;
    rv[6]=y*z; rv[7]=x*y; rv[8]=x*z;
    short* rr = &relbf[tid*36];
    float rbf[9];
    #pragma unroll
    for (int k=0;k<9;++k){
      unsigned short hb = f_bits(rv[k]);
      rr[k] = (short)hb; rbf[k] = bits_f(hb);
    }
    #pragma unroll
    for (int k=9;k<32;++k) rr[k]=0;
    float s = g1s[99], ssq = g1s[100];
    #pragma unroll
    for (int i=0;i<9;++i){
      s += rbf[i]*g1s[i];
      ssq += 2.f*rbf[i]*g1s[9+i];
      #pragma unroll
      for (int jj=0;jj<9;++jj) ssq += rbf[i]*rbf[jj]*g1s[18+i*9+jj];
    }
    float mean = s*(1.f/256.f);
    float var  = ssq*(1.f/256.f) - mean*mean;
    rmean[tid] = mean; rrstd[tid] = rsqrtf(var + 1e-5f);
  } else if (tid < 128){
    qsum[tid-64] = 0.f;
  }
  __syncthreads();

  const int wave = tid >> 6, lane = tid & 63, quad = lane >> 4, l16 = lane & 15;

  // ---- phase 2: MFMA mm1 + in-register LN1/ReLU -> h_bf + hreg (packed bf16 pairs)
  unsigned hreg[4][4][2];   // [ci][rb][rpair]
  {
    bf16x8 af[4];
    #pragma unroll
    for (int rb=0;rb<4;++rb)
      af[rb] = *(const bf16x8*)&relbf[(rb*16 + l16)*36 + quad*8];
    f32x4 hacc[4][4];
    #pragma unroll
    for (int ci=0;ci<4;++ci){
      int cb = wave*4 + ci;
      bf16x8 bfw = *(const bf16x8*)&w1t[(cb*16 + l16)*32 + quad*8];
      #pragma unroll
      for (int rb=0;rb<4;++rb)
        hacc[ci][rb] = __builtin_amdgcn_mfma_f32_16x16x32_bf16(af[rb], bfw, (f32x4){0.f,0.f,0.f,0.f}, 0,0,0);
    }
    f32x4 rmv[4], rsv[4];
    #pragma unroll
    for (int rb=0;rb<4;++rb){
      rmv[rb] = *(const f32x4*)&rmean[rb*16 + quad*4];
      rsv[rb] = *(const f32x4*)&rrstd[rb*16 + quad*4];
    }
    #pragma unroll
    for (int ci=0;ci<4;++ci){
      int col = (wave*4+ci)*16 + l16;
      float b1c = b1g[col], g1c = g1g[col], be1c = be1g[col];
      int chb = col >> 3, lo = col & 7;
      #pragma unroll
      for (int rb=0;rb<4;++rb){
        float hn[4];
        #pragma unroll
        for (int r=0;r<4;++r)
          hn[r] = fmaxf((hacc[ci][rb][r] + b1c - rmv[rb][r]) * rsv[rb][r] * g1c + be1c, 0.f);
        unsigned p0 = cvt_pk_bf16(hn[0], hn[1]);
        unsigned p1 = cvt_pk_bf16(hn[2], hn[3]);
        hreg[ci][rb][0] = p0; hreg[ci][rb][1] = p1;
        int row0 = rb*16 + quad*4;
        h_bf[(row0+0)*256 + ((chb + row0+0)&31)*8 + lo] = (short)(p0 & 0xffff);
        h_bf[(row0+1)*256 + ((chb + row0+1)&31)*8 + lo] = (short)(p0 >> 16);
        h_bf[(row0+2)*256 + ((chb + row0+2)&31)*8 + lo] = (short)(p1 & 0xffff);
        h_bf[(row0+3)*256 + ((chb + row0+3)&31)*8 + lo] = (short)(p1 >> 16);
      }
    }
  }
  __syncthreads();

  // ---- phase 3: U = H@Gm_ext; wave0 ext tile -> msum/wbsum; Q from hreg
  {
    f32x4 acc[4][4];
    #pragma unroll
    for (int ci=0;ci<4;++ci)
      #pragma unroll
      for (int rb=0;rb<4;++rb) acc[ci][rb] = (f32x4){0.f,0.f,0.f,0.f};
    f32x4 eacc[4];
    #pragma unroll
    for (int rb=0;rb<4;++rb) eacc[rb] = (f32x4){0.f,0.f,0.f,0.f};
    for (int ks=0;ks<8;++ks){
      bf16x8 a4[4];
      #pragma unroll
      for (int rb=0;rb<4;++rb){
        int row = rb*16 + l16;
        a4[rb] = *(const bf16x8*)&h_bf[row*256 + (((ks*4 + quad) + row)&31)*8];
      }
      #pragma unroll
      for (int ci=0;ci<4;++ci){
        // fragment-contiguous B load: frag = (wave*4+ci)*8 + ks, per-lane 16B
        bf16x8 bg = *(const bf16x8*)&Gm[((wave*4+ci)*8 + ks)*512 + lane*8];
        #pragma unroll
        for (int rb=0;rb<4;++rb)
          acc[ci][rb] = __builtin_amdgcn_mfma_f32_16x16x32_bf16(a4[rb], bg, acc[ci][rb], 0,0,0);
      }
      if (wave == 0){
        bf16x8 bge = *(const bf16x8*)&Gm[(128 + ks)*512 + lane*8];
        #pragma unroll
        for (int rb=0;rb<4;++rb)
          eacc[rb] = __builtin_amdgcn_mfma_f32_16x16x32_bf16(a4[rb], bge, eacc[rb], 0,0,0);
      }
    }
    if (wave == 0 && l16 < 2){
      float* dst = (l16 == 0) ? msum : wbsum;
      #pragma unroll
      for (int rb=0;rb<4;++rb)
        #pragma unroll
        for (int r=0;r<4;++r) dst[rb*16 + quad*4 + r] = eacc[rb][r];
    }
    #pragma unroll
    for (int rb=0;rb<4;++rb){
      #pragma unroll
      for (int r=0;r<4;++r){
        int row = rb*16 + quad*4 + r;
        float qp = 0.f;
        #pragma unroll
        for (int ci=0;ci<4;++ci){
          unsigned p = hreg[ci][rb][r>>1];
          float hv = (r & 1) ? hi_f(p) : lo_f(p);
          qp += acc[ci][rb][r] * hv;
        }
        qp += __shfl_xor(qp,1);
        qp += __shfl_xor(qp,2);
        qp += __shfl_xor(qp,4);
        qp += __shfl_xor(qp,8);
        if (l16 == 0) atomicAdd(&qsum[row], qp);
      }
    }
  }
  __syncthreads();
  if (tid < 64){
    float Sb = gscal[0], Sbb = gscal[1];
    float m2 = (msum[tid] + Sb)*(1.f/768.f);
    float ssq = qsum[tid] + 2.f*wbsum[tid] + Sbb;
    float var = ssq*(1.f/768.f) - m2*m2;
    rmean[tid] = m2; rrstd[tid] = rsqrtf(var + 1e-5f);
  }
  __syncthreads();
  float* gp = gv + ((size_t)pair*6 + jt)*258;
  if (tid < 64){
    float rr = rrstd[tid], tt = rmean[tid]*rrstd[tid];
    for (int m = 32; m >= 1; m >>= 1){ rr += __shfl_xor(rr,m); tt += __shfl_xor(tt,m); }
    if (tid == 0){ gp[256] = rr; gp[257] = tt; }
  }
  // ---- V = sum_j rstd_j h_j : from hreg; quad-reduce via shfl; coalesced stores
  {
    float vp[4] = {0.f, 0.f, 0.f, 0.f};
    #pragma unroll
    for (int rb=0;rb<4;++rb){
      #pragma unroll
      for (int r=0;r<4;++r){
        int row = rb*16 + quad*4 + r;
        float rs = rrstd[row];
        #pragma unroll
        for (int ci=0;ci<4;++ci){
          unsigned p = hreg[ci][rb][r>>1];
          float hv = (r & 1) ? hi_f(p) : lo_f(p);
          vp[ci] += rs * hv;
        }
      }
    }
    #pragma unroll
    for (int ci=0;ci<4;++ci){
      vp[ci] += __shfl_xor(vp[ci],16);
      vp[ci] += __shfl_xor(vp[ci],32);
    }
    if (quad == 0){
      #pragma unroll
      for (int ci=0;ci<4;++ci)
        gp[(wave*4+ci)*16 + l16] = vp[ci];
    }
  }
}

// ================= finalize geo: reduce 6 partials + LN2(V@W2) =================
__global__ __launch_bounds__(256) void k_geofin(
    const float* __restrict__ gv, const short* __restrict__ w2r,
    const float* __restrict__ b2g, const float* __restrict__ g2g,
    const float* __restrict__ be2g, unsigned short* __restrict__ geo)
{
  __shared__ float V[256];
  __shared__ float RT[2];
  const int tid = threadIdx.x, pair = blockIdx.x;
  const float* gp = gv + (size_t)pair*6*258;
  V[tid] = gp[tid] + gp[258 + tid] + gp[2*258 + tid]
         + gp[3*258 + tid] + gp[4*258 + tid] + gp[5*258 + tid];
  if (tid < 2){
    float r = 0.f;
    #pragma unroll
    for (int t = 0; t < 6; ++t) r += gp[t*258 + 256 + tid];
    RT[tid] = r;
  }
  __syncthreads();
  const float R = RT[0], T = RT[1];
  const unsigned short* wr = (const unsigned short*)w2r;
  float a0 = 0.f, a1 = 0.f, a2 = 0.f;
  #pragma unroll 4
  for (int k = 0; k < 256; ++k){
    float vk = V[k];
    const unsigned short* row = wr + (size_t)k*768;
    a0 += vk * bits_f(row[tid]);
    a1 += vk * bits_f(row[tid+256]);
    a2 += vk * bits_f(row[tid+512]);
  }
  size_t base = (size_t)pair*DD;
  geo[base + tid]       = f_bits(g2g[tid]    *(a0 + b2g[tid]    *R - T)*(1.f/384.f) + be2g[tid]);
  geo[base + tid + 256] = f_bits(g2g[tid+256]*(a1 + b2g[tid+256]*R - T)*(1.f/384.f) + be2g[tid+256]);
  geo[base + tid + 512] = f_bits(g2g[tid+512]*(a2 + b2g[tid+512]*R - T)*(1.f/384.f) + be2g[tid+512]);
}

// ================= superpoint means: parallel list-build + 2-deep gather (grid=128) =================
__global__ __launch_bounds__(256) void k_mean(
    const int* __restrict__ lab, const float* __restrict__ feat,
    const unsigned short* __restrict__ geo, float* __restrict__ cntw,
    unsigned short* __restrict__ xmean, float* __restrict__ gmean)
{
  __shared__ int ls[NN];
  __shared__ int ent[NN];
  __shared__ int cnt_s;
  const int tid = threadIdx.x;
  const int bs = blockIdx.x, b = bs >> 6, s = bs & 63;
  if (tid == 0) cnt_s = 0;
  for (int j = tid; j < NN; j += 256) ls[j] = lab[b*NN + j];
  __syncthreads();
  for (int j = tid; j < NN; j += 256){
    if (ls[j] == s){
      int p = atomicAdd(&cnt_s, 1);
      ent[p] = j;
    }
  }
  __syncthreads();
  const int cnt = cnt_s;
  float f0=0.f, f1=0.f, f2=0.f, g0=0.f, g1=0.f, g2=0.f;
  int idx = 0;
  for (; idx + 1 < cnt; idx += 2){
    size_t ra = (size_t)(b*NN + ent[idx])*DD;
    size_t rb = (size_t)(b*NN + ent[idx+1])*DD;
    float a0 = feat[ra+tid], a1 = feat[ra+tid+256], a2 = feat[ra+tid+512];
    float b0 = feat[rb+tid], b1v = feat[rb+tid+256], b2 = feat[rb+tid+512];
    float ga0 = bits_f(geo[ra+tid]), ga1 = bits_f(geo[ra+tid+256]), ga2 = bits_f(geo[ra+tid+512]);
    float gb0 = bits_f(geo[rb+tid]), gb1 = bits_f(geo[rb+tid+256]), gb2 = bits_f(geo[rb+tid+512]);
    f0 += a0 + b0; f1 += a1 + b1v; f2 += a2 + b2;
    g0 += ga0 + gb0; g1 += ga1 + gb1; g2 += ga2 + gb2;
  }
  if (idx < cnt){
    size_t ra = (size_t)(b*NN + ent[idx])*DD;
    f0 += feat[ra+tid]; f1 += feat[ra+tid+256]; f2 += feat[ra+tid+512];
    g0 += bits_f(geo[ra+tid]); g1 += bits_f(geo[ra+tid+256]); g2 += bits_f(geo[ra+tid+512]);
  }
  const float inv = 1.f / fmaxf((float)cnt, 1.f);
  if (tid == 0) cntw[bs] = (float)cnt;
  size_t base = (size_t)bs * DD;
  xmean[base + tid]       = f_bits(f0*inv);
  xmean[base + tid + 256] = f_bits(f1*inv);
  xmean[base + tid + 512] = f_bits(f2*inv);
  gmean[base + tid]       = g0*inv;
  gmean[base + tid + 256] = g1*inv;
  gmean[base + tid + 512] = g2*inv;
}

// ================= aggregator MLP via MFMA (grid=8, 16 rows/block) =================
__global__ __launch_bounds__(256) void k_mlp(
    const unsigned short* __restrict__ xmean, const float* __restrict__ gmean,
    const short* __restrict__ w1T, const float* __restrict__ b1g,
    const float* __restrict__ g1g, const float* __restrict__ be1g,
    const short* __restrict__ w2T, const float* __restrict__ b2g,
    const float* __restrict__ g2g, const float* __restrict__ be2g,
    float* __restrict__ comb)
{
  __shared__ short hA[16*264];     // bf16 hidden, padded stride
  __shared__ float rsum[16], rsq[16], rmean[16], rrstd[16];
  const int tid = threadIdx.x;
  const int wave = tid >> 6, lane = tid & 63, quad = lane >> 4, l16 = lane & 15;
  const int bs0 = blockIdx.x * 16;
  if (tid < 16){ rsum[tid] = 0.f; rsq[tid] = 0.f; }
  __syncthreads();

  // ---- layer 1: [16x768] @ agw1T(frag, ktiles=24) -> 16x256, LN1+ReLU -> hA
  f32x4 acc[4];
  #pragma unroll
  for (int cb=0;cb<4;++cb) acc[cb] = (f32x4){0.f,0.f,0.f,0.f};
  for (int ks = 0; ks < 24; ++ks){
    bf16x8 af = *(const bf16x8*)&((const short*)xmean)[(size_t)(bs0 + l16)*DD + ks*32 + quad*8];
    #pragma unroll
    for (int cb=0;cb<4;++cb){
      bf16x8 bw = *(const bf16x8*)&w1T[((wave*4+cb)*24 + ks)*512 + lane*8];
      acc[cb] = __builtin_amdgcn_mfma_f32_16x16x32_bf16(af, bw, acc[cb], 0,0,0);
    }
  }
  {
    float ps[4] = {0.f,0.f,0.f,0.f}, pq[4] = {0.f,0.f,0.f,0.f};
    #pragma unroll
    for (int cb=0;cb<4;++cb){
      int col = wave*64 + cb*16 + l16;
      float b1c = b1g[col];
      #pragma unroll
      for (int r=0;r<4;++r){
        float v = acc[cb][r] + b1c;
        acc[cb][r] = v;
        ps[r] += v; pq[r] += v*v;
      }
    }
    #pragma unroll
    for (int r=0;r<4;++r){
      ps[r] += __shfl_xor(ps[r],1); pq[r] += __shfl_xor(pq[r],1);
      ps[r] += __shfl_xor(ps[r],2); pq[r] += __shfl_xor(pq[r],2);
      ps[r] += __shfl_xor(ps[r],4); pq[r] += __shfl_xor(pq[r],4);
      ps[r] += __shfl_xor(ps[r],8); pq[r] += __shfl_xor(pq[r],8);
      if (l16 == 0){ atomicAdd(&rsum[quad*4+r], ps[r]); atomicAdd(&rsq[quad*4+r], pq[r]); }
    }
  }
  __syncthreads();
  if (tid < 16){
    float mean = rsum[tid]*(1.f/HH);
    float var  = rsq[tid]*(1.f/HH) - mean*mean;
    rmean[tid] = mean; rrstd[tid] = rsqrtf(var + 1e-5f);
    rsum[tid] = 0.f; rsq[tid] = 0.f;     // re-zero for LN2
  }
  __syncthreads();
  #pragma unroll
  for (int cb=0;cb<4;++cb){
    int col = wave*64 + cb*16 + l16;
    float g1c = g1g[col], be1c = be1g[col];
    #pragma unroll
    for (int r=0;r<4;++r){
      int row = quad*4 + r;
      float h = fmaxf((acc[cb][r]-rmean[row])*rrstd[row]*g1c + be1c, 0.f);
      hA[row*264 + col] = (short)f_bits(h);
    }
  }
  __syncthreads();

  // ---- layer 2: [16x256] @ agw2T(frag, ktiles=8) -> 16x768, LN2 -> comb (+gmean)
  f32x4 acc2[12];
  #pragma unroll
  for (int cb=0;cb<12;++cb) acc2[cb] = (f32x4){0.f,0.f,0.f,0.f};
  for (int ks = 0; ks < 8; ++ks){
    bf16x8 af = *(const bf16x8*)&hA[l16*264 + ks*32 + quad*8];
    #pragma unroll
    for (int cb=0;cb<12;++cb){
      bf16x8 bw = *(const bf16x8*)&w2T[((wave*12+cb)*8 + ks)*512 + lane*8];
      acc2[cb] = __builtin_amdgcn_mfma_f32_16x16x32_bf16(af, bw, acc2[cb], 0,0,0);
    }
  }
  {
    float ps[4] = {0.f,0.f,0.f,0.f}, pq[4] = {0.f,0.f,0.f,0.f};
    #pragma unroll
    for (int cb=0;cb<12;++cb){
      int col = wave*192 + cb*16 + l16;
      float b2c = b2g[col];
      #pragma unroll
      for (int r=0;r<4;++r){
        float v = acc2[cb][r] + b2c;
        acc2[cb][r] = v;
        ps[r] += v; pq[r] += v*v;
      }
    }
    #pragma unroll
    for (int r=0;r<4;++r){
      ps[r] += __shfl_xor(ps[r],1); pq[r] += __shfl_xor(pq[r],1);
      ps[r] += __shfl_xor(ps[r],2); pq[r] += __shfl_xor(pq[r],2);
      ps[r] += __shfl_xor(ps[r],4); pq[r] += __shfl_xor(pq[r],4);
      ps[r] += __shfl_xor(ps[r],8); pq[r] += __shfl_xor(pq[r],8);
      if (l16 == 0){ atomicAdd(&rsum[quad*4+r], ps[r]); atomicAdd(&rsq[quad*4+r], pq[r]); }
    }
  }
  __syncthreads();
  if (tid < 16){
    float mean = rsum[tid]*(1.f/DD);
    float var  = rsq[tid]*(1.f/DD) - mean*mean;
    rmean[tid] = mean; rrstd[tid] = rsqrtf(var + 1e-5f);
  }
  __syncthreads();
  #pragma unroll
  for (int cb=0;cb<12;++cb){
    int col = wave*192 + cb*16 + l16;
    float g2c = g2g[col], be2c = be2g[col];
    #pragma unroll
    for (int r=0;r<4;++r){
      int row = quad*4 + r;
      size_t idx = (size_t)(bs0+row)*DD + col;
      comb[idx] = (acc2[cb][r]-rmean[row])*rrstd[row]*g2c + be2c + gmean[idx];
    }
  }
}

// ================= gather + enhanced =================
__global__ void k_enhance(const float* __restrict__ feat, const int* __restrict__ lab,
                          const float* __restrict__ cntw, const float* __restrict__ comb,
                          float* __restrict__ enh, unsigned short* __restrict__ enhb)
{
  int idx = blockIdx.x * 256 + threadIdx.x;
  int c = idx % DD; int bn = idx / DD; int b = bn / NN;
  int l = lab[bn];
  float f = feat[idx];
  float cg = comb[(size_t)(b*SS + l)*DD + c];
  float cnt = cntw[b*SS + l];
  float e = (cnt >= 2.0f) ? (0.7f*f + 0.3f*cg) : f;
  enh[idx] = e;
  enhb[idx] = f_bits(e);
}

// ================= q/k/v projections via MFMA; weights in fragment layout =================
__global__ __launch_bounds__(256, 4) void k_qkv(
    const unsigned short* __restrict__ enhb, const unsigned short* __restrict__ geo,
    const short* __restrict__ wqT, const short* __restrict__ wkT, const short* __restrict__ wvT,
    const float* __restrict__ bq, const float* __restrict__ bk, const float* __restrict__ bv,
    unsigned short* __restrict__ qo, unsigned short* __restrict__ ko, unsigned short* __restrict__ vo)
{
  const int tid = threadIdx.x, blk = blockIdx.x;   // 432 = 3 mats * 48 rt * 3 ct
  const int m = blk / 144, rem = blk % 144;
  const int rt = rem / 3, ct = rem % 3;
  const int wave = tid >> 6, lane = tid & 63, quad = lane >> 4, l16 = lane & 15;
  const short* WT = (m==0)?wqT:(m==1)?wkT:wvT;
  const float* Bv = (m==0)?bq:(m==1)?bk:bv;
  unsigned short* Y = (m==0)?qo:(m==1)?ko:vo;
  const short* X = (const short*)((m==0)? enhb : geo);
  const float oscale = (m==0)? 0.10206207261596577f : 1.0f;
  const int row0 = rt*16;
  const int col0 = ct*256 + wave*64;
  const int nt0 = ct*16 + wave*4;

  f32x4 acc[4];
  #pragma unroll
  for (int cb=0;cb<4;++cb) acc[cb] = (f32x4){0.f,0.f,0.f,0.f};
  for (int ks = 0; ks < 24; ++ks){
    bf16x8 af = *(const bf16x8*)&X[(size_t)(row0 + l16)*DD + ks*32 + quad*8];
    #pragma unroll
    for (int cb=0;cb<4;++cb){
      bf16x8 bw = *(const bf16x8*)&WT[((nt0+cb)*24 + ks)*512 + lane*8];
      acc[cb] = __builtin_amdgcn_mfma_f32_16x16x32_bf16(af, bw, acc[cb], 0,0,0);
    }
  }
  #pragma unroll
  for (int cb=0;cb<4;++cb){
    int col = col0 + cb*16 + l16;
    float bb = Bv[col];
    #pragma unroll
    for (int r=0;r<4;++r){
      int row = row0 + quad*4 + r;
      Y[(size_t)row*DD + col] = f_bits((acc[cb][r] + bb)*oscale);
    }
  }
}

// ================= attention: split over jt halves (384 blocks) =================
__global__ __launch_bounds__(256) void k_attn_split(
    const unsigned short* __restrict__ qws, const unsigned short* __restrict__ kws,
    const unsigned short* __restrict__ vws, float* __restrict__ pws)
{
  __shared__ short kt[64*104];
  __shared__ short vt[64*104];
  __shared__ float st[32*66];
  __shared__ float lsum[32];
  const int tid = threadIdx.x;
  const int half = blockIdx.x / 192;
  const int inner = blockIdx.x % 192;
  const int b = inner / (NHH*12); int rem = inner % (NHH*12);
  const int h = rem / 12; const int qt = rem % 12; const int q0 = qt*32;
  const int sq = tid >> 3, jp = tid & 7;
  const int qp = tid >> 4, dp = tid & 15;
  unsigned qreg[48];
  {
    const unsigned* qr = (const unsigned*)(qws + (size_t)(b*NN + q0 + sq)*DD + h*DHH);
    #pragma unroll
    for (int d2 = 0; d2 < 48; ++d2) qreg[d2] = qr[d2];
  }
  if (tid < 32) lsum[tid] = 0.f;
  float Oacc[2][6];
  #pragma unroll
  for (int a = 0; a < 2; ++a)
    #pragma unroll
    for (int m = 0; m < 6; ++m) Oacc[a][m] = 0.f;

  for (int jt = half*3; jt < half*3 + 3; ++jt){
    const int j0 = jt * 64;
    __syncthreads();
    for (int x = tid; x < 64*48; x += 256){
      int jl = x / 48, du = x % 48;
      size_t rowoff = (size_t)(b*NN + j0 + jl)*DD + h*DHH;
      ((unsigned*)&kt[jl*104])[du] = ((const unsigned*)(kws + rowoff))[du];
      ((unsigned*)&vt[jl*104])[du] = ((const unsigned*)(vws + rowoff))[du];
    }
    __syncthreads();
    float lpart = 0.f;
    #pragma unroll
    for (int jj = 0; jj < 8; ++jj){
      int j = jp*8 + jj;
      const uint4* kr4 = (const uint4*)&kt[j*104];
      float s = 0.f;
      #pragma unroll
      for (int d4 = 0; d4 < 12; ++d4){
        uint4 kk = kr4[d4];
        unsigned q0r = qreg[4*d4], q1r = qreg[4*d4+1], q2r = qreg[4*d4+2], q3r = qreg[4*d4+3];
        s += lo_f(kk.x)*lo_f(q0r) + hi_f(kk.x)*hi_f(q0r);
        s += lo_f(kk.y)*lo_f(q1r) + hi_f(kk.y)*hi_f(q1r);
        s += lo_f(kk.z)*lo_f(q2r) + hi_f(kk.z)*hi_f(q2r);
        s += lo_f(kk.w)*lo_f(q3r) + hi_f(kk.w)*hi_f(q3r);
      }
      float p = __expf(s);
      st[sq*66 + j] = p;
      lpart += p;
    }
    lpart += __shfl_xor(lpart,1);
    lpart += __shfl_xor(lpart,2);
    lpart += __shfl_xor(lpart,4);
    if (jp == 0) lsum[sq] += lpart;
    __syncthreads();
    #pragma unroll 4
    for (int j = 0; j < 64; ++j){
      float p0 = st[(2*qp)*66 + j];
      float p1 = st[(2*qp+1)*66 + j];
      const unsigned* vr = (const unsigned*)&vt[j*104 + dp*6];
      #pragma unroll
      for (int m = 0; m < 3; ++m){
        unsigned vv = vr[m];
        float v0 = lo_f(vv), v1 = hi_f(vv);
        Oacc[0][2*m]   += p0*v0; Oacc[0][2*m+1] += p0*v1;
        Oacc[1][2*m]   += p1*v0; Oacc[1][2*m+1] += p1*v1;
      }
    }
  }
  __syncthreads();
  float* pb = pws + ((size_t)inner*2 + half)*3104;
  #pragma unroll
  for (int m = 0; m < 6; ++m){
    pb[(2*qp)*96 + dp*6 + m]   = Oacc[0][m];
    pb[(2*qp+1)*96 + dp*6 + m] = Oacc[1][m];
  }
  if (tid < 32) pb[3072 + tid] = lsum[tid];
}

// ================= attention finalize =================
__global__ __launch_bounds__(256) void k_attnfin(
    const float* __restrict__ pws, unsigned short* __restrict__ ows)
{
  __shared__ float ls[32];
  const int tid = threadIdx.x, inner = blockIdx.x;
  const int b = inner / (NHH*12); int rem = inner % (NHH*12);
  const int h = rem / 12; const int qt = rem % 12; const int q0 = qt*32;
  const float* p0 = pws + (size_t)inner*2*3104;
  const float* p1 = p0 + 3104;
  if (tid < 32) ls[tid] = 1.f / (p0[3072+tid] + p1[3072+tid]);
  __syncthreads();
  #pragma unroll
  for (int u = 0; u < 12; ++u){
    int e = tid + u*256;
    int q = e / 96, d = e % 96;
    float o = (p0[e] + p1[e]) * ls[q];
    ows[(size_t)(b*NN + q0 + q)*DD + h*DHH + d] = f_bits(o);
  }
}

// ================= attention fallback (single-pass) =================
__global__ __launch_bounds__(256) void k_attn_full(
    const unsigned short* __restrict__ qws, const unsigned short* __restrict__ kws,
    const unsigned short* __restrict__ vws, unsigned short* __restrict__ ows)
{
  __shared__ short kt[64*104];
  __shared__ short vt[64*104];
  __shared__ float st[32*66];
  __shared__ float lsum[32];
  const int tid = threadIdx.x;
  const int blk = blockIdx.x;
  const int b = blk / (NHH*12); int rem = blk % (NHH*12);
  const int h = rem / 12; const int qt = rem % 12; const int q0 = qt*32;
  const int sq = tid >> 3, jp = tid & 7;
  const int qp = tid >> 4, dp = tid & 15;
  unsigned qreg[48];
  {
    const unsigned* qr = (const unsigned*)(qws + (size_t)(b*NN + q0 + sq)*DD + h*DHH);
    #pragma unroll
    for (int d2 = 0; d2 < 48; ++d2) qreg[d2] = qr[d2];
  }
  if (tid < 32) lsum[tid] = 0.f;
  float Oacc[2][6];
  #pragma unroll
  for (int a = 0; a < 2; ++a)
    #pragma unroll
    for (int m = 0; m < 6; ++m) Oacc[a][m] = 0.f;
  for (int jt = 0; jt < 6; ++jt){
    const int j0 = jt * 64;
    __syncthreads();
    for (int x = tid; x < 64*48; x += 256){
      int jl = x / 48, du = x % 48;
      size_t rowoff = (size_t)(b*NN + j0 + jl)*DD + h*DHH;
      ((unsigned*)&kt[jl*104])[du] = ((const unsigned*)(kws + rowoff))[du];
      ((unsigned*)&vt[jl*104])[du] = ((const unsigned*)(vws + rowoff))[du];
    }
    __syncthreads();
    float lpart = 0.f;
    #pragma unroll
    for (int jj = 0; jj < 8; ++jj){
      int j = jp*8 + jj;
      const uint4* kr4 = (const uint4*)&kt[j*104];
      float s = 0.f;
      #pragma unroll
      for (int d4 = 0; d4 < 12; ++d4){
        uint4 kk = kr4[d4];
        unsigned q0r = qreg[4*d4], q1r = qreg[4*d4+1], q2r = qreg[4*d4+2], q3r = qreg[4*d4+3];
        s += lo_f(kk.x)*lo_f(q0r) + hi_f(kk.x)*hi_f(q0r);
        s += lo_f(kk.y)*lo_f(q1r) + hi_f(kk.y)*hi_f(q1r);
        s += lo_f(kk.z)*lo_f(q2r) + hi_f(kk.z)*hi_f(q2r);
        s += lo_f(kk.w)*lo_f(q3r) + hi_f(kk.w)*hi_f(q3r);
      }
      float p = __expf(s);
      st[sq*66 + j] = p;
      lpart += p;
    }
    lpart += __shfl_xor(lpart,1);
    lpart += __shfl_xor(lpart,2);
    lpart += __shfl_xor(lpart,4);
    if (jp == 0) lsum[sq] += lpart;
    __syncthreads();
    #pragma unroll 4
    for (int j = 0; j < 64; ++j){
      float p0 = st[(2*qp)*66 + j];
      float p1 = st[(2*qp+1)*66 + j];
      const unsigned* vr = (const unsigned*)&vt[j*104 + dp*6];
      #pragma unroll
      for (int m = 0; m < 3; ++m){
        unsigned vv = vr[m];
        float v0 = lo_f(vv), v1 = hi_f(vv);
        Oacc[0][2*m]   += p0*v0; Oacc[0][2*m+1] += p0*v1;
        Oacc[1][2*m]   += p1*v0; Oacc[1][2*m+1] += p1*v1;
      }
    }
  }
  __syncthreads();
  float l0 = 1.f / lsum[2*qp], l1 = 1.f / lsum[2*qp+1];
  size_t ob = (size_t)(b*NN + q0)*DD + h*DHH + dp*6;
  #pragma unroll
  for (int m = 0; m < 6; ++m){
    ows[ob + (size_t)(2*qp)*DD + m]   = f_bits(Oacc[0][m]*l0);
    ows[ob + (size_t)(2*qp+1)*DD + m] = f_bits(Oacc[1][m]*l1);
  }
}

// ================= output projection via MFMA; woT in fragment layout =================
__global__ __launch_bounds__(256, 4) void k_out(
    const unsigned short* __restrict__ ows, const float* __restrict__ enh,
    const short* __restrict__ woT, const float* __restrict__ bo, float* __restrict__ out)
{
  const int tid = threadIdx.x, blk = blockIdx.x;   // 144 = 48 rt * 3 ct
  const int rt = blk / 3, ct = blk % 3;
  const int wave = tid >> 6, lane = tid & 63, quad = lane >> 4, l16 = lane & 15;
  const int row0 = rt*16;
  const int col0 = ct*256 + wave*64;
  const int nt0 = ct*16 + wave*4;
  f32x4 acc[4];
  #pragma unroll
  for (int cb=0;cb<4;++cb) acc[cb] = (f32x4){0.f,0.f,0.f,0.f};
  for (int ks = 0; ks < 24; ++ks){
    bf16x8 af = *(const bf16x8*)&((const short*)ows)[(size_t)(row0 + l16)*DD + ks*32 + quad*8];
    #pragma unroll
    for (int cb=0;cb<4;++cb){
      bf16x8 bw = *(const bf16x8*)&woT[((nt0+cb)*24 + ks)*512 + lane*8];
      acc[cb] = __builtin_amdgcn_mfma_f32_16x16x32_bf16(af, bw, acc[cb], 0,0,0);
    }
  }
  #pragma unroll
  for (int cb=0;cb<4;++cb){
    int col = col0 + cb*16 + l16;
    float bb = bo[col];
    #pragma unroll
    for (int r=0;r<4;++r){
      size_t idx = (size_t)(row0 + quad*4 + r)*DD + col;
      out[idx] = enh[idx] + 0.5f*(acc[cb][r] + bb);
    }
  }
}

extern "C" void kernel_launch(void* const* d_in, const int* in_sizes, int n_in,
                              void* d_out, int out_size, void* d_ws, size_t ws_size,
                              hipStream_t stream) {
  const float* coord = (const float*)d_in[0];
  const float* feat  = (const float*)d_in[1];
  const int*   lab   = (const int*)d_in[2];
  const float* ge_w1 = (const float*)d_in[3];
  const float* ge_b1 = (const float*)d_in[4];
  const float* ge_g1 = (const float*)d_in[5];
  const float* ge_be1= (const float*)d_in[6];
  const float* ge_w2 = (const float*)d_in[7];
  const float* ge_b2 = (const float*)d_in[8];
  const float* ge_g2 = (const float*)d_in[9];
  const float* ge_be2= (const float*)d_in[10];
  const float* ag_w1 = (const float*)d_in[11];
  const float* ag_b1 = (const float*)d_in[12];
  const float* ag_g1 = (const float*)d_in[13];
  const float* ag_be1= (const float*)d_in[14];
  const float* ag_w2 = (const float*)d_in[15];
  const float* ag_b2 = (const float*)d_in[16];
  const float* ag_g2 = (const float*)d_in[17];
  const float* ag_be2= (const float*)d_in[18];
  const float* wq = (const float*)d_in[19];
  const float* bq = (const float*)d_in[20];
  const float* wk = (const float*)d_in[21];
  const float* bk = (const float*)d_in[22];
  const float* wv = (const float*)d_in[23];
  const float* bv = (const float*)d_in[24];
  const float* wo = (const float*)d_in[25];
  const float* bo = (const float*)d_in[26];

  char* w = (char*)d_ws;
  unsigned short* geo_bf = (unsigned short*)(w);              // 1,179,648  [ow overlay]
  float*          enh_f  = (float*)(w + 1179648);             // 2,359,296
  unsigned short* enh_bf = (unsigned short*)(w + 3538944);    // 1,179,648
  unsigned short* qw_bf  = (unsigned short*)(w + 4718592);    // 1,179,648
  unsigned short* kw_bf  = (unsigned short*)(w + 5898240);    // 1,179,648
  unsigned short* vw_bf  = (unsigned short*)(w + 7077888);    // 1,179,648
  // gv OVERLAYS qw/kw/vw + hole: alive only between k_geo and k_geofin,
  // both strictly before k_qkv writes qw/kw/vw.  768*6*258*4 = 4,755,456 B
  // spans [4718592, 9474048) < cntw @ 9842688.
  float*          gv     = (float*)(w + 4718592);
  // gmean/xmean: alive only from k_mean to k_mlp (after gv is dead);
  // overlay the dead gv region tail [8257536, 8847360).
  float*          gmean  = (float*)(w + 8257536);             //   393,216
  unsigned short* xmean  = (unsigned short*)(w + 8650752);    //   196,608
  float*          cntw   = (float*)(w + 9842688);             //       512
  float*          comb   = (float*)(w + 9843200);             //   393,216
  short*          w2T    = (short*)(w + 10236416);            //   393,216
  short*          w2r    = (short*)(w + 10629632);            //   393,216
  short*          w1t    = (short*)(w + 11022848);            //    16,384
  short*          Gm     = (short*)(w + 11039232);            //   147,456 (fragment layout)
  float*          g1s    = (float*)(w + 11186688);            //       512
  float*          gscal  = (float*)(w + 11187200);            //       256
  short*          wqT    = (short*)(w + 11187456);            // 1,179,648 (fragment layout)
  short*          wkT    = (short*)(w + 12367104);            // 1,179,648 (fragment layout)
  short*          wvT    = (short*)(w + 13546752);            // 1,179,648 (fragment layout)
  short*          woT    = (short*)(w + 14726400);            // 1,179,648 (fragment layout)
  short*          agw1T  = (short*)(w + 15906048);            //   393,216 (fragment layout)
  short*          agw2T  = (short*)(w + 16299264);            //   393,216 (fragment layout)
  float*          pws    = (float*)(w + 16692480);            // 4,767,744 (optional)
  unsigned short* ow_bf  = geo_bf;
  const bool split_attn = (ws_size >= 21460224);

  hipLaunchKernelGGL(k_prep,    dim3(1520),  dim3(256), 0, stream,
                     ge_w2, ge_w1, wq, wk, wv, wo, ag_w1, ag_w2,
                     w2T, w2r, wqT, wkT, wvT, woT, w1t, agw1T, agw2T);
  hipLaunchKernelGGL(k_gprep,   dim3(66),    dim3(256), 0, stream,
                     w2r, ge_b2, w1t, ge_b1, Gm, gscal, g1s);
  hipLaunchKernelGGL(k_geo,     dim3(4608),  dim3(256), 0, stream,
                     coord, w1t, ge_b1, ge_g1, ge_be1, Gm, gscal, g1s, gv);
  hipLaunchKernelGGL(k_geofin,  dim3(768),   dim3(256), 0, stream,
                     gv, w2r, ge_b2, ge_g2, ge_be2, geo_bf);
  hipLaunchKernelGGL(k_mean,    dim3(128),   dim3(256), 0, stream,
                     lab, feat, geo_bf, cntw, xmean, gmean);
  hipLaunchKernelGGL(k_mlp,     dim3(8),     dim3(256), 0, stream,
                     xmean, gmean, agw1T, ag_b1, ag_g1, ag_be1,
                     agw2T, ag_b2, ag_g2, ag_be2, comb);
  hipLaunchKernelGGL(k_enhance, dim3(2304),  dim3(256), 0, stream,
                     feat, lab, cntw, comb, enh_f, enh_bf);
  hipLaunchKernelGGL(k_qkv,     dim3(432),   dim3(256), 0, stream,
                     enh_bf, geo_bf, wqT, wkT, wvT, bq, bk, bv, qw_bf, kw_bf, vw_bf);
  if (split_attn){
    hipLaunchKernelGGL(k_attn_split, dim3(384), dim3(256), 0, stream,
                       qw_bf, kw_bf, vw_bf, pws);
    hipLaunchKernelGGL(k_attnfin,    dim3(192), dim3(256), 0, stream,
                       pws, ow_bf);
  } else {
    hipLaunchKernelGGL(k_attn_full,  dim3(192), dim3(256), 0, stream,
                       qw_bf, kw_bf, vw_bf, ow_bf);
  }
  hipLaunchKernelGGL(k_out,     dim3(144),   dim3(256), 0, stream,
                     ow_bf, enh_f, woT, bo, (float*)d_out);
}

// Round 15
// 367.235 us; speedup vs baseline: 1.0339x; 1.0339x over previous
//
#include <hip/hip_runtime.h>
#include <hip/hip_bf16.h>
#include <stdint.h>
#include <stddef.h>

#define BB 2
#define NN 384
#define DD 768
#define HH 256
#define SS 64
#define NHH 8
#define DHH 96

typedef __attribute__((ext_vector_type(8))) short bf16x8;
typedef __attribute__((ext_vector_type(4))) float f32x4;

__device__ __forceinline__ float bits_f(unsigned short u){
  unsigned x = ((unsigned)u) << 16; float f; __builtin_memcpy(&f, &x, 4); return f;
}
__device__ __forceinline__ unsigned short f_bits(float a){
  unsigned x; __builtin_memcpy(&x, &a, 4);
  unsigned r = x + 0x7fffu + ((x >> 16) & 1u);
  return (unsigned short)(r >> 16);
}
__device__ __forceinline__ float lo_f(unsigned u){ unsigned x = u << 16; float f; __builtin_memcpy(&f,&x,4); return f; }
__device__ __forceinline__ float hi_f(unsigned u){ unsigned x = u & 0xffff0000u; float f; __builtin_memcpy(&f,&x,4); return f; }
// hardware RTNE pack: lo=bf16(a), hi=bf16(b) — same rounding as f_bits
__device__ __forceinline__ unsigned cvt_pk_bf16(float a, float b){
  unsigned r; asm("v_cvt_pk_bf16_f32 %0, %1, %2" : "=v"(r) : "v"(a), "v"(b));
  return r;
}

// ================= prep: all transposes (LDS-tiled, coalesced) =================
__global__ __launch_bounds__(256) void k_prep(
    const float* __restrict__ w2, const float* __restrict__ w1g,
    const float* __restrict__ wq, const float* __restrict__ wk,
    const float* __restrict__ wv, const float* __restrict__ wo,
    const float* __restrict__ aw1, const float* __restrict__ aw2,
    short* __restrict__ w2T, short* __restrict__ w2r,
    short* __restrict__ wqT, short* __restrict__ wkT, short* __restrict__ wvT,
    short* __restrict__ woT, short* __restrict__ w1t,
    short* __restrict__ agw1T, short* __restrict__ agw2T)
{
  __shared__ short tile[64*66];
  const int tid = threadIdx.x, blk = blockIdx.x;
  if (blk < 48){               // w2 [256,768] -> w2T [768,256]
    int t = blk;
    int r0 = (t/12)*64, c0 = (t%12)*64;
    int g = tid >> 6, c = tid & 63;
    #pragma unroll
    for (int i=0;i<16;++i){
      int r = i*4 + g;
      tile[r*66 + c] = (short)f_bits(w2[(size_t)(r0+r)*768 + c0 + c]);
    }
    __syncthreads();
    #pragma unroll
    for (int i=0;i<16;++i){
      int cc = i*4 + g, rr = c;
      w2T[(size_t)(c0+cc)*256 + r0 + rr] = tile[rr*66 + cc];
    }
    return;
  }
  if (blk < 816){              // w2r: row-major bf16 copy
    int idx = (blk-48)*256 + tid;
    w2r[idx] = (short)f_bits(w2[idx]);
    return;
  }
  if (blk < 1392){             // attn weights [768,768] -> T[n][k]
    int t = blk - 816;
    int mat = t / 144, tt = t % 144;
    const float* W = (mat==0)?wq:(mat==1)?wk:(mat==2)?wv:wo;
    short* T = (mat==0)?wqT:(mat==1)?wkT:(mat==2)?wvT:woT;
    int r0 = (tt/12)*64, c0 = (tt%12)*64;
    int g = tid >> 6, c = tid & 63;
    #pragma unroll
    for (int i=0;i<16;++i){
      int r = i*4 + g;
      tile[r*66 + c] = (short)f_bits(W[(size_t)(r0+r)*768 + c0 + c]);
    }
    __syncthreads();
    #pragma unroll
    for (int i=0;i<16;++i){
      int cc = i*4 + g, rr = c;
      T[(size_t)(c0+cc)*768 + r0 + rr] = tile[rr*66 + cc];
    }
    return;
  }
  if (blk < 1424){             // w1t [256c][32k], K padded
    int idx = (blk-1392)*256 + tid;
    int c = idx >> 5, kk = idx & 31;
    w1t[idx] = (kk < 9) ? (short)f_bits(w1g[kk*256 + c]) : (short)0;
    return;
  }
  if (blk < 1472){             // ag_w1 [768,256] -> agw1T [256n][768k]
    int t = blk - 1424;
    int r0 = (t/4)*64, c0 = (t%4)*64;
    int g = tid >> 6, c = tid & 63;
    #pragma unroll
    for (int i=0;i<16;++i){
      int r = i*4 + g;
      tile[r*66 + c] = (short)f_bits(aw1[(size_t)(r0+r)*256 + c0 + c]);
    }
    __syncthreads();
    #pragma unroll
    for (int i=0;i<16;++i){
      int cc = i*4 + g, rr = c;
      agw1T[(size_t)(c0+cc)*768 + r0 + rr] = tile[rr*66 + cc];
    }
    return;
  }
  {                            // ag_w2 [256,768] -> agw2T [768n][256k]
    int t = blk - 1472;
    int r0 = (t/12)*64, c0 = (t%12)*64;
    int g = tid >> 6, c = tid & 63;
    #pragma unroll
    for (int i=0;i<16;++i){
      int r = i*4 + g;
      tile[r*66 + c] = (short)f_bits(aw2[(size_t)(r0+r)*768 + c0 + c]);
    }
    __syncthreads();
    #pragma unroll
    for (int i=0;i<16;++i){
      int cc = i*4 + g, rr = c;
      agw2T[(size_t)(c0+cc)*256 + r0 + rr] = tile[rr*66 + cc];
    }
  }
}

// ================= Gram prep v2 — Gm written in MFMA-fragment layout =================
// GmF element (n,k): frag f = (n>>4)*8 + (k>>5); lane = ((k>>3)&3)*16 + (n&15); e = k&7
// index (shorts) = f*512 + lane*8 + e.  Consumers read one contiguous 1KB burst per frag.
__global__ __launch_bounds__(256) void k_gprep(const short* __restrict__ w2r,
                                               const float* __restrict__ b2,
                                               const short* __restrict__ w1t,
                                               const float* __restrict__ b1,
                                               short* __restrict__ Gm, float* __restrict__ gscal,
                                               float* __restrict__ g1s){
  __shared__ float b2s[768];
  __shared__ float red[8];
  const int tid = threadIdx.x, blk = blockIdx.x;
  if (blk < 64){
    const int wave = tid >> 6, lane = tid & 63, quad = lane >> 4, l16 = lane & 15;
    const int id = blk*4 + wave, ti = id >> 4, tj = id & 15;
    f32x4 acc = (f32x4){0.f,0.f,0.f,0.f};
    for (int ks = 0; ks < 24; ++ks){
      bf16x8 af = *(const bf16x8*)&w2r[(size_t)(ti*16 + l16)*768 + ks*32 + quad*8];
      bf16x8 bf = *(const bf16x8*)&w2r[(size_t)(tj*16 + l16)*768 + ks*32 + quad*8];
      acc = __builtin_amdgcn_mfma_f32_16x16x32_bf16(af, bf, acc, 0,0,0);
    }
    // value at (n = ti*16 + quad*4 + r, k = tj*16 + l16)
    {
      int k = tj*16 + l16;
      int fbase = ti*8 + (k >> 5);
      int ksub = ((k >> 3) & 3);
      int e = k & 7;
      #pragma unroll
      for (int r = 0; r < 4; ++r){
        int ln = ksub*16 + (quad*4 + r);
        Gm[fbase*512 + ln*8 + e] = (short)f_bits(acc[r]);
      }
    }
  } else if (blk == 64){
    for (int c = tid; c < 768; c += 256) b2s[c] = b2[c];
    __syncthreads();
    float sa = 0.f, wa = 0.f;
    const uint4* wr = (const uint4*)(w2r + (size_t)tid*768);
    #pragma unroll 4
    for (int kk = 0; kk < 96; ++kk){
      uint4 ww = wr[kk];
      const float* bp = &b2s[kk*8];
      float x0=lo_f(ww.x), x1=hi_f(ww.x), x2=lo_f(ww.y), x3=hi_f(ww.y);
      float x4=lo_f(ww.z), x5=hi_f(ww.z), x6=lo_f(ww.w), x7=hi_f(ww.w);
      sa += (x0+x1)+(x2+x3)+(x4+x5)+(x6+x7);
      wa += bp[0]*x0 + bp[1]*x1 + bp[2]*x2 + bp[3]*x3
          + bp[4]*x4 + bp[5]*x5 + bp[6]*x6 + bp[7]*x7;
    }
    // ext rows in fragment layout: n=256 (sa), n=257 (wa), n=258..287 zero; k = tid
    {
      int e = tid & 7;
      int ksub = (tid >> 3) & 3;
      int f16 = 128 + (tid >> 5);            // tile 16 fragments
      Gm[f16*512 + (ksub*16 + 0)*8 + e] = (short)f_bits(sa);   // n=256
      Gm[f16*512 + (ksub*16 + 1)*8 + e] = (short)f_bits(wa);   // n=257
      #pragma unroll
      for (int rr = 258; rr < 288; ++rr){
        int ff = (rr >> 4)*8 + (tid >> 5);
        int ln = ksub*16 + (rr & 15);
        Gm[ff*512 + ln*8 + e] = 0;
      }
    }
    float pb = 0.f, pbb = 0.f;
    for (int c = tid; c < 768; c += 256){ float bb = b2s[c]; pb += bb; pbb += bb*bb; }
    for (int m = 32; m >= 1; m >>= 1){ pb += __shfl_xor(pb,m); pbb += __shfl_xor(pbb,m); }
    if ((tid & 63) == 0){ red[tid>>6] = pb; red[4+(tid>>6)] = pbb; }
    __syncthreads();
    if (tid == 0){ gscal[0] = red[0]+red[1]+red[2]+red[3]; gscal[1] = red[4]+red[5]+red[6]+red[7]; }
  } else {
    const unsigned short* w1u = (const unsigned short*)w1t;
    if (tid < 81){
      int i = tid / 9, j = tid % 9;
      float acc = 0.f;
      for (int c = 0; c < 256; ++c)
        acc += bits_f(w1u[c*32 + i]) * bits_f(w1u[c*32 + j]);
      g1s[18 + tid] = acc;
    } else if (tid < 90){
      int i = tid - 81;
      float sa = 0.f, sb = 0.f;
      for (int c = 0; c < 256; ++c){
        float x = bits_f(w1u[c*32 + i]);
        sa += x; sb += x * b1[c];
      }
      g1s[i] = sa; g1s[9 + i] = sb;
    } else if (tid == 90){
      float pb = 0.f, pbb = 0.f;
      for (int c = 0; c < 256; ++c){ float bb = b1[c]; pb += bb; pbb += bb*bb; }
      g1s[99] = pb; g1s[100] = pbb;
    }
  }
}

// ================= geometric encoder; WG=(pair,jt), 256 thr, 3 WG/CU =================
// Gm consumed in fragment layout: per-(ci,ks) load = contiguous 1KB wave burst.
// Disjoint partials: gv[(pair*6+jt)*258 + {0..255:V, 256:R, 257:T}]
__global__ __launch_bounds__(256, 3) void k_geo(
    const float* __restrict__ coord, const short* __restrict__ w1t,
    const float* __restrict__ b1g, const float* __restrict__ g1g, const float* __restrict__ be1g,
    const short* __restrict__ Gm, const float* __restrict__ gscal,
    const float* __restrict__ g1s, float* __restrict__ gv)
{
  __shared__ short relbf[64*36];
  __shared__ short h_bf[64*256];   // chunk-swizzled: phys_chunk=((col>>3)+row)&31
  __shared__ float rmean[64], rrstd[64];
  __shared__ float msum[64], wbsum[64], qsum[64];

  const int tid = threadIdx.x;
  const int pair = blockIdx.x % 768;
  const int jt   = blockIdx.x / 768;
  const int j0 = jt * 64;
  const int b = pair / NN;

  if (tid < 64){
    int j = j0 + tid;
    float cix = coord[pair*3+0], ciy = coord[pair*3+1], ciz = coord[pair*3+2];
    float dx = cix - coord[(b*NN+j)*3+0];
    float dy = ciy - coord[(b*NN+j)*3+1];
    float dz = ciz - coord[(b*NN+j)*3+2];
    float dist = sqrtf(dx*dx + dy*dy + dz*dz);
    float inv = 1.f / fmaxf(dist, 1e-12f);
    float x = dx*inv, y = dy*inv, z = dz*inv;
    float rv[9];
    rv[0]=dist; rv[1]=x; rv[2]=y; rv[3]=z; rv[4]=0.f; rv[5]=0.f;
    rv[6]=y*z; rv[7]=x*y; rv[8]=x*z;
    short* rr = &relbf[tid*36];
    float rbf[9];
    #pragma unroll
    for (int k=0;k<9;++k){
      unsigned short hb = f_bits(rv[k]);
      rr[k] = (short)hb; rbf[k] = bits_f(hb);
    }
    #pragma unroll
    for (int k=9;k<32;++k) rr[k]=0;
    float s = g1s[99], ssq = g1s[100];
    #pragma unroll
    for (int i=0;i<9;++i){
      s += rbf[i]*g1s[i];
      ssq += 2.f*rbf[i]*g1s[9+i];
      #pragma unroll
      for (int jj=0;jj<9;++jj) ssq += rbf[i]*rbf[jj]*g1s[18+i*9+jj];
    }
    float mean = s*(1.f/256.f);
    float var  = ssq*(1.f/256.f) - mean*mean;
    rmean[tid] = mean; rrstd[tid] = rsqrtf(var + 1e-5f);
  } else if (tid < 128){
    qsum[tid-64] = 0.f;
  }
  __syncthreads();

  const int wave = tid >> 6, lane = tid & 63, quad = lane >> 4, l16 = lane & 15;

  // ---- phase 2: MFMA mm1 + in-register LN1/ReLU -> h_bf + hreg (packed bf16 pairs)
  unsigned hreg[4][4][2];   // [ci][rb][rpair]
  {
    bf16x8 af[4];
    #pragma unroll
    for (int rb=0;rb<4;++rb)
      af[rb] = *(const bf16x8*)&relbf[(rb*16 + l16)*36 + quad*8];
    f32x4 hacc[4][4];
    #pragma unroll
    for (int ci=0;ci<4;++ci){
      int cb = wave*4 + ci;
      bf16x8 bfw = *(const bf16x8*)&w1t[(cb*16 + l16)*32 + quad*8];
      #pragma unroll
      for (int rb=0;rb<4;++rb)
        hacc[ci][rb] = __builtin_amdgcn_mfma_f32_16x16x32_bf16(af[rb], bfw, (f32x4){0.f,0.f,0.f,0.f}, 0,0,0);
    }
    f32x4 rmv[4], rsv[4];
    #pragma unroll
    for (int rb=0;rb<4;++rb){
      rmv[rb] = *(const f32x4*)&rmean[rb*16 + quad*4];
      rsv[rb] = *(const f32x4*)&rrstd[rb*16 + quad*4];
    }
    #pragma unroll
    for (int ci=0;ci<4;++ci){
      int col = (wave*4+ci)*16 + l16;
      float b1c = b1g[col], g1c = g1g[col], be1c = be1g[col];
      int chb = col >> 3, lo = col & 7;
      #pragma unroll
      for (int rb=0;rb<4;++rb){
        float hn[4];
        #pragma unroll
        for (int r=0;r<4;++r)
          hn[r] = fmaxf((hacc[ci][rb][r] + b1c - rmv[rb][r]) * rsv[rb][r] * g1c + be1c, 0.f);
        unsigned p0 = cvt_pk_bf16(hn[0], hn[1]);
        unsigned p1 = cvt_pk_bf16(hn[2], hn[3]);
        hreg[ci][rb][0] = p0; hreg[ci][rb][1] = p1;
        int row0 = rb*16 + quad*4;
        h_bf[(row0+0)*256 + ((chb + row0+0)&31)*8 + lo] = (short)(p0 & 0xffff);
        h_bf[(row0+1)*256 + ((chb + row0+1)&31)*8 + lo] = (short)(p0 >> 16);
        h_bf[(row0+2)*256 + ((chb + row0+2)&31)*8 + lo] = (short)(p1 & 0xffff);
        h_bf[(row0+3)*256 + ((chb + row0+3)&31)*8 + lo] = (short)(p1 >> 16);
      }
    }
  }
  __syncthreads();

  // ---- phase 3: U = H@Gm_ext; wave0 ext tile -> msum/wbsum; Q from hreg
  {
    f32x4 acc[4][4];
    #pragma unroll
    for (int ci=0;ci<4;++ci)
      #pragma unroll
      for (int rb=0;rb<4;++rb) acc[ci][rb] = (f32x4){0.f,0.f,0.f,0.f};
    f32x4 eacc[4];
    #pragma unroll
    for (int rb=0;rb<4;++rb) eacc[rb] = (f32x4){0.f,0.f,0.f,0.f};
    for (int ks=0;ks<8;++ks){
      bf16x8 a4[4];
      #pragma unroll
      for (int rb=0;rb<4;++rb){
        int row = rb*16 + l16;
        a4[rb] = *(const bf16x8*)&h_bf[row*256 + (((ks*4 + quad) + row)&31)*8];
      }
      #pragma unroll
      for (int ci=0;ci<4;++ci){
        // fragment-contiguous B load: frag = (wave*4+ci)*8 + ks, per-lane 16B
        bf16x8 bg = *(const bf16x8*)&Gm[((wave*4+ci)*8 + ks)*512 + lane*8];
        #pragma unroll
        for (int rb=0;rb<4;++rb)
          acc[ci][rb] = __builtin_amdgcn_mfma_f32_16x16x32_bf16(a4[rb], bg, acc[ci][rb], 0,0,0);
      }
      if (wave == 0){
        bf16x8 bge = *(const bf16x8*)&Gm[(128 + ks)*512 + lane*8];
        #pragma unroll
        for (int rb=0;rb<4;++rb)
          eacc[rb] = __builtin_amdgcn_mfma_f32_16x16x32_bf16(a4[rb], bge, eacc[rb], 0,0,0);
      }
    }
    if (wave == 0 && l16 < 2){
      float* dst = (l16 == 0) ? msum : wbsum;
      #pragma unroll
      for (int rb=0;rb<4;++rb)
        #pragma unroll
        for (int r=0;r<4;++r) dst[rb*16 + quad*4 + r] = eacc[rb][r];
    }
    #pragma unroll
    for (int rb=0;rb<4;++rb){
      #pragma unroll
      for (int r=0;r<4;++r){
        int row = rb*16 + quad*4 + r;
        float qp = 0.f;
        #pragma unroll
        for (int ci=0;ci<4;++ci){
          unsigned p = hreg[ci][rb][r>>1];
          float hv = (r & 1) ? hi_f(p) : lo_f(p);
          qp += acc[ci][rb][r] * hv;
        }
        qp += __shfl_xor(qp,1);
        qp += __shfl_xor(qp,2);
        qp += __shfl_xor(qp,4);
        qp += __shfl_xor(qp,8);
        if (l16 == 0) atomicAdd(&qsum[row], qp);
      }
    }
  }
  __syncthreads();
  if (tid < 64){
    float Sb = gscal[0], Sbb = gscal[1];
    float m2 = (msum[tid] + Sb)*(1.f/768.f);
    float ssq = qsum[tid] + 2.f*wbsum[tid] + Sbb;
    float var = ssq*(1.f/768.f) - m2*m2;
    rmean[tid] = m2; rrstd[tid] = rsqrtf(var + 1e-5f);
  }
  __syncthreads();
  float* gp = gv + ((size_t)pair*6 + jt)*258;
  if (tid < 64){
    float rr = rrstd[tid], tt = rmean[tid]*rrstd[tid];
    for (int m = 32; m >= 1; m >>= 1){ rr += __shfl_xor(rr,m); tt += __shfl_xor(tt,m); }
    if (tid == 0){ gp[256] = rr; gp[257] = tt; }
  }
  // ---- V = sum_j rstd_j h_j : from hreg; quad-reduce via shfl; coalesced stores
  {
    float vp[4] = {0.f, 0.f, 0.f, 0.f};
    #pragma unroll
    for (int rb=0;rb<4;++rb){
      #pragma unroll
      for (int r=0;r<4;++r){
        int row = rb*16 + quad*4 + r;
        float rs = rrstd[row];
        #pragma unroll
        for (int ci=0;ci<4;++ci){
          unsigned p = hreg[ci][rb][r>>1];
          float hv = (r & 1) ? hi_f(p) : lo_f(p);
          vp[ci] += rs * hv;
        }
      }
    }
    #pragma unroll
    for (int ci=0;ci<4;++ci){
      vp[ci] += __shfl_xor(vp[ci],16);
      vp[ci] += __shfl_xor(vp[ci],32);
    }
    if (quad == 0){
      #pragma unroll
      for (int ci=0;ci<4;++ci)
        gp[(wave*4+ci)*16 + l16] = vp[ci];
    }
  }
}

// ================= finalize geo: reduce 6 partials + LN2(V@W2) =================
__global__ __launch_bounds__(256) void k_geofin(
    const float* __restrict__ gv, const short* __restrict__ w2r,
    const float* __restrict__ b2g, const float* __restrict__ g2g,
    const float* __restrict__ be2g, unsigned short* __restrict__ geo)
{
  __shared__ float V[256];
  __shared__ float RT[2];
  const int tid = threadIdx.x, pair = blockIdx.x;
  const float* gp = gv + (size_t)pair*6*258;
  V[tid] = gp[tid] + gp[258 + tid] + gp[2*258 + tid]
         + gp[3*258 + tid] + gp[4*258 + tid] + gp[5*258 + tid];
  if (tid < 2){
    float r = 0.f;
    #pragma unroll
    for (int t = 0; t < 6; ++t) r += gp[t*258 + 256 + tid];
    RT[tid] = r;
  }
  __syncthreads();
  const float R = RT[0], T = RT[1];
  const unsigned short* wr = (const unsigned short*)w2r;
  float a0 = 0.f, a1 = 0.f, a2 = 0.f;
  #pragma unroll 4
  for (int k = 0; k < 256; ++k){
    float vk = V[k];
    const unsigned short* row = wr + (size_t)k*768;
    a0 += vk * bits_f(row[tid]);
    a1 += vk * bits_f(row[tid+256]);
    a2 += vk * bits_f(row[tid+512]);
  }
  size_t base = (size_t)pair*DD;
  geo[base + tid]       = f_bits(g2g[tid]    *(a0 + b2g[tid]    *R - T)*(1.f/384.f) + be2g[tid]);
  geo[base + tid + 256] = f_bits(g2g[tid+256]*(a1 + b2g[tid+256]*R - T)*(1.f/384.f) + be2g[tid+256]);
  geo[base + tid + 512] = f_bits(g2g[tid+512]*(a2 + b2g[tid+512]*R - T)*(1.f/384.f) + be2g[tid+512]);
}

// ================= superpoint means: parallel list-build + 2-deep gather (grid=128) =================
__global__ __launch_bounds__(256) void k_mean(
    const int* __restrict__ lab, const float* __restrict__ feat,
    const unsigned short* __restrict__ geo, float* __restrict__ cntw,
    unsigned short* __restrict__ xmean, float* __restrict__ gmean)
{
  __shared__ int ls[NN];
  __shared__ int ent[NN];
  __shared__ int cnt_s;
  const int tid = threadIdx.x;
  const int bs = blockIdx.x, b = bs >> 6, s = bs & 63;
  if (tid == 0) cnt_s = 0;
  for (int j = tid; j < NN; j += 256) ls[j] = lab[b*NN + j];
  __syncthreads();
  for (int j = tid; j < NN; j += 256){
    if (ls[j] == s){
      int p = atomicAdd(&cnt_s, 1);
      ent[p] = j;
    }
  }
  __syncthreads();
  const int cnt = cnt_s;
  float f0=0.f, f1=0.f, f2=0.f, g0=0.f, g1=0.f, g2=0.f;
  int idx = 0;
  for (; idx + 1 < cnt; idx += 2){
    size_t ra = (size_t)(b*NN + ent[idx])*DD;
    size_t rb = (size_t)(b*NN + ent[idx+1])*DD;
    float a0 = feat[ra+tid], a1 = feat[ra+tid+256], a2 = feat[ra+tid+512];
    float b0 = feat[rb+tid], b1v = feat[rb+tid+256], b2 = feat[rb+tid+512];
    float ga0 = bits_f(geo[ra+tid]), ga1 = bits_f(geo[ra+tid+256]), ga2 = bits_f(geo[ra+tid+512]);
    float gb0 = bits_f(geo[rb+tid]), gb1 = bits_f(geo[rb+tid+256]), gb2 = bits_f(geo[rb+tid+512]);
    f0 += a0 + b0; f1 += a1 + b1v; f2 += a2 + b2;
    g0 += ga0 + gb0; g1 += ga1 + gb1; g2 += ga2 + gb2;
  }
  if (idx < cnt){
    size_t ra = (size_t)(b*NN + ent[idx])*DD;
    f0 += feat[ra+tid]; f1 += feat[ra+tid+256]; f2 += feat[ra+tid+512];
    g0 += bits_f(geo[ra+tid]); g1 += bits_f(geo[ra+tid+256]); g2 += bits_f(geo[ra+tid+512]);
  }
  const float inv = 1.f / fmaxf((float)cnt, 1.f);
  if (tid == 0) cntw[bs] = (float)cnt;
  size_t base = (size_t)bs * DD;
  xmean[base + tid]       = f_bits(f0*inv);
  xmean[base + tid + 256] = f_bits(f1*inv);
  xmean[base + tid + 512] = f_bits(f2*inv);
  gmean[base + tid]       = g0*inv;
  gmean[base + tid + 256] = g1*inv;
  gmean[base + tid + 512] = g2*inv;
}

// ================= aggregator MLP via MFMA (grid=8, 16 rows/block) =================
__global__ __launch_bounds__(256) void k_mlp(
    const unsigned short* __restrict__ xmean, const float* __restrict__ gmean,
    const short* __restrict__ w1T, const float* __restrict__ b1g,
    const float* __restrict__ g1g, const float* __restrict__ be1g,
    const short* __restrict__ w2T, const float* __restrict__ b2g,
    const float* __restrict__ g2g, const float* __restrict__ be2g,
    float* __restrict__ comb)
{
  __shared__ short hA[16*264];     // bf16 hidden, padded stride
  __shared__ float rsum[16], rsq[16], rmean[16], rrstd[16];
  const int tid = threadIdx.x;
  const int wave = tid >> 6, lane = tid & 63, quad = lane >> 4, l16 = lane & 15;
  const int bs0 = blockIdx.x * 16;
  if (tid < 16){ rsum[tid] = 0.f; rsq[tid] = 0.f; }
  __syncthreads();

  // ---- layer 1: [16x768] @ agw1T[256n][768k] -> 16x256, LN1+ReLU -> hA
  f32x4 acc[4];
  #pragma unroll
  for (int cb=0;cb<4;++cb) acc[cb] = (f32x4){0.f,0.f,0.f,0.f};
  for (int ks = 0; ks < 24; ++ks){
    bf16x8 af = *(const bf16x8*)&((const short*)xmean)[(size_t)(bs0 + l16)*DD + ks*32 + quad*8];
    #pragma unroll
    for (int cb=0;cb<4;++cb){
      bf16x8 bw = *(const bf16x8*)&w1T[(size_t)(wave*64 + cb*16 + l16)*768 + ks*32 + quad*8];
      acc[cb] = __builtin_amdgcn_mfma_f32_16x16x32_bf16(af, bw, acc[cb], 0,0,0);
    }
  }
  {
    float ps[4] = {0.f,0.f,0.f,0.f}, pq[4] = {0.f,0.f,0.f,0.f};
    #pragma unroll
    for (int cb=0;cb<4;++cb){
      int col = wave*64 + cb*16 + l16;
      float b1c = b1g[col];
      #pragma unroll
      for (int r=0;r<4;++r){
        float v = acc[cb][r] + b1c;
        acc[cb][r] = v;
        ps[r] += v; pq[r] += v*v;
      }
    }
    #pragma unroll
    for (int r=0;r<4;++r){
      ps[r] += __shfl_xor(ps[r],1); pq[r] += __shfl_xor(pq[r],1);
      ps[r] += __shfl_xor(ps[r],2); pq[r] += __shfl_xor(pq[r],2);
      ps[r] += __shfl_xor(ps[r],4); pq[r] += __shfl_xor(pq[r],4);
      ps[r] += __shfl_xor(ps[r],8); pq[r] += __shfl_xor(pq[r],8);
      if (l16 == 0){ atomicAdd(&rsum[quad*4+r], ps[r]); atomicAdd(&rsq[quad*4+r], pq[r]); }
    }
  }
  __syncthreads();
  if (tid < 16){
    float mean = rsum[tid]*(1.f/HH);
    float var  = rsq[tid]*(1.f/HH) - mean*mean;
    rmean[tid] = mean; rrstd[tid] = rsqrtf(var + 1e-5f);
    rsum[tid] = 0.f; rsq[tid] = 0.f;     // re-zero for LN2
  }
  __syncthreads();
  #pragma unroll
  for (int cb=0;cb<4;++cb){
    int col = wave*64 + cb*16 + l16;
    float g1c = g1g[col], be1c = be1g[col];
    #pragma unroll
    for (int r=0;r<4;++r){
      int row = quad*4 + r;
      float h = fmaxf((acc[cb][r]-rmean[row])*rrstd[row]*g1c + be1c, 0.f);
      hA[row*264 + col] = (short)f_bits(h);
    }
  }
  __syncthreads();

  // ---- layer 2: [16x256] @ agw2T[768n][256k] -> 16x768, LN2 -> comb (+gmean)
  f32x4 acc2[12];
  #pragma unroll
  for (int cb=0;cb<12;++cb) acc2[cb] = (f32x4){0.f,0.f,0.f,0.f};
  for (int ks = 0; ks < 8; ++ks){
    bf16x8 af = *(const bf16x8*)&hA[l16*264 + ks*32 + quad*8];
    #pragma unroll
    for (int cb=0;cb<12;++cb){
      bf16x8 bw = *(const bf16x8*)&w2T[(size_t)(wave*192 + cb*16 + l16)*256 + ks*32 + quad*8];
      acc2[cb] = __builtin_amdgcn_mfma_f32_16x16x32_bf16(af, bw, acc2[cb], 0,0,0);
    }
  }
  {
    float ps[4] = {0.f,0.f,0.f,0.f}, pq[4] = {0.f,0.f,0.f,0.f};
    #pragma unroll
    for (int cb=0;cb<12;++cb){
      int col = wave*192 + cb*16 + l16;
      float b2c = b2g[col];
      #pragma unroll
      for (int r=0;r<4;++r){
        float v = acc2[cb][r] + b2c;
        acc2[cb][r] = v;
        ps[r] += v; pq[r] += v*v;
      }
    }
    #pragma unroll
    for (int r=0;r<4;++r){
      ps[r] += __shfl_xor(ps[r],1); pq[r] += __shfl_xor(pq[r],1);
      ps[r] += __shfl_xor(ps[r],2); pq[r] += __shfl_xor(pq[r],2);
      ps[r] += __shfl_xor(ps[r],4); pq[r] += __shfl_xor(pq[r],4);
      ps[r] += __shfl_xor(ps[r],8); pq[r] += __shfl_xor(pq[r],8);
      if (l16 == 0){ atomicAdd(&rsum[quad*4+r], ps[r]); atomicAdd(&rsq[quad*4+r], pq[r]); }
    }
  }
  __syncthreads();
  if (tid < 16){
    float mean = rsum[tid]*(1.f/DD);
    float var  = rsq[tid]*(1.f/DD) - mean*mean;
    rmean[tid] = mean; rrstd[tid] = rsqrtf(var + 1e-5f);
  }
  __syncthreads();
  #pragma unroll
  for (int cb=0;cb<12;++cb){
    int col = wave*192 + cb*16 + l16;
    float g2c = g2g[col], be2c = be2g[col];
    #pragma unroll
    for (int r=0;r<4;++r){
      int row = quad*4 + r;
      size_t idx = (size_t)(bs0+row)*DD + col;
      comb[idx] = (acc2[cb][r]-rmean[row])*rrstd[row]*g2c + be2c + gmean[idx];
    }
  }
}

// ================= gather + enhanced =================
__global__ void k_enhance(const float* __restrict__ feat, const int* __restrict__ lab,
                          const float* __restrict__ cntw, const float* __restrict__ comb,
                          float* __restrict__ enh, unsigned short* __restrict__ enhb)
{
  int idx = blockIdx.x * 256 + threadIdx.x;
  int c = idx % DD; int bn = idx / DD; int b = bn / NN;
  int l = lab[bn];
  float f = feat[idx];
  float cg = comb[(size_t)(b*SS + l)*DD + c];
  float cnt = cntw[b*SS + l];
  float e = (cnt >= 2.0f) ? (0.7f*f + 0.3f*cg) : f;
  enh[idx] = e;
  enhb[idx] = f_bits(e);
}

// ================= q/k/v projections via MFMA (16-row tiles, 432 blocks) =================
__global__ __launch_bounds__(256, 4) void k_qkv(
    const unsigned short* __restrict__ enhb, const unsigned short* __restrict__ geo,
    const short* __restrict__ wqT, const short* __restrict__ wkT, const short* __restrict__ wvT,
    const float* __restrict__ bq, const float* __restrict__ bk, const float* __restrict__ bv,
    unsigned short* __restrict__ qo, unsigned short* __restrict__ ko, unsigned short* __restrict__ vo)
{
  const int tid = threadIdx.x, blk = blockIdx.x;   // 432 = 3 mats * 48 rt * 3 ct
  const int m = blk / 144, rem = blk % 144;
  const int rt = rem / 3, ct = rem % 3;
  const int wave = tid >> 6, lane = tid & 63, quad = lane >> 4, l16 = lane & 15;
  const short* WT = (m==0)?wqT:(m==1)?wkT:wvT;
  const float* Bv = (m==0)?bq:(m==1)?bk:bv;
  unsigned short* Y = (m==0)?qo:(m==1)?ko:vo;
  const short* X = (const short*)((m==0)? enhb : geo);
  const float oscale = (m==0)? 0.10206207261596577f : 1.0f;
  const int row0 = rt*16;
  const int col0 = ct*256 + wave*64;

  f32x4 acc[4];
  #pragma unroll
  for (int cb=0;cb<4;++cb) acc[cb] = (f32x4){0.f,0.f,0.f,0.f};
  for (int ks = 0; ks < 24; ++ks){
    bf16x8 af = *(const bf16x8*)&X[(size_t)(row0 + l16)*DD + ks*32 + quad*8];
    #pragma unroll
    for (int cb=0;cb<4;++cb){
      bf16x8 bw = *(const bf16x8*)&WT[(size_t)(col0 + cb*16 + l16)*DD + ks*32 + quad*8];
      acc[cb] = __builtin_amdgcn_mfma_f32_16x16x32_bf16(af, bw, acc[cb], 0,0,0);
    }
  }
  #pragma unroll
  for (int cb=0;cb<4;++cb){
    int col = col0 + cb*16 + l16;
    float bb = Bv[col];
    #pragma unroll
    for (int r=0;r<4;++r){
      int row = row0 + quad*4 + r;
      Y[(size_t)row*DD + col] = f_bits((acc[cb][r] + bb)*oscale);
    }
  }
}

// ================= attention: split over jt halves (384 blocks) =================
__global__ __launch_bounds__(256) void k_attn_split(
    const unsigned short* __restrict__ qws, const unsigned short* __restrict__ kws,
    const unsigned short* __restrict__ vws, float* __restrict__ pws)
{
  __shared__ short kt[64*104];
  __shared__ short vt[64*104];
  __shared__ float st[32*66];
  __shared__ float lsum[32];
  const int tid = threadIdx.x;
  const int half = blockIdx.x / 192;
  const int inner = blockIdx.x % 192;
  const int b = inner / (NHH*12); int rem = inner % (NHH*12);
  const int h = rem / 12; const int qt = rem % 12; const int q0 = qt*32;
  const int sq = tid >> 3, jp = tid & 7;
  const int qp = tid >> 4, dp = tid & 15;
  unsigned qreg[48];
  {
    const unsigned* qr = (const unsigned*)(qws + (size_t)(b*NN + q0 + sq)*DD + h*DHH);
    #pragma unroll
    for (int d2 = 0; d2 < 48; ++d2) qreg[d2] = qr[d2];
  }
  if (tid < 32) lsum[tid] = 0.f;
  float Oacc[2][6];
  #pragma unroll
  for (int a = 0; a < 2; ++a)
    #pragma unroll
    for (int m = 0; m < 6; ++m) Oacc[a][m] = 0.f;

  for (int jt = half*3; jt < half*3 + 3; ++jt){
    const int j0 = jt * 64;
    __syncthreads();
    for (int x = tid; x < 64*48; x += 256){
      int jl = x / 48, du = x % 48;
      size_t rowoff = (size_t)(b*NN + j0 + jl)*DD + h*DHH;
      ((unsigned*)&kt[jl*104])[du] = ((const unsigned*)(kws + rowoff))[du];
      ((unsigned*)&vt[jl*104])[du] = ((const unsigned*)(vws + rowoff))[du];
    }
    __syncthreads();
    float lpart = 0.f;
    #pragma unroll
    for (int jj = 0; jj < 8; ++jj){
      int j = jp*8 + jj;
      const uint4* kr4 = (const uint4*)&kt[j*104];
      float s = 0.f;
      #pragma unroll
      for (int d4 = 0; d4 < 12; ++d4){
        uint4 kk = kr4[d4];
        unsigned q0r = qreg[4*d4], q1r = qreg[4*d4+1], q2r = qreg[4*d4+2], q3r = qreg[4*d4+3];
        s += lo_f(kk.x)*lo_f(q0r) + hi_f(kk.x)*hi_f(q0r);
        s += lo_f(kk.y)*lo_f(q1r) + hi_f(kk.y)*hi_f(q1r);
        s += lo_f(kk.z)*lo_f(q2r) + hi_f(kk.z)*hi_f(q2r);
        s += lo_f(kk.w)*lo_f(q3r) + hi_f(kk.w)*hi_f(q3r);
      }
      float p = __expf(s);
      st[sq*66 + j] = p;
      lpart += p;
    }
    lpart += __shfl_xor(lpart,1);
    lpart += __shfl_xor(lpart,2);
    lpart += __shfl_xor(lpart,4);
    if (jp == 0) lsum[sq] += lpart;
    __syncthreads();
    #pragma unroll 4
    for (int j = 0; j < 64; ++j){
      float p0 = st[(2*qp)*66 + j];
      float p1 = st[(2*qp+1)*66 + j];
      const unsigned* vr = (const unsigned*)&vt[j*104 + dp*6];
      #pragma unroll
      for (int m = 0; m < 3; ++m){
        unsigned vv = vr[m];
        float v0 = lo_f(vv), v1 = hi_f(vv);
        Oacc[0][2*m]   += p0*v0; Oacc[0][2*m+1] += p0*v1;
        Oacc[1][2*m]   += p1*v0; Oacc[1][2*m+1] += p1*v1;
      }
    }
  }
  __syncthreads();
  float* pb = pws + ((size_t)inner*2 + half)*3104;
  #pragma unroll
  for (int m = 0; m < 6; ++m){
    pb[(2*qp)*96 + dp*6 + m]   = Oacc[0][m];
    pb[(2*qp+1)*96 + dp*6 + m] = Oacc[1][m];
  }
  if (tid < 32) pb[3072 + tid] = lsum[tid];
}

// ================= attention finalize =================
__global__ __launch_bounds__(256) void k_attnfin(
    const float* __restrict__ pws, unsigned short* __restrict__ ows)
{
  __shared__ float ls[32];
  const int tid = threadIdx.x, inner = blockIdx.x;
  const int b = inner / (NHH*12); int rem = inner % (NHH*12);
  const int h = rem / 12; const int qt = rem % 12; const int q0 = qt*32;
  const float* p0 = pws + (size_t)inner*2*3104;
  const float* p1 = p0 + 3104;
  if (tid < 32) ls[tid] = 1.f / (p0[3072+tid] + p1[3072+tid]);
  __syncthreads();
  #pragma unroll
  for (int u = 0; u < 12; ++u){
    int e = tid + u*256;
    int q = e / 96, d = e % 96;
    float o = (p0[e] + p1[e]) * ls[q];
    ows[(size_t)(b*NN + q0 + q)*DD + h*DHH + d] = f_bits(o);
  }
}

// ================= attention fallback (single-pass) =================
__global__ __launch_bounds__(256) void k_attn_full(
    const unsigned short* __restrict__ qws, const unsigned short* __restrict__ kws,
    const unsigned short* __restrict__ vws, unsigned short* __restrict__ ows)
{
  __shared__ short kt[64*104];
  __shared__ short vt[64*104];
  __shared__ float st[32*66];
  __shared__ float lsum[32];
  const int tid = threadIdx.x;
  const int blk = blockIdx.x;
  const int b = blk / (NHH*12); int rem = blk % (NHH*12);
  const int h = rem / 12; const int qt = rem % 12; const int q0 = qt*32;
  const int sq = tid >> 3, jp = tid & 7;
  const int qp = tid >> 4, dp = tid & 15;
  unsigned qreg[48];
  {
    const unsigned* qr = (const unsigned*)(qws + (size_t)(b*NN + q0 + sq)*DD + h*DHH);
    #pragma unroll
    for (int d2 = 0; d2 < 48; ++d2) qreg[d2] = qr[d2];
  }
  if (tid < 32) lsum[tid] = 0.f;
  float Oacc[2][6];
  #pragma unroll
  for (int a = 0; a < 2; ++a)
    #pragma unroll
    for (int m = 0; m < 6; ++m) Oacc[a][m] = 0.f;
  for (int jt = 0; jt < 6; ++jt){
    const int j0 = jt * 64;
    __syncthreads();
    for (int x = tid; x < 64*48; x += 256){
      int jl = x / 48, du = x % 48;
      size_t rowoff = (size_t)(b*NN + j0 + jl)*DD + h*DHH;
      ((unsigned*)&kt[jl*104])[du] = ((const unsigned*)(kws + rowoff))[du];
      ((unsigned*)&vt[jl*104])[du] = ((const unsigned*)(vws + rowoff))[du];
    }
    __syncthreads();
    float lpart = 0.f;
    #pragma unroll
    for (int jj = 0; jj < 8; ++jj){
      int j = jp*8 + jj;
      const uint4* kr4 = (const uint4*)&kt[j*104];
      float s = 0.f;
      #pragma unroll
      for (int d4 = 0; d4 < 12; ++d4){
        uint4 kk = kr4[d4];
        unsigned q0r = qreg[4*d4], q1r = qreg[4*d4+1], q2r = qreg[4*d4+2], q3r = qreg[4*d4+3];
        s += lo_f(kk.x)*lo_f(q0r) + hi_f(kk.x)*hi_f(q0r);
        s += lo_f(kk.y)*lo_f(q1r) + hi_f(kk.y)*hi_f(q1r);
        s += lo_f(kk.z)*lo_f(q2r) + hi_f(kk.z)*hi_f(q2r);
        s += lo_f(kk.w)*lo_f(q3r) + hi_f(kk.w)*hi_f(q3r);
      }
      float p = __expf(s);
      st[sq*66 + j] = p;
      lpart += p;
    }
    lpart += __shfl_xor(lpart,1);
    lpart += __shfl_xor(lpart,2);
    lpart += __shfl_xor(lpart,4);
    if (jp == 0) lsum[sq] += lpart;
    __syncthreads();
    #pragma unroll 4
    for (int j = 0; j < 64; ++j){
      float p0 = st[(2*qp)*66 + j];
      float p1 = st[(2*qp+1)*66 + j];
      const unsigned* vr = (const unsigned*)&vt[j*104 + dp*6];
      #pragma unroll
      for (int m = 0; m < 3; ++m){
        unsigned vv = vr[m];
        float v0 = lo_f(vv), v1 = hi_f(vv);
        Oacc[0][2*m]   += p0*v0; Oacc[0][2*m+1] += p0*v1;
        Oacc[1][2*m]   += p1*v0; Oacc[1][2*m+1] += p1*v1;
      }
    }
  }
  __syncthreads();
  float l0 = 1.f / lsum[2*qp], l1 = 1.f / lsum[2*qp+1];
  size_t ob = (size_t)(b*NN + q0)*DD + h*DHH + dp*6;
  #pragma unroll
  for (int m = 0; m < 6; ++m){
    ows[ob + (size_t)(2*qp)*DD + m]   = f_bits(Oacc[0][m]*l0);
    ows[ob + (size_t)(2*qp+1)*DD + m] = f_bits(Oacc[1][m]*l1);
  }
}

// ================= output projection via MFMA (16-row tiles, 144 blocks) =================
__global__ __launch_bounds__(256, 4) void k_out(
    const unsigned short* __restrict__ ows, const float* __restrict__ enh,
    const short* __restrict__ woT, const float* __restrict__ bo, float* __restrict__ out)
{
  const int tid = threadIdx.x, blk = blockIdx.x;   // 144 = 48 rt * 3 ct
  const int rt = blk / 3, ct = blk % 3;
  const int wave = tid >> 6, lane = tid & 63, quad = lane >> 4, l16 = lane & 15;
  const int row0 = rt*16;
  const int col0 = ct*256 + wave*64;
  f32x4 acc[4];
  #pragma unroll
  for (int cb=0;cb<4;++cb) acc[cb] = (f32x4){0.f,0.f,0.f,0.f};
  for (int ks = 0; ks < 24; ++ks){
    bf16x8 af = *(const bf16x8*)&((const short*)ows)[(size_t)(row0 + l16)*DD + ks*32 + quad*8];
    #pragma unroll
    for (int cb=0;cb<4;++cb){
      bf16x8 bw = *(const bf16x8*)&woT[(size_t)(col0 + cb*16 + l16)*DD + ks*32 + quad*8];
      acc[cb] = __builtin_amdgcn_mfma_f32_16x16x32_bf16(af, bw, acc[cb], 0,0,0);
    }
  }
  #pragma unroll
  for (int cb=0;cb<4;++cb){
    int col = col0 + cb*16 + l16;
    float bb = bo[col];
    #pragma unroll
    for (int r=0;r<4;++r){
      size_t idx = (size_t)(row0 + quad*4 + r)*DD + col;
      out[idx] = enh[idx] + 0.5f*(acc[cb][r] + bb);
    }
  }
}

extern "C" void kernel_launch(void* const* d_in, const int* in_sizes, int n_in,
                              void* d_out, int out_size, void* d_ws, size_t ws_size,
                              hipStream_t stream) {
  const float* coord = (const float*)d_in[0];
  const float* feat  = (const float*)d_in[1];
  const int*   lab   = (const int*)d_in[2];
  const float* ge_w1 = (const float*)d_in[3];
  const float* ge_b1 = (const float*)d_in[4];
  const float* ge_g1 = (const float*)d_in[5];
  const float* ge_be1= (const float*)d_in[6];
  const float* ge_w2 = (const float*)d_in[7];
  const float* ge_b2 = (const float*)d_in[8];
  const float* ge_g2 = (const float*)d_in[9];
  const float* ge_be2= (const float*)d_in[10];
  const float* ag_w1 = (const float*)d_in[11];
  const float* ag_b1 = (const float*)d_in[12];
  const float* ag_g1 = (const float*)d_in[13];
  const float* ag_be1= (const float*)d_in[14];
  const float* ag_w2 = (const float*)d_in[15];
  const float* ag_b2 = (const float*)d_in[16];
  const float* ag_g2 = (const float*)d_in[17];
  const float* ag_be2= (const float*)d_in[18];
  const float* wq = (const float*)d_in[19];
  const float* bq = (const float*)d_in[20];
  const float* wk = (const float*)d_in[21];
  const float* bk = (const float*)d_in[22];
  const float* wv = (const float*)d_in[23];
  const float* bv = (const float*)d_in[24];
  const float* wo = (const float*)d_in[25];
  const float* bo = (const float*)d_in[26];

  char* w = (char*)d_ws;
  unsigned short* geo_bf = (unsigned short*)(w);              // 1,179,648  [ow overlay]
  float*          enh_f  = (float*)(w + 1179648);             // 2,359,296
  unsigned short* enh_bf = (unsigned short*)(w + 3538944);    // 1,179,648
  unsigned short* qw_bf  = (unsigned short*)(w + 4718592);    // 1,179,648
  unsigned short* kw_bf  = (unsigned short*)(w + 5898240);    // 1,179,648
  unsigned short* vw_bf  = (unsigned short*)(w + 7077888);    // 1,179,648
  // gv OVERLAYS qw/kw/vw + hole: alive only between k_geo and k_geofin,
  // both strictly before k_qkv writes qw/kw/vw.  768*6*258*4 = 4,755,456 B
  // spans [4718592, 9474048) < cntw @ 9842688.
  float*          gv     = (float*)(w + 4718592);
  // gmean/xmean: alive only from k_mean to k_mlp (after gv is dead);
  // overlay the dead gv region tail [8257536, 8847360).
  float*          gmean  = (float*)(w + 8257536);             //   393,216
  unsigned short* xmean  = (unsigned short*)(w + 8650752);    //   196,608
  float*          cntw   = (float*)(w + 9842688);             //       512
  float*          comb   = (float*)(w + 9843200);             //   393,216
  short*          w2T    = (short*)(w + 10236416);            //   393,216
  short*          w2r    = (short*)(w + 10629632);            //   393,216
  short*          w1t    = (short*)(w + 11022848);            //    16,384
  short*          Gm     = (short*)(w + 11039232);            //   147,456 (fragment layout)
  float*          g1s    = (float*)(w + 11186688);            //       512
  float*          gscal  = (float*)(w + 11187200);            //       256
  short*          wqT    = (short*)(w + 11187456);            // 1,179,648
  short*          wkT    = (short*)(w + 12367104);            // 1,179,648
  short*          wvT    = (short*)(w + 13546752);            // 1,179,648
  short*          woT    = (short*)(w + 14726400);            // 1,179,648
  short*          agw1T  = (short*)(w + 15906048);            //   393,216
  short*          agw2T  = (short*)(w + 16299264);            //   393,216
  float*          pws    = (float*)(w + 16692480);            // 4,767,744 (optional)
  unsigned short* ow_bf  = geo_bf;
  const bool split_attn = (ws_size >= 21460224);

  hipLaunchKernelGGL(k_prep,    dim3(1520),  dim3(256), 0, stream,
                     ge_w2, ge_w1, wq, wk, wv, wo, ag_w1, ag_w2,
                     w2T, w2r, wqT, wkT, wvT, woT, w1t, agw1T, agw2T);
  hipLaunchKernelGGL(k_gprep,   dim3(66),    dim3(256), 0, stream,
                     w2r, ge_b2, w1t, ge_b1, Gm, gscal, g1s);
  hipLaunchKernelGGL(k_geo,     dim3(4608),  dim3(256), 0, stream,
                     coord, w1t, ge_b1, ge_g1, ge_be1, Gm, gscal, g1s, gv);
  hipLaunchKernelGGL(k_geofin,  dim3(768),   dim3(256), 0, stream,
                     gv, w2r, ge_b2, ge_g2, ge_be2, geo_bf);
  hipLaunchKernelGGL(k_mean,    dim3(128),   dim3(256), 0, stream,
                     lab, feat, geo_bf, cntw, xmean, gmean);
  hipLaunchKernelGGL(k_mlp,     dim3(8),     dim3(256), 0, stream,
                     xmean, gmean, agw1T, ag_b1, ag_g1, ag_be1,
                     agw2T, ag_b2, ag_g2, ag_be2, comb);
  hipLaunchKernelGGL(k_enhance, dim3(2304),  dim3(256), 0, stream,
                     feat, lab, cntw, comb, enh_f, enh_bf);
  hipLaunchKernelGGL(k_qkv,     dim3(432),   dim3(256), 0, stream,
                     enh_bf, geo_bf, wqT, wkT, wvT, bq, bk, bv, qw_bf, kw_bf, vw_bf);
  if (split_attn){
    hipLaunchKernelGGL(k_attn_split, dim3(384), dim3(256), 0, stream,
                       qw_bf, kw_bf, vw_bf, pws);
    hipLaunchKernelGGL(k_attnfin,    dim3(192), dim3(256), 0, stream,
                       pws, ow_bf);
  } else {
    hipLaunchKernelGGL(k_attn_full,  dim3(192), dim3(256), 0, stream,
                       qw_bf, kw_bf, vw_bf, ow_bf);
  }
  hipLaunchKernelGGL(k_out,     dim3(144),   dim3(256), 0, stream,
                     ow_bf, enh_f, woT, bo, (float*)d_out);
}

// Round 16
// 355.819 us; speedup vs baseline: 1.0670x; 1.0321x over previous
//
#include <hip/hip_runtime.h>
#include <hip/hip_bf16.h>
#include <stdint.h>
#include <stddef.h>

#define BB 2
#define NN 384
#define DD 768
#define HH 256
#define SS 64
#define NHH 8
#define DHH 96

typedef __attribute__((ext_vector_type(8))) short bf16x8;
typedef __attribute__((ext_vector_type(4))) float f32x4;

__device__ __forceinline__ float bits_f(unsigned short u){
  unsigned x = ((unsigned)u) << 16; float f; __builtin_memcpy(&f, &x, 4); return f;
}
__device__ __forceinline__ unsigned short f_bits(float a){
  unsigned x; __builtin_memcpy(&x, &a, 4);
  unsigned r = x + 0x7fffu + ((x >> 16) & 1u);
  return (unsigned short)(r >> 16);
}
__device__ __forceinline__ float lo_f(unsigned u){ unsigned x = u << 16; float f; __builtin_memcpy(&f,&x,4); return f; }
__device__ __forceinline__ float hi_f(unsigned u){ unsigned x = u & 0xffff0000u; float f; __builtin_memcpy(&f,&x,4); return f; }
// hardware RTNE pack: lo=bf16(a), hi=bf16(b) — same rounding as f_bits
__device__ __forceinline__ unsigned cvt_pk_bf16(float a, float b){
  unsigned r; asm("v_cvt_pk_bf16_f32 %0, %1, %2" : "=v"(r) : "v"(a), "v"(b));
  return r;
}

// ================= prep: all transposes (LDS-tiled, coalesced) =================
__global__ __launch_bounds__(256) void k_prep(
    const float* __restrict__ w2, const float* __restrict__ w1g,
    const float* __restrict__ wq, const float* __restrict__ wk,
    const float* __restrict__ wv, const float* __restrict__ wo,
    const float* __restrict__ aw1, const float* __restrict__ aw2,
    short* __restrict__ w2T, short* __restrict__ w2r,
    short* __restrict__ wqT, short* __restrict__ wkT, short* __restrict__ wvT,
    short* __restrict__ woT, short* __restrict__ w1t,
    short* __restrict__ agw1T, short* __restrict__ agw2T)
{
  __shared__ short tile[64*66];
  const int tid = threadIdx.x, blk = blockIdx.x;
  if (blk < 48){               // w2 [256,768] -> w2T [768,256]
    int t = blk;
    int r0 = (t/12)*64, c0 = (t%12)*64;
    int g = tid >> 6, c = tid & 63;
    #pragma unroll
    for (int i=0;i<16;++i){
      int r = i*4 + g;
      tile[r*66 + c] = (short)f_bits(w2[(size_t)(r0+r)*768 + c0 + c]);
    }
    __syncthreads();
    #pragma unroll
    for (int i=0;i<16;++i){
      int cc = i*4 + g, rr = c;
      w2T[(size_t)(c0+cc)*256 + r0 + rr] = tile[rr*66 + cc];
    }
    return;
  }
  if (blk < 816){              // w2r: row-major bf16 copy
    int idx = (blk-48)*256 + tid;
    w2r[idx] = (short)f_bits(w2[idx]);
    return;
  }
  if (blk < 1392){             // attn weights [768,768] -> T[n][k]
    int t = blk - 816;
    int mat = t / 144, tt = t % 144;
    const float* W = (mat==0)?wq:(mat==1)?wk:(mat==2)?wv:wo;
    short* T = (mat==0)?wqT:(mat==1)?wkT:(mat==2)?wvT:woT;
    int r0 = (tt/12)*64, c0 = (tt%12)*64;
    int g = tid >> 6, c = tid & 63;
    #pragma unroll
    for (int i=0;i<16;++i){
      int r = i*4 + g;
      tile[r*66 + c] = (short)f_bits(W[(size_t)(r0+r)*768 + c0 + c]);
    }
    __syncthreads();
    #pragma unroll
    for (int i=0;i<16;++i){
      int cc = i*4 + g, rr = c;
      T[(size_t)(c0+cc)*768 + r0 + rr] = tile[rr*66 + cc];
    }
    return;
  }
  if (blk < 1424){             // w1t [256c][32k], K padded
    int idx = (blk-1392)*256 + tid;
    int c = idx >> 5, kk = idx & 31;
    w1t[idx] = (kk < 9) ? (short)f_bits(w1g[kk*256 + c]) : (short)0;
    return;
  }
  if (blk < 1472){             // ag_w1 [768,256] -> agw1T [256n][768k]
    int t = blk - 1424;
    int r0 = (t/4)*64, c0 = (t%4)*64;
    int g = tid >> 6, c = tid & 63;
    #pragma unroll
    for (int i=0;i<16;++i){
      int r = i*4 + g;
      tile[r*66 + c] = (short)f_bits(aw1[(size_t)(r0+r)*256 + c0 + c]);
    }
    __syncthreads();
    #pragma unroll
    for (int i=0;i<16;++i){
      int cc = i*4 + g, rr = c;
      agw1T[(size_t)(c0+cc)*768 + r0 + rr] = tile[rr*66 + cc];
    }
    return;
  }
  {                            // ag_w2 [256,768] -> agw2T [768n][256k]
    int t = blk - 1472;
    int r0 = (t/12)*64, c0 = (t%12)*64;
    int g = tid >> 6, c = tid & 63;
    #pragma unroll
    for (int i=0;i<16;++i){
      int r = i*4 + g;
      tile[r*66 + c] = (short)f_bits(aw2[(size_t)(r0+r)*768 + c0 + c]);
    }
    __syncthreads();
    #pragma unroll
    for (int i=0;i<16;++i){
      int cc = i*4 + g, rr = c;
      agw2T[(size_t)(c0+cc)*256 + r0 + rr] = tile[rr*66 + cc];
    }
  }
}

// ================= Gram prep v2 — Gm written in MFMA-fragment layout =================
// GmF element (n,k): frag f = (n>>4)*8 + (k>>5); lane = ((k>>3)&3)*16 + (n&15); e = k&7
// index (shorts) = f*512 + lane*8 + e.  Consumers read one contiguous 1KB burst per frag.
__global__ __launch_bounds__(256) void k_gprep(const short* __restrict__ w2r,
                                               const float* __restrict__ b2,
                                               const short* __restrict__ w1t,
                                               const float* __restrict__ b1,
                                               short* __restrict__ Gm, float* __restrict__ gscal,
                                               float* __restrict__ g1s){
  __shared__ float b2s[768];
  __shared__ float red[8];
  const int tid = threadIdx.x, blk = blockIdx.x;
  if (blk < 64){
    const int wave = tid >> 6, lane = tid & 63, quad = lane >> 4, l16 = lane & 15;
    const int id = blk*4 + wave, ti = id >> 4, tj = id & 15;
    f32x4 acc = (f32x4){0.f,0.f,0.f,0.f};
    for (int ks = 0; ks < 24; ++ks){
      bf16x8 af = *(const bf16x8*)&w2r[(size_t)(ti*16 + l16)*768 + ks*32 + quad*8];
      bf16x8 bf = *(const bf16x8*)&w2r[(size_t)(tj*16 + l16)*768 + ks*32 + quad*8];
      acc = __builtin_amdgcn_mfma_f32_16x16x32_bf16(af, bf, acc, 0,0,0);
    }
    // value at (n = ti*16 + quad*4 + r, k = tj*16 + l16)
    {
      int k = tj*16 + l16;
      int fbase = ti*8 + (k >> 5);
      int ksub = ((k >> 3) & 3);
      int e = k & 7;
      #pragma unroll
      for (int r = 0; r < 4; ++r){
        int ln = ksub*16 + (quad*4 + r);
        Gm[fbase*512 + ln*8 + e] = (short)f_bits(acc[r]);
      }
    }
  } else if (blk == 64){
    for (int c = tid; c < 768; c += 256) b2s[c] = b2[c];
    __syncthreads();
    float sa = 0.f, wa = 0.f;
    const uint4* wr = (const uint4*)(w2r + (size_t)tid*768);
    #pragma unroll 4
    for (int kk = 0; kk < 96; ++kk){
      uint4 ww = wr[kk];
      const float* bp = &b2s[kk*8];
      float x0=lo_f(ww.x), x1=hi_f(ww.x), x2=lo_f(ww.y), x3=hi_f(ww.y);
      float x4=lo_f(ww.z), x5=hi_f(ww.z), x6=lo_f(ww.w), x7=hi_f(ww.w);
      sa += (x0+x1)+(x2+x3)+(x4+x5)+(x6+x7);
      wa += bp[0]*x0 + bp[1]*x1 + bp[2]*x2 + bp[3]*x3
          + bp[4]*x4 + bp[5]*x5 + bp[6]*x6 + bp[7]*x7;
    }
    // ext rows in fragment layout: n=256 (sa), n=257 (wa), n=258..287 zero; k = tid
    {
      int e = tid & 7;
      int ksub = (tid >> 3) & 3;
      int f16 = 128 + (tid >> 5);            // tile 16 fragments
      Gm[f16*512 + (ksub*16 + 0)*8 + e] = (short)f_bits(sa);   // n=256
      Gm[f16*512 + (ksub*16 + 1)*8 + e] = (short)f_bits(wa);   // n=257
      #pragma unroll
      for (int rr = 258; rr < 288; ++rr){
        int ff = (rr >> 4)*8 + (tid >> 5);
        int ln = ksub*16 + (rr & 15);
        Gm[ff*512 + ln*8 + e] = 0;
      }
    }
    float pb = 0.f, pbb = 0.f;
    for (int c = tid; c < 768; c += 256){ float bb = b2s[c]; pb += bb; pbb += bb*bb; }
    for (int m = 32; m >= 1; m >>= 1){ pb += __shfl_xor(pb,m); pbb += __shfl_xor(pbb,m); }
    if ((tid & 63) == 0){ red[tid>>6] = pb; red[4+(tid>>6)] = pbb; }
    __syncthreads();
    if (tid == 0){ gscal[0] = red[0]+red[1]+red[2]+red[3]; gscal[1] = red[4]+red[5]+red[6]+red[7]; }
  } else {
    const unsigned short* w1u = (const unsigned short*)w1t;
    if (tid < 81){
      int i = tid / 9, j = tid % 9;
      float acc = 0.f;
      for (int c = 0; c < 256; ++c)
        acc += bits_f(w1u[c*32 + i]) * bits_f(w1u[c*32 + j]);
      g1s[18 + tid] = acc;
    } else if (tid < 90){
      int i = tid - 81;
      float sa = 0.f, sb = 0.f;
      for (int c = 0; c < 256; ++c){
        float x = bits_f(w1u[c*32 + i]);
        sa += x; sb += x * b1[c];
      }
      g1s[i] = sa; g1s[9 + i] = sb;
    } else if (tid == 90){
      float pb = 0.f, pbb = 0.f;
      for (int c = 0; c < 256; ++c){ float bb = b1[c]; pb += bb; pbb += bb*bb; }
      g1s[99] = pb; g1s[100] = pbb;
    }
  }
}

// ================= geometric encoder; WG=(pair,jt), 256 thr, 3 WG/CU =================
// Gm consumed in fragment layout: per-(ci,ks) load = contiguous 1KB wave burst.
// Disjoint partials: gv[(pair*6+jt)*258 + {0..255:V, 256:R, 257:T}]
__global__ __launch_bounds__(256, 3) void k_geo(
    const float* __restrict__ coord, const short* __restrict__ w1t,
    const float* __restrict__ b1g, const float* __restrict__ g1g, const float* __restrict__ be1g,
    const short* __restrict__ Gm, const float* __restrict__ gscal,
    const float* __restrict__ g1s, float* __restrict__ gv)
{
  __shared__ short relbf[64*36];
  __shared__ short h_bf[64*256];   // chunk-swizzled: phys_chunk=((col>>3)+row)&31
  __shared__ float rmean[64], rrstd[64];
  __shared__ float msum[64], wbsum[64], qsum[64];

  const int tid = threadIdx.x;
  const int pair = blockIdx.x % 768;
  const int jt   = blockIdx.x / 768;
  const int j0 = jt * 64;
  const int b = pair / NN;

  if (tid < 64){
    int j = j0 + tid;
    float cix = coord[pair*3+0], ciy = coord[pair*3+1], ciz = coord[pair*3+2];
    float dx = cix - coord[(b*NN+j)*3+0];
    float dy = ciy - coord[(b*NN+j)*3+1];
    float dz = ciz - coord[(b*NN+j)*3+2];
    float dist = sqrtf(dx*dx + dy*dy + dz*dz);
    float inv = 1.f / fmaxf(dist, 1e-12f);
    float x = dx*inv, y = dy*inv, z = dz*inv;
    float rv[9];
    rv[0]=dist; rv[1]=x; rv[2]=y; rv[3]=z; rv[4]=0.f; rv[5]=0.f;
    rv[6]=y*z; rv[7]=x*y; rv[8]=x*z;
    short* rr = &relbf[tid*36];
    float rbf[9];
    #pragma unroll
    for (int k=0;k<9;++k){
      unsigned short hb = f_bits(rv[k]);
      rr[k] = (short)hb; rbf[k] = bits_f(hb);
    }
    #pragma unroll
    for (int k=9;k<32;++k) rr[k]=0;
    float s = g1s[99], ssq = g1s[100];
    #pragma unroll
    for (int i=0;i<9;++i){
      s += rbf[i]*g1s[i];
      ssq += 2.f*rbf[i]*g1s[9+i];
      #pragma unroll
      for (int jj=0;jj<9;++jj) ssq += rbf[i]*rbf[jj]*g1s[18+i*9+jj];
    }
    float mean = s*(1.f/256.f);
    float var  = ssq*(1.f/256.f) - mean*mean;
    rmean[tid] = mean; rrstd[tid] = rsqrtf(var + 1e-5f);
  } else if (tid < 128){
    qsum[tid-64] = 0.f;
  }
  __syncthreads();

  const int wave = tid >> 6, lane = tid & 63, quad = lane >> 4, l16 = lane & 15;

  // ---- phase 2: MFMA mm1 + in-register LN1/ReLU -> h_bf + hreg (packed bf16 pairs)
  unsigned hreg[4][4][2];   // [ci][rb][rpair]
  {
    bf16x8 af[4];
    #pragma unroll
    for (int rb=0;rb<4;++rb)
      af[rb] = *(const bf16x8*)&relbf[(rb*16 + l16)*36 + quad*8];
    f32x4 hacc[4][4];
    #pragma unroll
    for (int ci=0;ci<4;++ci){
      int cb = wave*4 + ci;
      bf16x8 bfw = *(const bf16x8*)&w1t[(cb*16 + l16)*32 + quad*8];
      #pragma unroll
      for (int rb=0;rb<4;++rb)
        hacc[ci][rb] = __builtin_amdgcn_mfma_f32_16x16x32_bf16(af[rb], bfw, (f32x4){0.f,0.f,0.f,0.f}, 0,0,0);
    }
    f32x4 rmv[4], rsv[4];
    #pragma unroll
    for (int rb=0;rb<4;++rb){
      rmv[rb] = *(const f32x4*)&rmean[rb*16 + quad*4];
      rsv[rb] = *(const f32x4*)&rrstd[rb*16 + quad*4];
    }
    #pragma unroll
    for (int ci=0;ci<4;++ci){
      int col = (wave*4+ci)*16 + l16;
      float b1c = b1g[col], g1c = g1g[col], be1c = be1g[col];
      int chb = col >> 3, lo = col & 7;
      #pragma unroll
      for (int rb=0;rb<4;++rb){
        float hn[4];
        #pragma unroll
        for (int r=0;r<4;++r)
          hn[r] = fmaxf((hacc[ci][rb][r] + b1c - rmv[rb][r]) * rsv[rb][r] * g1c + be1c, 0.f);
        unsigned p0 = cvt_pk_bf16(hn[0], hn[1]);
        unsigned p1 = cvt_pk_bf16(hn[2], hn[3]);
        hreg[ci][rb][0] = p0; hreg[ci][rb][1] = p1;
        int row0 = rb*16 + quad*4;
        h_bf[(row0+0)*256 + ((chb + row0+0)&31)*8 + lo] = (short)(p0 & 0xffff);
        h_bf[(row0+1)*256 + ((chb + row0+1)&31)*8 + lo] = (short)(p0 >> 16);
        h_bf[(row0+2)*256 + ((chb + row0+2)&31)*8 + lo] = (short)(p1 & 0xffff);
        h_bf[(row0+3)*256 + ((chb + row0+3)&31)*8 + lo] = (short)(p1 >> 16);
      }
    }
  }
  __syncthreads();

  // ---- phase 3: U = H@Gm_ext; wave0 ext tile -> msum/wbsum; Q from hreg
  {
    f32x4 acc[4][4];
    #pragma unroll
    for (int ci=0;ci<4;++ci)
      #pragma unroll
      for (int rb=0;rb<4;++rb) acc[ci][rb] = (f32x4){0.f,0.f,0.f,0.f};
    f32x4 eacc[4];
    #pragma unroll
    for (int rb=0;rb<4;++rb) eacc[rb] = (f32x4){0.f,0.f,0.f,0.f};
    for (int ks=0;ks<8;++ks){
      bf16x8 a4[4];
      #pragma unroll
      for (int rb=0;rb<4;++rb){
        int row = rb*16 + l16;
        a4[rb] = *(const bf16x8*)&h_bf[row*256 + (((ks*4 + quad) + row)&31)*8];
      }
      #pragma unroll
      for (int ci=0;ci<4;++ci){
        // fragment-contiguous B load: frag = (wave*4+ci)*8 + ks, per-lane 16B
        bf16x8 bg = *(const bf16x8*)&Gm[((wave*4+ci)*8 + ks)*512 + lane*8];
        #pragma unroll
        for (int rb=0;rb<4;++rb)
          acc[ci][rb] = __builtin_amdgcn_mfma_f32_16x16x32_bf16(a4[rb], bg, acc[ci][rb], 0,0,0);
      }
      if (wave == 0){
        bf16x8 bge = *(const bf16x8*)&Gm[(128 + ks)*512 + lane*8];
        #pragma unroll
        for (int rb=0;rb<4;++rb)
          eacc[rb] = __builtin_amdgcn_mfma_f32_16x16x32_bf16(a4[rb], bge, eacc[rb], 0,0,0);
      }
    }
    if (wave == 0 && l16 < 2){
      float* dst = (l16 == 0) ? msum : wbsum;
      #pragma unroll
      for (int rb=0;rb<4;++rb)
        #pragma unroll
        for (int r=0;r<4;++r) dst[rb*16 + quad*4 + r] = eacc[rb][r];
    }
    #pragma unroll
    for (int rb=0;rb<4;++rb){
      #pragma unroll
      for (int r=0;r<4;++r){
        int row = rb*16 + quad*4 + r;
        float qp = 0.f;
        #pragma unroll
        for (int ci=0;ci<4;++ci){
          unsigned p = hreg[ci][rb][r>>1];
          float hv = (r & 1) ? hi_f(p) : lo_f(p);
          qp += acc[ci][rb][r] * hv;
        }
        qp += __shfl_xor(qp,1);
        qp += __shfl_xor(qp,2);
        qp += __shfl_xor(qp,4);
        qp += __shfl_xor(qp,8);
        if (l16 == 0) atomicAdd(&qsum[row], qp);
      }
    }
  }
  __syncthreads();
  if (tid < 64){
    float Sb = gscal[0], Sbb = gscal[1];
    float m2 = (msum[tid] + Sb)*(1.f/768.f);
    float ssq = qsum[tid] + 2.f*wbsum[tid] + Sbb;
    float var = ssq*(1.f/768.f) - m2*m2;
    rmean[tid] = m2; rrstd[tid] = rsqrtf(var + 1e-5f);
  }
  __syncthreads();
  float* gp = gv + ((size_t)pair*6 + jt)*258;
  if (tid < 64){
    float rr = rrstd[tid], tt = rmean[tid]*rrstd[tid];
    for (int m = 32; m >= 1; m >>= 1){ rr += __shfl_xor(rr,m); tt += __shfl_xor(tt,m); }
    if (tid == 0){ gp[256] = rr; gp[257] = tt; }
  }
  // ---- V = sum_j rstd_j h_j : from hreg; quad-reduce via shfl; coalesced stores
  {
    float vp[4] = {0.f, 0.f, 0.f, 0.f};
    #pragma unroll
    for (int rb=0;rb<4;++rb){
      #pragma unroll
      for (int r=0;r<4;++r){
        int row = rb*16 + quad*4 + r;
        float rs = rrstd[row];
        #pragma unroll
        for (int ci=0;ci<4;++ci){
          unsigned p = hreg[ci][rb][r>>1];
          float hv = (r & 1) ? hi_f(p) : lo_f(p);
          vp[ci] += rs * hv;
        }
      }
    }
    #pragma unroll
    for (int ci=0;ci<4;++ci){
      vp[ci] += __shfl_xor(vp[ci],16);
      vp[ci] += __shfl_xor(vp[ci],32);
    }
    if (quad == 0){
      #pragma unroll
      for (int ci=0;ci<4;++ci)
        gp[(wave*4+ci)*16 + l16] = vp[ci];
    }
  }
}

// ================= finalize geo: reduce 6 partials + LN2(V@W2) =================
__global__ __launch_bounds__(256) void k_geofin(
    const float* __restrict__ gv, const short* __restrict__ w2r,
    const float* __restrict__ b2g, const float* __restrict__ g2g,
    const float* __restrict__ be2g, unsigned short* __restrict__ geo)
{
  __shared__ float V[256];
  __shared__ float RT[2];
  const int tid = threadIdx.x, pair = blockIdx.x;
  const float* gp = gv + (size_t)pair*6*258;
  V[tid] = gp[tid] + gp[258 + tid] + gp[2*258 + tid]
         + gp[3*258 + tid] + gp[4*258 + tid] + gp[5*258 + tid];
  if (tid < 2){
    float r = 0.f;
    #pragma unroll
    for (int t = 0; t < 6; ++t) r += gp[t*258 + 256 + tid];
    RT[tid] = r;
  }
  __syncthreads();
  const float R = RT[0], T = RT[1];
  const unsigned short* wr = (const unsigned short*)w2r;
  float a0 = 0.f, a1 = 0.f, a2 = 0.f;
  #pragma unroll 4
  for (int k = 0; k < 256; ++k){
    float vk = V[k];
    const unsigned short* row = wr + (size_t)k*768;
    a0 += vk * bits_f(row[tid]);
    a1 += vk * bits_f(row[tid+256]);
    a2 += vk * bits_f(row[tid+512]);
  }
  size_t base = (size_t)pair*DD;
  geo[base + tid]       = f_bits(g2g[tid]    *(a0 + b2g[tid]    *R - T)*(1.f/384.f) + be2g[tid]);
  geo[base + tid + 256] = f_bits(g2g[tid+256]*(a1 + b2g[tid+256]*R - T)*(1.f/384.f) + be2g[tid+256]);
  geo[base + tid + 512] = f_bits(g2g[tid+512]*(a2 + b2g[tid+512]*R - T)*(1.f/384.f) + be2g[tid+512]);
}

// ================= superpoint means: parallel list-build + 2-deep gather (grid=128) =================
__global__ __launch_bounds__(256) void k_mean(
    const int* __restrict__ lab, const float* __restrict__ feat,
    const unsigned short* __restrict__ geo, float* __restrict__ cntw,
    unsigned short* __restrict__ xmean, float* __restrict__ gmean)
{
  __shared__ int ls[NN];
  __shared__ int ent[NN];
  __shared__ int cnt_s;
  const int tid = threadIdx.x;
  const int bs = blockIdx.x, b = bs >> 6, s = bs & 63;
  if (tid == 0) cnt_s = 0;
  for (int j = tid; j < NN; j += 256) ls[j] = lab[b*NN + j];
  __syncthreads();
  for (int j = tid; j < NN; j += 256){
    if (ls[j] == s){
      int p = atomicAdd(&cnt_s, 1);
      ent[p] = j;
    }
  }
  __syncthreads();
  const int cnt = cnt_s;
  float f0=0.f, f1=0.f, f2=0.f, g0=0.f, g1=0.f, g2=0.f;
  int idx = 0;
  for (; idx + 1 < cnt; idx += 2){
    size_t ra = (size_t)(b*NN + ent[idx])*DD;
    size_t rb = (size_t)(b*NN + ent[idx+1])*DD;
    float a0 = feat[ra+tid], a1 = feat[ra+tid+256], a2 = feat[ra+tid+512];
    float b0 = feat[rb+tid], b1v = feat[rb+tid+256], b2 = feat[rb+tid+512];
    float ga0 = bits_f(geo[ra+tid]), ga1 = bits_f(geo[ra+tid+256]), ga2 = bits_f(geo[ra+tid+512]);
    float gb0 = bits_f(geo[rb+tid]), gb1 = bits_f(geo[rb+tid+256]), gb2 = bits_f(geo[rb+tid+512]);
    f0 += a0 + b0; f1 += a1 + b1v; f2 += a2 + b2;
    g0 += ga0 + gb0; g1 += ga1 + gb1; g2 += ga2 + gb2;
  }
  if (idx < cnt){
    size_t ra = (size_t)(b*NN + ent[idx])*DD;
    f0 += feat[ra+tid]; f1 += feat[ra+tid+256]; f2 += feat[ra+tid+512];
    g0 += bits_f(geo[ra+tid]); g1 += bits_f(geo[ra+tid+256]); g2 += bits_f(geo[ra+tid+512]);
  }
  const float inv = 1.f / fmaxf((float)cnt, 1.f);
  if (tid == 0) cntw[bs] = (float)cnt;
  size_t base = (size_t)bs * DD;
  xmean[base + tid]       = f_bits(f0*inv);
  xmean[base + tid + 256] = f_bits(f1*inv);
  xmean[base + tid + 512] = f_bits(f2*inv);
  gmean[base + tid]       = g0*inv;
  gmean[base + tid + 256] = g1*inv;
  gmean[base + tid + 512] = g2*inv;
}

// ================= aggregator MLP via MFMA (grid=8, 16 rows/block) =================
__global__ __launch_bounds__(256) void k_mlp(
    const unsigned short* __restrict__ xmean, const float* __restrict__ gmean,
    const short* __restrict__ w1T, const float* __restrict__ b1g,
    const float* __restrict__ g1g, const float* __restrict__ be1g,
    const short* __restrict__ w2T, const float* __restrict__ b2g,
    const float* __restrict__ g2g, const float* __restrict__ be2g,
    float* __restrict__ comb)
{
  __shared__ short hA[16*264];     // bf16 hidden, padded stride
  __shared__ float rsum[16], rsq[16], rmean[16], rrstd[16];
  const int tid = threadIdx.x;
  const int wave = tid >> 6, lane = tid & 63, quad = lane >> 4, l16 = lane & 15;
  const int bs0 = blockIdx.x * 16;
  if (tid < 16){ rsum[tid] = 0.f; rsq[tid] = 0.f; }
  __syncthreads();

  // ---- layer 1: [16x768] @ agw1T[256n][768k] -> 16x256, LN1+ReLU -> hA
  f32x4 acc[4];
  #pragma unroll
  for (int cb=0;cb<4;++cb) acc[cb] = (f32x4){0.f,0.f,0.f,0.f};
  for (int ks = 0; ks < 24; ++ks){
    bf16x8 af = *(const bf16x8*)&((const short*)xmean)[(size_t)(bs0 + l16)*DD + ks*32 + quad*8];
    #pragma unroll
    for (int cb=0;cb<4;++cb){
      bf16x8 bw = *(const bf16x8*)&w1T[(size_t)(wave*64 + cb*16 + l16)*768 + ks*32 + quad*8];
      acc[cb] = __builtin_amdgcn_mfma_f32_16x16x32_bf16(af, bw, acc[cb], 0,0,0);
    }
  }
  {
    float ps[4] = {0.f,0.f,0.f,0.f}, pq[4] = {0.f,0.f,0.f,0.f};
    #pragma unroll
    for (int cb=0;cb<4;++cb){
      int col = wave*64 + cb*16 + l16;
      float b1c = b1g[col];
      #pragma unroll
      for (int r=0;r<4;++r){
        float v = acc[cb][r] + b1c;
        acc[cb][r] = v;
        ps[r] += v; pq[r] += v*v;
      }
    }
    #pragma unroll
    for (int r=0;r<4;++r){
      ps[r] += __shfl_xor(ps[r],1); pq[r] += __shfl_xor(pq[r],1);
      ps[r] += __shfl_xor(ps[r],2); pq[r] += __shfl_xor(pq[r],2);
      ps[r] += __shfl_xor(ps[r],4); pq[r] += __shfl_xor(pq[r],4);
      ps[r] += __shfl_xor(ps[r],8); pq[r] += __shfl_xor(pq[r],8);
      if (l16 == 0){ atomicAdd(&rsum[quad*4+r], ps[r]); atomicAdd(&rsq[quad*4+r], pq[r]); }
    }
  }
  __syncthreads();
  if (tid < 16){
    float mean = rsum[tid]*(1.f/HH);
    float var  = rsq[tid]*(1.f/HH) - mean*mean;
    rmean[tid] = mean; rrstd[tid] = rsqrtf(var + 1e-5f);
    rsum[tid] = 0.f; rsq[tid] = 0.f;     // re-zero for LN2
  }
  __syncthreads();
  #pragma unroll
  for (int cb=0;cb<4;++cb){
    int col = wave*64 + cb*16 + l16;
    float g1c = g1g[col], be1c = be1g[col];
    #pragma unroll
    for (int r=0;r<4;++r){
      int row = quad*4 + r;
      float h = fmaxf((acc[cb][r]-rmean[row])*rrstd[row]*g1c + be1c, 0.f);
      hA[row*264 + col] = (short)f_bits(h);
    }
  }
  __syncthreads();

  // ---- layer 2: [16x256] @ agw2T[768n][256k] -> 16x768, LN2 -> comb (+gmean)
  f32x4 acc2[12];
  #pragma unroll
  for (int cb=0;cb<12;++cb) acc2[cb] = (f32x4){0.f,0.f,0.f,0.f};
  for (int ks = 0; ks < 8; ++ks){
    bf16x8 af = *(const bf16x8*)&hA[l16*264 + ks*32 + quad*8];
    #pragma unroll
    for (int cb=0;cb<12;++cb){
      bf16x8 bw = *(const bf16x8*)&w2T[(size_t)(wave*192 + cb*16 + l16)*256 + ks*32 + quad*8];
      acc2[cb] = __builtin_amdgcn_mfma_f32_16x16x32_bf16(af, bw, acc2[cb], 0,0,0);
    }
  }
  {
    float ps[4] = {0.f,0.f,0.f,0.f}, pq[4] = {0.f,0.f,0.f,0.f};
    #pragma unroll
    for (int cb=0;cb<12;++cb){
      int col = wave*192 + cb*16 + l16;
      float b2c = b2g[col];
      #pragma unroll
      for (int r=0;r<4;++r){
        float v = acc2[cb][r] + b2c;
        acc2[cb][r] = v;
        ps[r] += v; pq[r] += v*v;
      }
    }
    #pragma unroll
    for (int r=0;r<4;++r){
      ps[r] += __shfl_xor(ps[r],1); pq[r] += __shfl_xor(pq[r],1);
      ps[r] += __shfl_xor(ps[r],2); pq[r] += __shfl_xor(pq[r],2);
      ps[r] += __shfl_xor(ps[r],4); pq[r] += __shfl_xor(pq[r],4);
      ps[r] += __shfl_xor(ps[r],8); pq[r] += __shfl_xor(pq[r],8);
      if (l16 == 0){ atomicAdd(&rsum[quad*4+r], ps[r]); atomicAdd(&rsq[quad*4+r], pq[r]); }
    }
  }
  __syncthreads();
  if (tid < 16){
    float mean = rsum[tid]*(1.f/DD);
    float var  = rsq[tid]*(1.f/DD) - mean*mean;
    rmean[tid] = mean; rrstd[tid] = rsqrtf(var + 1e-5f);
  }
  __syncthreads();
  #pragma unroll
  for (int cb=0;cb<12;++cb){
    int col = wave*192 + cb*16 + l16;
    float g2c = g2g[col], be2c = be2g[col];
    #pragma unroll
    for (int r=0;r<4;++r){
      int row = quad*4 + r;
      size_t idx = (size_t)(bs0+row)*DD + col;
      comb[idx] = (acc2[cb][r]-rmean[row])*rrstd[row]*g2c + be2c + gmean[idx];
    }
  }
}

// ================= gather + enhanced =================
__global__ void k_enhance(const float* __restrict__ feat, const int* __restrict__ lab,
                          const float* __restrict__ cntw, const float* __restrict__ comb,
                          float* __restrict__ enh, unsigned short* __restrict__ enhb)
{
  int idx = blockIdx.x * 256 + threadIdx.x;
  int c = idx % DD; int bn = idx / DD; int b = bn / NN;
  int l = lab[bn];
  float f = feat[idx];
  float cg = comb[(size_t)(b*SS + l)*DD + c];
  float cnt = cntw[b*SS + l];
  float e = (cnt >= 2.0f) ? (0.7f*f + 0.3f*cg) : f;
  enh[idx] = e;
  enhb[idx] = f_bits(e);
}

// ================= q/k/v projections via MFMA (16-row tiles, 432 blocks) =================
__global__ __launch_bounds__(256, 4) void k_qkv(
    const unsigned short* __restrict__ enhb, const unsigned short* __restrict__ geo,
    const short* __restrict__ wqT, const short* __restrict__ wkT, const short* __restrict__ wvT,
    const float* __restrict__ bq, const float* __restrict__ bk, const float* __restrict__ bv,
    unsigned short* __restrict__ qo, unsigned short* __restrict__ ko, unsigned short* __restrict__ vo)
{
  const int tid = threadIdx.x, blk = blockIdx.x;   // 432 = 3 mats * 48 rt * 3 ct
  const int m = blk / 144, rem = blk % 144;
  const int rt = rem / 3, ct = rem % 3;
  const int wave = tid >> 6, lane = tid & 63, quad = lane >> 4, l16 = lane & 15;
  const short* WT = (m==0)?wqT:(m==1)?wkT:wvT;
  const float* Bv = (m==0)?bq:(m==1)?bk:bv;
  unsigned short* Y = (m==0)?qo:(m==1)?ko:vo;
  const short* X = (const short*)((m==0)? enhb : geo);
  const float oscale = (m==0)? 0.10206207261596577f : 1.0f;
  const int row0 = rt*16;
  const int col0 = ct*256 + wave*64;

  f32x4 acc[4];
  #pragma unroll
  for (int cb=0;cb<4;++cb) acc[cb] = (f32x4){0.f,0.f,0.f,0.f};
  for (int ks = 0; ks < 24; ++ks){
    bf16x8 af = *(const bf16x8*)&X[(size_t)(row0 + l16)*DD + ks*32 + quad*8];
    #pragma unroll
    for (int cb=0;cb<4;++cb){
      bf16x8 bw = *(const bf16x8*)&WT[(size_t)(col0 + cb*16 + l16)*DD + ks*32 + quad*8];
      acc[cb] = __builtin_amdgcn_mfma_f32_16x16x32_bf16(af, bw, acc[cb], 0,0,0);
    }
  }
  #pragma unroll
  for (int cb=0;cb<4;++cb){
    int col = col0 + cb*16 + l16;
    float bb = Bv[col];
    #pragma unroll
    for (int r=0;r<4;++r){
      int row = row0 + quad*4 + r;
      Y[(size_t)row*DD + col] = f_bits((acc[cb][r] + bb)*oscale);
    }
  }
}

// ================= attention: split over jt halves; QK^T via MFMA =================
__global__ __launch_bounds__(256) void k_attn_split(
    const unsigned short* __restrict__ qws, const unsigned short* __restrict__ kws,
    const unsigned short* __restrict__ vws, float* __restrict__ pws)
{
  __shared__ short kt[64*104];
  __shared__ short vt[64*104];
  __shared__ float st[32*66];
  __shared__ float lsum[32];
  const int tid = threadIdx.x;
  const int half = blockIdx.x / 192;
  const int inner = blockIdx.x % 192;
  const int b = inner / (NHH*12); int rem = inner % (NHH*12);
  const int h = rem / 12; const int qt = rem % 12; const int q0 = qt*32;
  const int wave = tid >> 6, lane = tid & 63, quad = lane >> 4, l16 = lane & 15;
  const int qp = tid >> 4, dp = tid & 15;

  // Q A-fragments (jt-invariant): mt in {0,1} row-tiles, ks in {0,1,2} k-steps.
  // A-frag (verified in k_gprep): lane holds row = l16, k = ks*32 + quad*8 .. +7
  bf16x8 aq0_0, aq0_1, aq0_2, aq1_0, aq1_1, aq1_2;
  {
    const short* qb = (const short*)qws;
    size_t r0 = (size_t)(b*NN + q0 + l16)*DD + h*DHH;
    size_t r1 = (size_t)(b*NN + q0 + 16 + l16)*DD + h*DHH;
    aq0_0 = *(const bf16x8*)&qb[r0 + 0*32 + quad*8];
    aq0_1 = *(const bf16x8*)&qb[r0 + 1*32 + quad*8];
    aq0_2 = *(const bf16x8*)&qb[r0 + 2*32 + quad*8];
    aq1_0 = *(const bf16x8*)&qb[r1 + 0*32 + quad*8];
    aq1_1 = *(const bf16x8*)&qb[r1 + 1*32 + quad*8];
    aq1_2 = *(const bf16x8*)&qb[r1 + 2*32 + quad*8];
  }
  if (tid < 32) lsum[tid] = 0.f;
  float Oacc[2][6];
  #pragma unroll
  for (int a = 0; a < 2; ++a)
    #pragma unroll
    for (int m = 0; m < 6; ++m) Oacc[a][m] = 0.f;

  for (int jt = half*3; jt < half*3 + 3; ++jt){
    const int j0 = jt * 64;
    __syncthreads();
    for (int x = tid; x < 64*48; x += 256){
      int jl = x / 48, du = x % 48;
      size_t rowoff = (size_t)(b*NN + j0 + jl)*DD + h*DHH;
      ((unsigned*)&kt[jl*104])[du] = ((const unsigned*)(kws + rowoff))[du];
      ((unsigned*)&vt[jl*104])[du] = ((const unsigned*)(vws + rowoff))[du];
    }
    __syncthreads();
    // ---- S = Q @ K^T via MFMA: wave owns j-tile = wave (j = wave*16 + l16)
    {
      f32x4 sacc0 = (f32x4){0.f,0.f,0.f,0.f};
      f32x4 sacc1 = (f32x4){0.f,0.f,0.f,0.f};
      {
        bf16x8 bk0 = *(const bf16x8*)&kt[(wave*16 + l16)*104 + 0*32 + quad*8];
        sacc0 = __builtin_amdgcn_mfma_f32_16x16x32_bf16(aq0_0, bk0, sacc0, 0,0,0);
        sacc1 = __builtin_amdgcn_mfma_f32_16x16x32_bf16(aq1_0, bk0, sacc1, 0,0,0);
        bf16x8 bk1 = *(const bf16x8*)&kt[(wave*16 + l16)*104 + 1*32 + quad*8];
        sacc0 = __builtin_amdgcn_mfma_f32_16x16x32_bf16(aq0_1, bk1, sacc0, 0,0,0);
        sacc1 = __builtin_amdgcn_mfma_f32_16x16x32_bf16(aq1_1, bk1, sacc1, 0,0,0);
        bf16x8 bk2 = *(const bf16x8*)&kt[(wave*16 + l16)*104 + 2*32 + quad*8];
        sacc0 = __builtin_amdgcn_mfma_f32_16x16x32_bf16(aq0_2, bk2, sacc0, 0,0,0);
        sacc1 = __builtin_amdgcn_mfma_f32_16x16x32_bf16(aq1_2, bk2, sacc1, 0,0,0);
      }
      // C-layout: row q = mt*16 + quad*4 + r, col j = wave*16 + l16
      int j = wave*16 + l16;
      #pragma unroll
      for (int r = 0; r < 4; ++r){
        int q = quad*4 + r;
        float p = __expf(sacc0[r]);
        st[q*66 + j] = p;
        float pr = p;
        pr += __shfl_xor(pr,1);
        pr += __shfl_xor(pr,2);
        pr += __shfl_xor(pr,4);
        pr += __shfl_xor(pr,8);
        if (l16 == 0) atomicAdd(&lsum[q], pr);
      }
      #pragma unroll
      for (int r = 0; r < 4; ++r){
        int q = 16 + quad*4 + r;
        float p = __expf(sacc1[r]);
        st[q*66 + j] = p;
        float pr = p;
        pr += __shfl_xor(pr,1);
        pr += __shfl_xor(pr,2);
        pr += __shfl_xor(pr,4);
        pr += __shfl_xor(pr,8);
        if (l16 == 0) atomicAdd(&lsum[q], pr);
      }
    }
    __syncthreads();
    #pragma unroll 4
    for (int j = 0; j < 64; ++j){
      float p0 = st[(2*qp)*66 + j];
      float p1 = st[(2*qp+1)*66 + j];
      const unsigned* vr = (const unsigned*)&vt[j*104 + dp*6];
      #pragma unroll
      for (int m = 0; m < 3; ++m){
        unsigned vv = vr[m];
        float v0 = lo_f(vv), v1 = hi_f(vv);
        Oacc[0][2*m]   += p0*v0; Oacc[0][2*m+1] += p0*v1;
        Oacc[1][2*m]   += p1*v0; Oacc[1][2*m+1] += p1*v1;
      }
    }
  }
  __syncthreads();
  float* pb = pws + ((size_t)inner*2 + half)*3104;
  #pragma unroll
  for (int m = 0; m < 6; ++m){
    pb[(2*qp)*96 + dp*6 + m]   = Oacc[0][m];
    pb[(2*qp+1)*96 + dp*6 + m] = Oacc[1][m];
  }
  if (tid < 32) pb[3072 + tid] = lsum[tid];
}

// ================= attention finalize =================
__global__ __launch_bounds__(256) void k_attnfin(
    const float* __restrict__ pws, unsigned short* __restrict__ ows)
{
  __shared__ float ls[32];
  const int tid = threadIdx.x, inner = blockIdx.x;
  const int b = inner / (NHH*12); int rem = inner % (NHH*12);
  const int h = rem / 12; const int qt = rem % 12; const int q0 = qt*32;
  const float* p0 = pws + (size_t)inner*2*3104;
  const float* p1 = p0 + 3104;
  if (tid < 32) ls[tid] = 1.f / (p0[3072+tid] + p1[3072+tid]);
  __syncthreads();
  #pragma unroll
  for (int u = 0; u < 12; ++u){
    int e = tid + u*256;
    int q = e / 96, d = e % 96;
    float o = (p0[e] + p1[e]) * ls[q];
    ows[(size_t)(b*NN + q0 + q)*DD + h*DHH + d] = f_bits(o);
  }
}

// ================= attention fallback (single-pass) =================
__global__ __launch_bounds__(256) void k_attn_full(
    const unsigned short* __restrict__ qws, const unsigned short* __restrict__ kws,
    const unsigned short* __restrict__ vws, unsigned short* __restrict__ ows)
{
  __shared__ short kt[64*104];
  __shared__ short vt[64*104];
  __shared__ float st[32*66];
  __shared__ float lsum[32];
  const int tid = threadIdx.x;
  const int blk = blockIdx.x;
  const int b = blk / (NHH*12); int rem = blk % (NHH*12);
  const int h = rem / 12; const int qt = rem % 12; const int q0 = qt*32;
  const int sq = tid >> 3, jp = tid & 7;
  const int qp = tid >> 4, dp = tid & 15;
  unsigned qreg[48];
  {
    const unsigned* qr = (const unsigned*)(qws + (size_t)(b*NN + q0 + sq)*DD + h*DHH);
    #pragma unroll
    for (int d2 = 0; d2 < 48; ++d2) qreg[d2] = qr[d2];
  }
  if (tid < 32) lsum[tid] = 0.f;
  float Oacc[2][6];
  #pragma unroll
  for (int a = 0; a < 2; ++a)
    #pragma unroll
    for (int m = 0; m < 6; ++m) Oacc[a][m] = 0.f;
  for (int jt = 0; jt < 6; ++jt){
    const int j0 = jt * 64;
    __syncthreads();
    for (int x = tid; x < 64*48; x += 256){
      int jl = x / 48, du = x % 48;
      size_t rowoff = (size_t)(b*NN + j0 + jl)*DD + h*DHH;
      ((unsigned*)&kt[jl*104])[du] = ((const unsigned*)(kws + rowoff))[du];
      ((unsigned*)&vt[jl*104])[du] = ((const unsigned*)(vws + rowoff))[du];
    }
    __syncthreads();
    float lpart = 0.f;
    #pragma unroll
    for (int jj = 0; jj < 8; ++jj){
      int j = jp*8 + jj;
      const uint4* kr4 = (const uint4*)&kt[j*104];
      float s = 0.f;
      #pragma unroll
      for (int d4 = 0; d4 < 12; ++d4){
        uint4 kk = kr4[d4];
        unsigned q0r = qreg[4*d4], q1r = qreg[4*d4+1], q2r = qreg[4*d4+2], q3r = qreg[4*d4+3];
        s += lo_f(kk.x)*lo_f(q0r) + hi_f(kk.x)*hi_f(q0r);
        s += lo_f(kk.y)*lo_f(q1r) + hi_f(kk.y)*hi_f(q1r);
        s += lo_f(kk.z)*lo_f(q2r) + hi_f(kk.z)*hi_f(q2r);
        s += lo_f(kk.w)*lo_f(q3r) + hi_f(kk.w)*hi_f(q3r);
      }
      float p = __expf(s);
      st[sq*66 + j] = p;
      lpart += p;
    }
    lpart += __shfl_xor(lpart,1);
    lpart += __shfl_xor(lpart,2);
    lpart += __shfl_xor(lpart,4);
    if (jp == 0) lsum[sq] += lpart;
    __syncthreads();
    #pragma unroll 4
    for (int j = 0; j < 64; ++j){
      float p0 = st[(2*qp)*66 + j];
      float p1 = st[(2*qp+1)*66 + j];
      const unsigned* vr = (const unsigned*)&vt[j*104 + dp*6];
      #pragma unroll
      for (int m = 0; m < 3; ++m){
        unsigned vv = vr[m];
        float v0 = lo_f(vv), v1 = hi_f(vv);
        Oacc[0][2*m]   += p0*v0; Oacc[0][2*m+1] += p0*v1;
        Oacc[1][2*m]   += p1*v0; Oacc[1][2*m+1] += p1*v1;
      }
    }
  }
  __syncthreads();
  float l0 = 1.f / lsum[2*qp], l1 = 1.f / lsum[2*qp+1];
  size_t ob = (size_t)(b*NN + q0)*DD + h*DHH + dp*6;
  #pragma unroll
  for (int m = 0; m < 6; ++m){
    ows[ob + (size_t)(2*qp)*DD + m]   = f_bits(Oacc[0][m]*l0);
    ows[ob + (size_t)(2*qp+1)*DD + m] = f_bits(Oacc[1][m]*l1);
  }
}

// ================= output projection via MFMA (16-row tiles, 144 blocks) =================
__global__ __launch_bounds__(256, 4) void k_out(
    const unsigned short* __restrict__ ows, const float* __restrict__ enh,
    const short* __restrict__ woT, const float* __restrict__ bo, float* __restrict__ out)
{
  const int tid = threadIdx.x, blk = blockIdx.x;   // 144 = 48 rt * 3 ct
  const int rt = blk / 3, ct = blk % 3;
  const int wave = tid >> 6, lane = tid & 63, quad = lane >> 4, l16 = lane & 15;
  const int row0 = rt*16;
  const int col0 = ct*256 + wave*64;
  f32x4 acc[4];
  #pragma unroll
  for (int cb=0;cb<4;++cb) acc[cb] = (f32x4){0.f,0.f,0.f,0.f};
  for (int ks = 0; ks < 24; ++ks){
    bf16x8 af = *(const bf16x8*)&((const short*)ows)[(size_t)(row0 + l16)*DD + ks*32 + quad*8];
    #pragma unroll
    for (int cb=0;cb<4;++cb){
      bf16x8 bw = *(const bf16x8*)&woT[(size_t)(col0 + cb*16 + l16)*DD + ks*32 + quad*8];
      acc[cb] = __builtin_amdgcn_mfma_f32_16x16x32_bf16(af, bw, acc[cb], 0,0,0);
    }
  }
  #pragma unroll
  for (int cb=0;cb<4;++cb){
    int col = col0 + cb*16 + l16;
    float bb = bo[col];
    #pragma unroll
    for (int r=0;r<4;++r){
      size_t idx = (size_t)(row0 + quad*4 + r)*DD + col;
      out[idx] = enh[idx] + 0.5f*(acc[cb][r] + bb);
    }
  }
}

extern "C" void kernel_launch(void* const* d_in, const int* in_sizes, int n_in,
                              void* d_out, int out_size, void* d_ws, size_t ws_size,
                              hipStream_t stream) {
  const float* coord = (const float*)d_in[0];
  const float* feat  = (const float*)d_in[1];
  const int*   lab   = (const int*)d_in[2];
  const float* ge_w1 = (const float*)d_in[3];
  const float* ge_b1 = (const float*)d_in[4];
  const float* ge_g1 = (const float*)d_in[5];
  const float* ge_be1= (const float*)d_in[6];
  const float* ge_w2 = (const float*)d_in[7];
  const float* ge_b2 = (const float*)d_in[8];
  const float* ge_g2 = (const float*)d_in[9];
  const float* ge_be2= (const float*)d_in[10];
  const float* ag_w1 = (const float*)d_in[11];
  const float* ag_b1 = (const float*)d_in[12];
  const float* ag_g1 = (const float*)d_in[13];
  const float* ag_be1= (const float*)d_in[14];
  const float* ag_w2 = (const float*)d_in[15];
  const float* ag_b2 = (const float*)d_in[16];
  const float* ag_g2 = (const float*)d_in[17];
  const float* ag_be2= (const float*)d_in[18];
  const float* wq = (const float*)d_in[19];
  const float* bq = (const float*)d_in[20];
  const float* wk = (const float*)d_in[21];
  const float* bk = (const float*)d_in[22];
  const float* wv = (const float*)d_in[23];
  const float* bv = (const float*)d_in[24];
  const float* wo = (const float*)d_in[25];
  const float* bo = (const float*)d_in[26];

  char* w = (char*)d_ws;
  unsigned short* geo_bf = (unsigned short*)(w);              // 1,179,648  [ow overlay]
  float*          enh_f  = (float*)(w + 1179648);             // 2,359,296
  unsigned short* enh_bf = (unsigned short*)(w + 3538944);    // 1,179,648
  unsigned short* qw_bf  = (unsigned short*)(w + 4718592);    // 1,179,648
  unsigned short* kw_bf  = (unsigned short*)(w + 5898240);    // 1,179,648
  unsigned short* vw_bf  = (unsigned short*)(w + 7077888);    // 1,179,648
  // gv OVERLAYS qw/kw/vw + hole: alive only between k_geo and k_geofin,
  // both strictly before k_qkv writes qw/kw/vw.  768*6*258*4 = 4,755,456 B
  // spans [4718592, 9474048) < cntw @ 9842688.
  float*          gv     = (float*)(w + 4718592);
  // gmean/xmean: alive only from k_mean to k_mlp (after gv is dead);
  // overlay the dead gv region tail [8257536, 8847360).
  float*          gmean  = (float*)(w + 8257536);             //   393,216
  unsigned short* xmean  = (unsigned short*)(w + 8650752);    //   196,608
  float*          cntw   = (float*)(w + 9842688);             //       512
  float*          comb   = (float*)(w + 9843200);             //   393,216
  short*          w2T    = (short*)(w + 10236416);            //   393,216
  short*          w2r    = (short*)(w + 10629632);            //   393,216
  short*          w1t    = (short*)(w + 11022848);            //    16,384
  short*          Gm     = (short*)(w + 11039232);            //   147,456 (fragment layout)
  float*          g1s    = (float*)(w + 11186688);            //       512
  float*          gscal  = (float*)(w + 11187200);            //       256
  short*          wqT    = (short*)(w + 11187456);            // 1,179,648
  short*          wkT    = (short*)(w + 12367104);            // 1,179,648
  short*          wvT    = (short*)(w + 13546752);            // 1,179,648
  short*          woT    = (short*)(w + 14726400);            // 1,179,648
  short*          agw1T  = (short*)(w + 15906048);            //   393,216
  short*          agw2T  = (short*)(w + 16299264);            //   393,216
  float*          pws    = (float*)(w + 16692480);            // 4,767,744 (optional)
  unsigned short* ow_bf  = geo_bf;
  const bool split_attn = (ws_size >= 21460224);

  hipLaunchKernelGGL(k_prep,    dim3(1520),  dim3(256), 0, stream,
                     ge_w2, ge_w1, wq, wk, wv, wo, ag_w1, ag_w2,
                     w2T, w2r, wqT, wkT, wvT, woT, w1t, agw1T, agw2T);
  hipLaunchKernelGGL(k_gprep,   dim3(66),    dim3(256), 0, stream,
                     w2r, ge_b2, w1t, ge_b1, Gm, gscal, g1s);
  hipLaunchKernelGGL(k_geo,     dim3(4608),  dim3(256), 0, stream,
                     coord, w1t, ge_b1, ge_g1, ge_be1, Gm, gscal, g1s, gv);
  hipLaunchKernelGGL(k_geofin,  dim3(768),   dim3(256), 0, stream,
                     gv, w2r, ge_b2, ge_g2, ge_be2, geo_bf);
  hipLaunchKernelGGL(k_mean,    dim3(128),   dim3(256), 0, stream,
                     lab, feat, geo_bf, cntw, xmean, gmean);
  hipLaunchKernelGGL(k_mlp,     dim3(8),     dim3(256), 0, stream,
                     xmean, gmean, agw1T, ag_b1, ag_g1, ag_be1,
                     agw2T, ag_b2, ag_g2, ag_be2, comb);
  hipLaunchKernelGGL(k_enhance, dim3(2304),  dim3(256), 0, stream,
                     feat, lab, cntw, comb, enh_f, enh_bf);
  hipLaunchKernelGGL(k_qkv,     dim3(432),   dim3(256), 0, stream,
                     enh_bf, geo_bf, wqT, wkT, wvT, bq, bk, bv, qw_bf, kw_bf, vw_bf);
  if (split_attn){
    hipLaunchKernelGGL(k_attn_split, dim3(384), dim3(256), 0, stream,
                       qw_bf, kw_bf, vw_bf, pws);
    hipLaunchKernelGGL(k_attnfin,    dim3(192), dim3(256), 0, stream,
                       pws, ow_bf);
  } else {
    hipLaunchKernelGGL(k_attn_full,  dim3(192), dim3(256), 0, stream,
                       qw_bf, kw_bf, vw_bf, ow_bf);
  }
  hipLaunchKernelGGL(k_out,     dim3(144),   dim3(256), 0, stream,
                     ow_bf, enh_f, woT, bo, (float*)d_out);
}

// Round 17
// 349.477 us; speedup vs baseline: 1.0864x; 1.0181x over previous
//
#include <hip/hip_runtime.h>
#include <hip/hip_bf16.h>
#include <stdint.h>
#include <stddef.h>

#define BB 2
#define NN 384
#define DD 768
#define HH 256
#define SS 64
#define NHH 8
#define DHH 96

typedef __attribute__((ext_vector_type(8))) short bf16x8;
typedef __attribute__((ext_vector_type(4))) float f32x4;

__device__ __forceinline__ float bits_f(unsigned short u){
  unsigned x = ((unsigned)u) << 16; float f; __builtin_memcpy(&f, &x, 4); return f;
}
__device__ __forceinline__ unsigned short f_bits(float a){
  unsigned x; __builtin_memcpy(&x, &a, 4);
  unsigned r = x + 0x7fffu + ((x >> 16) & 1u);
  return (unsigned short)(r >> 16);
}
__device__ __forceinline__ float lo_f(unsigned u){ unsigned x = u << 16; float f; __builtin_memcpy(&f,&x,4); return f; }
__device__ __forceinline__ float hi_f(unsigned u){ unsigned x = u & 0xffff0000u; float f; __builtin_memcpy(&f,&x,4); return f; }
// hardware RTNE pack: lo=bf16(a), hi=bf16(b) — same rounding as f_bits
__device__ __forceinline__ unsigned cvt_pk_bf16(float a, float b){
  unsigned r; asm("v_cvt_pk_bf16_f32 %0, %1, %2" : "=v"(r) : "v"(a), "v"(b));
  return r;
}

// ================= prep: all transposes (LDS-tiled, coalesced) =================
__global__ __launch_bounds__(256) void k_prep(
    const float* __restrict__ w2, const float* __restrict__ w1g,
    const float* __restrict__ wq, const float* __restrict__ wk,
    const float* __restrict__ wv, const float* __restrict__ wo,
    const float* __restrict__ aw1, const float* __restrict__ aw2,
    short* __restrict__ w2T, short* __restrict__ w2r,
    short* __restrict__ wqT, short* __restrict__ wkT, short* __restrict__ wvT,
    short* __restrict__ woT, short* __restrict__ w1t,
    short* __restrict__ agw1T, short* __restrict__ agw2T)
{
  __shared__ short tile[64*66];
  const int tid = threadIdx.x, blk = blockIdx.x;
  if (blk < 48){               // w2 [256,768] -> w2T [768,256]
    int t = blk;
    int r0 = (t/12)*64, c0 = (t%12)*64;
    int g = tid >> 6, c = tid & 63;
    #pragma unroll
    for (int i=0;i<16;++i){
      int r = i*4 + g;
      tile[r*66 + c] = (short)f_bits(w2[(size_t)(r0+r)*768 + c0 + c]);
    }
    __syncthreads();
    #pragma unroll
    for (int i=0;i<16;++i){
      int cc = i*4 + g, rr = c;
      w2T[(size_t)(c0+cc)*256 + r0 + rr] = tile[rr*66 + cc];
    }
    return;
  }
  if (blk < 816){              // w2r: row-major bf16 copy
    int idx = (blk-48)*256 + tid;
    w2r[idx] = (short)f_bits(w2[idx]);
    return;
  }
  if (blk < 1392){             // attn weights [768,768] -> T[n][k]
    int t = blk - 816;
    int mat = t / 144, tt = t % 144;
    const float* W = (mat==0)?wq:(mat==1)?wk:(mat==2)?wv:wo;
    short* T = (mat==0)?wqT:(mat==1)?wkT:(mat==2)?wvT:woT;
    int r0 = (tt/12)*64, c0 = (tt%12)*64;
    int g = tid >> 6, c = tid & 63;
    #pragma unroll
    for (int i=0;i<16;++i){
      int r = i*4 + g;
      tile[r*66 + c] = (short)f_bits(W[(size_t)(r0+r)*768 + c0 + c]);
    }
    __syncthreads();
    #pragma unroll
    for (int i=0;i<16;++i){
      int cc = i*4 + g, rr = c;
      T[(size_t)(c0+cc)*768 + r0 + rr] = tile[rr*66 + cc];
    }
    return;
  }
  if (blk < 1424){             // w1t [256c][32k], K padded
    int idx = (blk-1392)*256 + tid;
    int c = idx >> 5, kk = idx & 31;
    w1t[idx] = (kk < 9) ? (short)f_bits(w1g[kk*256 + c]) : (short)0;
    return;
  }
  if (blk < 1472){             // ag_w1 [768,256] -> agw1T [256n][768k]
    int t = blk - 1424;
    int r0 = (t/4)*64, c0 = (t%4)*64;
    int g = tid >> 6, c = tid & 63;
    #pragma unroll
    for (int i=0;i<16;++i){
      int r = i*4 + g;
      tile[r*66 + c] = (short)f_bits(aw1[(size_t)(r0+r)*256 + c0 + c]);
    }
    __syncthreads();
    #pragma unroll
    for (int i=0;i<16;++i){
      int cc = i*4 + g, rr = c;
      agw1T[(size_t)(c0+cc)*768 + r0 + rr] = tile[rr*66 + cc];
    }
    return;
  }
  {                            // ag_w2 [256,768] -> agw2T [768n][256k]
    int t = blk - 1472;
    int r0 = (t/12)*64, c0 = (t%12)*64;
    int g = tid >> 6, c = tid & 63;
    #pragma unroll
    for (int i=0;i<16;++i){
      int r = i*4 + g;
      tile[r*66 + c] = (short)f_bits(aw2[(size_t)(r0+r)*768 + c0 + c]);
    }
    __syncthreads();
    #pragma unroll
    for (int i=0;i<16;++i){
      int cc = i*4 + g, rr = c;
      agw2T[(size_t)(c0+cc)*256 + r0 + rr] = tile[rr*66 + cc];
    }
  }
}

// ================= Gram prep v2 — Gm written in MFMA-fragment layout =================
// GmF element (n,k): frag f = (n>>4)*8 + (k>>5); lane = ((k>>3)&3)*16 + (n&15); e = k&7
// index (shorts) = f*512 + lane*8 + e.  Consumers read one contiguous 1KB burst per frag.
__global__ __launch_bounds__(256) void k_gprep(const short* __restrict__ w2r,
                                               const float* __restrict__ b2,
                                               const short* __restrict__ w1t,
                                               const float* __restrict__ b1,
                                               short* __restrict__ Gm, float* __restrict__ gscal,
                                               float* __restrict__ g1s){
  __shared__ float b2s[768];
  __shared__ float red[8];
  const int tid = threadIdx.x, blk = blockIdx.x;
  if (blk < 64){
    const int wave = tid >> 6, lane = tid & 63, quad = lane >> 4, l16 = lane & 15;
    const int id = blk*4 + wave, ti = id >> 4, tj = id & 15;
    f32x4 acc = (f32x4){0.f,0.f,0.f,0.f};
    for (int ks = 0; ks < 24; ++ks){
      bf16x8 af = *(const bf16x8*)&w2r[(size_t)(ti*16 + l16)*768 + ks*32 + quad*8];
      bf16x8 bf = *(const bf16x8*)&w2r[(size_t)(tj*16 + l16)*768 + ks*32 + quad*8];
      acc = __builtin_amdgcn_mfma_f32_16x16x32_bf16(af, bf, acc, 0,0,0);
    }
    // value at (n = ti*16 + quad*4 + r, k = tj*16 + l16)
    {
      int k = tj*16 + l16;
      int fbase = ti*8 + (k >> 5);
      int ksub = ((k >> 3) & 3);
      int e = k & 7;
      #pragma unroll
      for (int r = 0; r < 4; ++r){
        int ln = ksub*16 + (quad*4 + r);
        Gm[fbase*512 + ln*8 + e] = (short)f_bits(acc[r]);
      }
    }
  } else if (blk == 64){
    for (int c = tid; c < 768; c += 256) b2s[c] = b2[c];
    __syncthreads();
    float sa = 0.f, wa = 0.f;
    const uint4* wr = (const uint4*)(w2r + (size_t)tid*768);
    #pragma unroll 4
    for (int kk = 0; kk < 96; ++kk){
      uint4 ww = wr[kk];
      const float* bp = &b2s[kk*8];
      float x0=lo_f(ww.x), x1=hi_f(ww.x), x2=lo_f(ww.y), x3=hi_f(ww.y);
      float x4=lo_f(ww.z), x5=hi_f(ww.z), x6=lo_f(ww.w), x7=hi_f(ww.w);
      sa += (x0+x1)+(x2+x3)+(x4+x5)+(x6+x7);
      wa += bp[0]*x0 + bp[1]*x1 + bp[2]*x2 + bp[3]*x3
          + bp[4]*x4 + bp[5]*x5 + bp[6]*x6 + bp[7]*x7;
    }
    // ext rows in fragment layout: n=256 (sa), n=257 (wa), n=258..287 zero; k = tid
    {
      int e = tid & 7;
      int ksub = (tid >> 3) & 3;
      int f16 = 128 + (tid >> 5);            // tile 16 fragments
      Gm[f16*512 + (ksub*16 + 0)*8 + e] = (short)f_bits(sa);   // n=256
      Gm[f16*512 + (ksub*16 + 1)*8 + e] = (short)f_bits(wa);   // n=257
      #pragma unroll
      for (int rr = 258; rr < 288; ++rr){
        int ff = (rr >> 4)*8 + (tid >> 5);
        int ln = ksub*16 + (rr & 15);
        Gm[ff*512 + ln*8 + e] = 0;
      }
    }
    float pb = 0.f, pbb = 0.f;
    for (int c = tid; c < 768; c += 256){ float bb = b2s[c]; pb += bb; pbb += bb*bb; }
    for (int m = 32; m >= 1; m >>= 1){ pb += __shfl_xor(pb,m); pbb += __shfl_xor(pbb,m); }
    if ((tid & 63) == 0){ red[tid>>6] = pb; red[4+(tid>>6)] = pbb; }
    __syncthreads();
    if (tid == 0){ gscal[0] = red[0]+red[1]+red[2]+red[3]; gscal[1] = red[4]+red[5]+red[6]+red[7]; }
  } else {
    const unsigned short* w1u = (const unsigned short*)w1t;
    if (tid < 81){
      int i = tid / 9, j = tid % 9;
      float acc = 0.f;
      for (int c = 0; c < 256; ++c)
        acc += bits_f(w1u[c*32 + i]) * bits_f(w1u[c*32 + j]);
      g1s[18 + tid] = acc;
    } else if (tid < 90){
      int i = tid - 81;
      float sa = 0.f, sb = 0.f;
      for (int c = 0; c < 256; ++c){
        float x = bits_f(w1u[c*32 + i]);
        sa += x; sb += x * b1[c];
      }
      g1s[i] = sa; g1s[9 + i] = sb;
    } else if (tid == 90){
      float pb = 0.f, pbb = 0.f;
      for (int c = 0; c < 256; ++c){ float bb = b1[c]; pb += bb; pbb += bb*bb; }
      g1s[99] = pb; g1s[100] = pbb;
    }
  }
}

// ================= geometric encoder; WG=(pair,jt), 256 thr, 3 WG/CU =================
// Gm consumed in fragment layout: per-(ci,ks) load = contiguous 1KB wave burst.
// Disjoint partials: gv[(pair*6+jt)*258 + {0..255:V, 256:R, 257:T}]
__global__ __launch_bounds__(256, 3) void k_geo(
    const float* __restrict__ coord, const short* __restrict__ w1t,
    const float* __restrict__ b1g, const float* __restrict__ g1g, const float* __restrict__ be1g,
    const short* __restrict__ Gm, const float* __restrict__ gscal,
    const float* __restrict__ g1s, float* __restrict__ gv)
{
  __shared__ short relbf[64*36];
  __shared__ short h_bf[64*256];   // chunk-swizzled: phys_chunk=((col>>3)+row)&31
  __shared__ float rmean[64], rrstd[64];
  __shared__ float msum[64], wbsum[64], qsum[64];

  const int tid = threadIdx.x;
  const int pair = blockIdx.x % 768;
  const int jt   = blockIdx.x / 768;
  const int j0 = jt * 64;
  const int b = pair / NN;

  if (tid < 64){
    int j = j0 + tid;
    float cix = coord[pair*3+0], ciy = coord[pair*3+1], ciz = coord[pair*3+2];
    float dx = cix - coord[(b*NN+j)*3+0];
    float dy = ciy - coord[(b*NN+j)*3+1];
    float dz = ciz - coord[(b*NN+j)*3+2];
    float dist = sqrtf(dx*dx + dy*dy + dz*dz);
    float inv = 1.f / fmaxf(dist, 1e-12f);
    float x = dx*inv, y = dy*inv, z = dz*inv;
    float rv[9];
    rv[0]=dist; rv[1]=x; rv[2]=y; rv[3]=z; rv[4]=0.f; rv[5]=0.f;
    rv[6]=y*z; rv[7]=x*y; rv[8]=x*z;
    short* rr = &relbf[tid*36];
    float rbf[9];
    #pragma unroll
    for (int k=0;k<9;++k){
      unsigned short hb = f_bits(rv[k]);
      rr[k] = (short)hb; rbf[k] = bits_f(hb);
    }
    #pragma unroll
    for (int k=9;k<32;++k) rr[k]=0;
    float s = g1s[99], ssq = g1s[100];
    #pragma unroll
    for (int i=0;i<9;++i){
      s += rbf[i]*g1s[i];
      ssq += 2.f*rbf[i]*g1s[9+i];
      #pragma unroll
      for (int jj=0;jj<9;++jj) ssq += rbf[i]*rbf[jj]*g1s[18+i*9+jj];
    }
    float mean = s*(1.f/256.f);
    float var  = ssq*(1.f/256.f) - mean*mean;
    rmean[tid] = mean; rrstd[tid] = rsqrtf(var + 1e-5f);
  } else if (tid < 128){
    qsum[tid-64] = 0.f;
  }
  __syncthreads();

  const int wave = tid >> 6, lane = tid & 63, quad = lane >> 4, l16 = lane & 15;

  // ---- phase 2: MFMA mm1 + in-register LN1/ReLU -> h_bf + hreg (packed bf16 pairs)
  unsigned hreg[4][4][2];   // [ci][rb][rpair]
  {
    bf16x8 af[4];
    #pragma unroll
    for (int rb=0;rb<4;++rb)
      af[rb] = *(const bf16x8*)&relbf[(rb*16 + l16)*36 + quad*8];
    f32x4 hacc[4][4];
    #pragma unroll
    for (int ci=0;ci<4;++ci){
      int cb = wave*4 + ci;
      bf16x8 bfw = *(const bf16x8*)&w1t[(cb*16 + l16)*32 + quad*8];
      #pragma unroll
      for (int rb=0;rb<4;++rb)
        hacc[ci][rb] = __builtin_amdgcn_mfma_f32_16x16x32_bf16(af[rb], bfw, (f32x4){0.f,0.f,0.f,0.f}, 0,0,0);
    }
    f32x4 rmv[4], rsv[4];
    #pragma unroll
    for (int rb=0;rb<4;++rb){
      rmv[rb] = *(const f32x4*)&rmean[rb*16 + quad*4];
      rsv[rb] = *(const f32x4*)&rrstd[rb*16 + quad*4];
    }
    #pragma unroll
    for (int ci=0;ci<4;++ci){
      int col = (wave*4+ci)*16 + l16;
      float b1c = b1g[col], g1c = g1g[col], be1c = be1g[col];
      int chb = col >> 3, lo = col & 7;
      #pragma unroll
      for (int rb=0;rb<4;++rb){
        float hn[4];
        #pragma unroll
        for (int r=0;r<4;++r)
          hn[r] = fmaxf((hacc[ci][rb][r] + b1c - rmv[rb][r]) * rsv[rb][r] * g1c + be1c, 0.f);
        unsigned p0 = cvt_pk_bf16(hn[0], hn[1]);
        unsigned p1 = cvt_pk_bf16(hn[2], hn[3]);
        hreg[ci][rb][0] = p0; hreg[ci][rb][1] = p1;
        int row0 = rb*16 + quad*4;
        h_bf[(row0+0)*256 + ((chb + row0+0)&31)*8 + lo] = (short)(p0 & 0xffff);
        h_bf[(row0+1)*256 + ((chb + row0+1)&31)*8 + lo] = (short)(p0 >> 16);
        h_bf[(row0+2)*256 + ((chb + row0+2)&31)*8 + lo] = (short)(p1 & 0xffff);
        h_bf[(row0+3)*256 + ((chb + row0+3)&31)*8 + lo] = (short)(p1 >> 16);
      }
    }
  }
  __syncthreads();

  // ---- phase 3: U = H@Gm_ext; wave0 ext tile -> msum/wbsum; Q from hreg
  {
    f32x4 acc[4][4];
    #pragma unroll
    for (int ci=0;ci<4;++ci)
      #pragma unroll
      for (int rb=0;rb<4;++rb) acc[ci][rb] = (f32x4){0.f,0.f,0.f,0.f};
    f32x4 eacc[4];
    #pragma unroll
    for (int rb=0;rb<4;++rb) eacc[rb] = (f32x4){0.f,0.f,0.f,0.f};
    for (int ks=0;ks<8;++ks){
      bf16x8 a4[4];
      #pragma unroll
      for (int rb=0;rb<4;++rb){
        int row = rb*16 + l16;
        a4[rb] = *(const bf16x8*)&h_bf[row*256 + (((ks*4 + quad) + row)&31)*8];
      }
      #pragma unroll
      for (int ci=0;ci<4;++ci){
        // fragment-contiguous B load: frag = (wave*4+ci)*8 + ks, per-lane 16B
        bf16x8 bg = *(const bf16x8*)&Gm[((wave*4+ci)*8 + ks)*512 + lane*8];
        #pragma unroll
        for (int rb=0;rb<4;++rb)
          acc[ci][rb] = __builtin_amdgcn_mfma_f32_16x16x32_bf16(a4[rb], bg, acc[ci][rb], 0,0,0);
      }
      if (wave == 0){
        bf16x8 bge = *(const bf16x8*)&Gm[(128 + ks)*512 + lane*8];
        #pragma unroll
        for (int rb=0;rb<4;++rb)
          eacc[rb] = __builtin_amdgcn_mfma_f32_16x16x32_bf16(a4[rb], bge, eacc[rb], 0,0,0);
      }
    }
    if (wave == 0 && l16 < 2){
      float* dst = (l16 == 0) ? msum : wbsum;
      #pragma unroll
      for (int rb=0;rb<4;++rb)
        #pragma unroll
        for (int r=0;r<4;++r) dst[rb*16 + quad*4 + r] = eacc[rb][r];
    }
    #pragma unroll
    for (int rb=0;rb<4;++rb){
      #pragma unroll
      for (int r=0;r<4;++r){
        int row = rb*16 + quad*4 + r;
        float qp = 0.f;
        #pragma unroll
        for (int ci=0;ci<4;++ci){
          unsigned p = hreg[ci][rb][r>>1];
          float hv = (r & 1) ? hi_f(p) : lo_f(p);
          qp += acc[ci][rb][r] * hv;
        }
        qp += __shfl_xor(qp,1);
        qp += __shfl_xor(qp,2);
        qp += __shfl_xor(qp,4);
        qp += __shfl_xor(qp,8);
        if (l16 == 0) atomicAdd(&qsum[row], qp);
      }
    }
  }
  __syncthreads();
  if (tid < 64){
    float Sb = gscal[0], Sbb = gscal[1];
    float m2 = (msum[tid] + Sb)*(1.f/768.f);
    float ssq = qsum[tid] + 2.f*wbsum[tid] + Sbb;
    float var = ssq*(1.f/768.f) - m2*m2;
    rmean[tid] = m2; rrstd[tid] = rsqrtf(var + 1e-5f);
  }
  __syncthreads();
  float* gp = gv + ((size_t)pair*6 + jt)*258;
  if (tid < 64){
    float rr = rrstd[tid], tt = rmean[tid]*rrstd[tid];
    for (int m = 32; m >= 1; m >>= 1){ rr += __shfl_xor(rr,m); tt += __shfl_xor(tt,m); }
    if (tid == 0){ gp[256] = rr; gp[257] = tt; }
  }
  // ---- V = sum_j rstd_j h_j : from hreg; quad-reduce via shfl; coalesced stores
  {
    float vp[4] = {0.f, 0.f, 0.f, 0.f};
    #pragma unroll
    for (int rb=0;rb<4;++rb){
      #pragma unroll
      for (int r=0;r<4;++r){
        int row = rb*16 + quad*4 + r;
        float rs = rrstd[row];
        #pragma unroll
        for (int ci=0;ci<4;++ci){
          unsigned p = hreg[ci][rb][r>>1];
          float hv = (r & 1) ? hi_f(p) : lo_f(p);
          vp[ci] += rs * hv;
        }
      }
    }
    #pragma unroll
    for (int ci=0;ci<4;++ci){
      vp[ci] += __shfl_xor(vp[ci],16);
      vp[ci] += __shfl_xor(vp[ci],32);
    }
    if (quad == 0){
      #pragma unroll
      for (int ci=0;ci<4;++ci)
        gp[(wave*4+ci)*16 + l16] = vp[ci];
    }
  }
}

// ================= finalize geo: 4 pairs/block, shared w2r rows (grid=192) =================
__global__ __launch_bounds__(256) void k_geofin(
    const float* __restrict__ gv, const short* __restrict__ w2r,
    const float* __restrict__ b2g, const float* __restrict__ g2g,
    const float* __restrict__ be2g, unsigned short* __restrict__ geo)
{
  __shared__ float V4[4][256];
  __shared__ float RT4[8];
  const int tid = threadIdx.x;
  const int pair0 = blockIdx.x * 4;
  #pragma unroll
  for (int p = 0; p < 4; ++p){
    const float* gp = gv + (size_t)(pair0 + p)*6*258;
    V4[p][tid] = gp[tid] + gp[258 + tid] + gp[2*258 + tid]
               + gp[3*258 + tid] + gp[4*258 + tid] + gp[5*258 + tid];
  }
  if (tid < 8){
    int p = tid >> 1, e = tid & 1;
    const float* gp = gv + (size_t)(pair0 + p)*6*258;
    float r = 0.f;
    #pragma unroll
    for (int t = 0; t < 6; ++t) r += gp[t*258 + 256 + e];
    RT4[tid] = r;
  }
  __syncthreads();
  const unsigned short* wr = (const unsigned short*)w2r;
  float a0[4] = {0.f,0.f,0.f,0.f};
  float a1[4] = {0.f,0.f,0.f,0.f};
  float a2[4] = {0.f,0.f,0.f,0.f};
  #pragma unroll 4
  for (int k = 0; k < 256; ++k){
    const unsigned short* row = wr + (size_t)k*768;
    float w0 = bits_f(row[tid]);
    float w1 = bits_f(row[tid+256]);
    float w2v = bits_f(row[tid+512]);
    #pragma unroll
    for (int p = 0; p < 4; ++p){
      float vk = V4[p][k];
      a0[p] += vk * w0;
      a1[p] += vk * w1;
      a2[p] += vk * w2v;
    }
  }
  const float gg0 = g2g[tid],     bb0 = b2g[tid],     ee0 = be2g[tid];
  const float gg1 = g2g[tid+256], bb1 = b2g[tid+256], ee1 = be2g[tid+256];
  const float gg2 = g2g[tid+512], bb2 = b2g[tid+512], ee2 = be2g[tid+512];
  #pragma unroll
  for (int p = 0; p < 4; ++p){
    const float R = RT4[p*2], T = RT4[p*2+1];
    size_t base = (size_t)(pair0 + p)*DD;
    geo[base + tid]       = f_bits(gg0*(a0[p] + bb0*R - T)*(1.f/384.f) + ee0);
    geo[base + tid + 256] = f_bits(gg1*(a1[p] + bb1*R - T)*(1.f/384.f) + ee1);
    geo[base + tid + 512] = f_bits(gg2*(a2[p] + bb2*R - T)*(1.f/384.f) + ee2);
  }
}

// ================= superpoint means: parallel list-build + 2-deep gather (grid=128) =================
__global__ __launch_bounds__(256) void k_mean(
    const int* __restrict__ lab, const float* __restrict__ feat,
    const unsigned short* __restrict__ geo, float* __restrict__ cntw,
    unsigned short* __restrict__ xmean, float* __restrict__ gmean)
{
  __shared__ int ls[NN];
  __shared__ int ent[NN];
  __shared__ int cnt_s;
  const int tid = threadIdx.x;
  const int bs = blockIdx.x, b = bs >> 6, s = bs & 63;
  if (tid == 0) cnt_s = 0;
  for (int j = tid; j < NN; j += 256) ls[j] = lab[b*NN + j];
  __syncthreads();
  for (int j = tid; j < NN; j += 256){
    if (ls[j] == s){
      int p = atomicAdd(&cnt_s, 1);
      ent[p] = j;
    }
  }
  __syncthreads();
  const int cnt = cnt_s;
  float f0=0.f, f1=0.f, f2=0.f, g0=0.f, g1=0.f, g2=0.f;
  int idx = 0;
  for (; idx + 1 < cnt; idx += 2){
    size_t ra = (size_t)(b*NN + ent[idx])*DD;
    size_t rb = (size_t)(b*NN + ent[idx+1])*DD;
    float a0 = feat[ra+tid], a1 = feat[ra+tid+256], a2 = feat[ra+tid+512];
    float b0 = feat[rb+tid], b1v = feat[rb+tid+256], b2 = feat[rb+tid+512];
    float ga0 = bits_f(geo[ra+tid]), ga1 = bits_f(geo[ra+tid+256]), ga2 = bits_f(geo[ra+tid+512]);
    float gb0 = bits_f(geo[rb+tid]), gb1 = bits_f(geo[rb+tid+256]), gb2 = bits_f(geo[rb+tid+512]);
    f0 += a0 + b0; f1 += a1 + b1v; f2 += a2 + b2;
    g0 += ga0 + gb0; g1 += ga1 + gb1; g2 += ga2 + gb2;
  }
  if (idx < cnt){
    size_t ra = (size_t)(b*NN + ent[idx])*DD;
    f0 += feat[ra+tid]; f1 += feat[ra+tid+256]; f2 += feat[ra+tid+512];
    g0 += bits_f(geo[ra+tid]); g1 += bits_f(geo[ra+tid+256]); g2 += bits_f(geo[ra+tid+512]);
  }
  const float inv = 1.f / fmaxf((float)cnt, 1.f);
  if (tid == 0) cntw[bs] = (float)cnt;
  size_t base = (size_t)bs * DD;
  xmean[base + tid]       = f_bits(f0*inv);
  xmean[base + tid + 256] = f_bits(f1*inv);
  xmean[base + tid + 512] = f_bits(f2*inv);
  gmean[base + tid]       = g0*inv;
  gmean[base + tid + 256] = g1*inv;
  gmean[base + tid + 512] = g2*inv;
}

// ================= aggregator MLP via MFMA (grid=8, 16 rows/block) =================
__global__ __launch_bounds__(256) void k_mlp(
    const unsigned short* __restrict__ xmean, const float* __restrict__ gmean,
    const short* __restrict__ w1T, const float* __restrict__ b1g,
    const float* __restrict__ g1g, const float* __restrict__ be1g,
    const short* __restrict__ w2T, const float* __restrict__ b2g,
    const float* __restrict__ g2g, const float* __restrict__ be2g,
    float* __restrict__ comb)
{
  __shared__ short hA[16*264];     // bf16 hidden, padded stride
  __shared__ float rsum[16], rsq[16], rmean[16], rrstd[16];
  const int tid = threadIdx.x;
  const int wave = tid >> 6, lane = tid & 63, quad = lane >> 4, l16 = lane & 15;
  const int bs0 = blockIdx.x * 16;
  if (tid < 16){ rsum[tid] = 0.f; rsq[tid] = 0.f; }
  __syncthreads();

  // ---- layer 1: [16x768] @ agw1T[256n][768k] -> 16x256, LN1+ReLU -> hA
  f32x4 acc[4];
  #pragma unroll
  for (int cb=0;cb<4;++cb) acc[cb] = (f32x4){0.f,0.f,0.f,0.f};
  for (int ks = 0; ks < 24; ++ks){
    bf16x8 af = *(const bf16x8*)&((const short*)xmean)[(size_t)(bs0 + l16)*DD + ks*32 + quad*8];
    #pragma unroll
    for (int cb=0;cb<4;++cb){
      bf16x8 bw = *(const bf16x8*)&w1T[(size_t)(wave*64 + cb*16 + l16)*768 + ks*32 + quad*8];
      acc[cb] = __builtin_amdgcn_mfma_f32_16x16x32_bf16(af, bw, acc[cb], 0,0,0);
    }
  }
  {
    float ps[4] = {0.f,0.f,0.f,0.f}, pq[4] = {0.f,0.f,0.f,0.f};
    #pragma unroll
    for (int cb=0;cb<4;++cb){
      int col = wave*64 + cb*16 + l16;
      float b1c = b1g[col];
      #pragma unroll
      for (int r=0;r<4;++r){
        float v = acc[cb][r] + b1c;
        acc[cb][r] = v;
        ps[r] += v; pq[r] += v*v;
      }
    }
    #pragma unroll
    for (int r=0;r<4;++r){
      ps[r] += __shfl_xor(ps[r],1); pq[r] += __shfl_xor(pq[r],1);
      ps[r] += __shfl_xor(ps[r],2); pq[r] += __shfl_xor(pq[r],2);
      ps[r] += __shfl_xor(ps[r],4); pq[r] += __shfl_xor(pq[r],4);
      ps[r] += __shfl_xor(ps[r],8); pq[r] += __shfl_xor(pq[r],8);
      if (l16 == 0){ atomicAdd(&rsum[quad*4+r], ps[r]); atomicAdd(&rsq[quad*4+r], pq[r]); }
    }
  }
  __syncthreads();
  if (tid < 16){
    float mean = rsum[tid]*(1.f/HH);
    float var  = rsq[tid]*(1.f/HH) - mean*mean;
    rmean[tid] = mean; rrstd[tid] = rsqrtf(var + 1e-5f);
    rsum[tid] = 0.f; rsq[tid] = 0.f;     // re-zero for LN2
  }
  __syncthreads();
  #pragma unroll
  for (int cb=0;cb<4;++cb){
    int col = wave*64 + cb*16 + l16;
    float g1c = g1g[col], be1c = be1g[col];
    #pragma unroll
    for (int r=0;r<4;++r){
      int row = quad*4 + r;
      float h = fmaxf((acc[cb][r]-rmean[row])*rrstd[row]*g1c + be1c, 0.f);
      hA[row*264 + col] = (short)f_bits(h);
    }
  }
  __syncthreads();

  // ---- layer 2: [16x256] @ agw2T[768n][256k] -> 16x768, LN2 -> comb (+gmean)
  f32x4 acc2[12];
  #pragma unroll
  for (int cb=0;cb<12;++cb) acc2[cb] = (f32x4){0.f,0.f,0.f,0.f};
  for (int ks = 0; ks < 8; ++ks){
    bf16x8 af = *(const bf16x8*)&hA[l16*264 + ks*32 + quad*8];
    #pragma unroll
    for (int cb=0;cb<12;++cb){
      bf16x8 bw = *(const bf16x8*)&w2T[(size_t)(wave*192 + cb*16 + l16)*256 + ks*32 + quad*8];
      acc2[cb] = __builtin_amdgcn_mfma_f32_16x16x32_bf16(af, bw, acc2[cb], 0,0,0);
    }
  }
  {
    float ps[4] = {0.f,0.f,0.f,0.f}, pq[4] = {0.f,0.f,0.f,0.f};
    #pragma unroll
    for (int cb=0;cb<12;++cb){
      int col = wave*192 + cb*16 + l16;
      float b2c = b2g[col];
      #pragma unroll
      for (int r=0;r<4;++r){
        float v = acc2[cb][r] + b2c;
        acc2[cb][r] = v;
        ps[r] += v; pq[r] += v*v;
      }
    }
    #pragma unroll
    for (int r=0;r<4;++r){
      ps[r] += __shfl_xor(ps[r],1); pq[r] += __shfl_xor(pq[r],1);
      ps[r] += __shfl_xor(ps[r],2); pq[r] += __shfl_xor(pq[r],2);
      ps[r] += __shfl_xor(ps[r],4); pq[r] += __shfl_xor(pq[r],4);
      ps[r] += __shfl_xor(ps[r],8); pq[r] += __shfl_xor(pq[r],8);
      if (l16 == 0){ atomicAdd(&rsum[quad*4+r], ps[r]); atomicAdd(&rsq[quad*4+r], pq[r]); }
    }
  }
  __syncthreads();
  if (tid < 16){
    float mean = rsum[tid]*(1.f/DD);
    float var  = rsq[tid]*(1.f/DD) - mean*mean;
    rmean[tid] = mean; rrstd[tid] = rsqrtf(var + 1e-5f);
  }
  __syncthreads();
  #pragma unroll
  for (int cb=0;cb<12;++cb){
    int col = wave*192 + cb*16 + l16;
    float g2c = g2g[col], be2c = be2g[col];
    #pragma unroll
    for (int r=0;r<4;++r){
      int row = quad*4 + r;
      size_t idx = (size_t)(bs0+row)*DD + col;
      comb[idx] = (acc2[cb][r]-rmean[row])*rrstd[row]*g2c + be2c + gmean[idx];
    }
  }
}

// ================= gather + enhanced =================
__global__ void k_enhance(const float* __restrict__ feat, const int* __restrict__ lab,
                          const float* __restrict__ cntw, const float* __restrict__ comb,
                          float* __restrict__ enh, unsigned short* __restrict__ enhb)
{
  int idx = blockIdx.x * 256 + threadIdx.x;
  int c = idx % DD; int bn = idx / DD; int b = bn / NN;
  int l = lab[bn];
  float f = feat[idx];
  float cg = comb[(size_t)(b*SS + l)*DD + c];
  float cnt = cntw[b*SS + l];
  float e = (cnt >= 2.0f) ? (0.7f*f + 0.3f*cg) : f;
  enh[idx] = e;
  enhb[idx] = f_bits(e);
}

// ================= q/k/v projections via MFMA (16-row tiles, 432 blocks) =================
__global__ __launch_bounds__(256, 4) void k_qkv(
    const unsigned short* __restrict__ enhb, const unsigned short* __restrict__ geo,
    const short* __restrict__ wqT, const short* __restrict__ wkT, const short* __restrict__ wvT,
    const float* __restrict__ bq, const float* __restrict__ bk, const float* __restrict__ bv,
    unsigned short* __restrict__ qo, unsigned short* __restrict__ ko, unsigned short* __restrict__ vo)
{
  const int tid = threadIdx.x, blk = blockIdx.x;   // 432 = 3 mats * 48 rt * 3 ct
  const int m = blk / 144, rem = blk % 144;
  const int rt = rem / 3, ct = rem % 3;
  const int wave = tid >> 6, lane = tid & 63, quad = lane >> 4, l16 = lane & 15;
  const short* WT = (m==0)?wqT:(m==1)?wkT:wvT;
  const float* Bv = (m==0)?bq:(m==1)?bk:bv;
  unsigned short* Y = (m==0)?qo:(m==1)?ko:vo;
  const short* X = (const short*)((m==0)? enhb : geo);
  const float oscale = (m==0)? 0.10206207261596577f : 1.0f;
  const int row0 = rt*16;
  const int col0 = ct*256 + wave*64;

  f32x4 acc[4];
  #pragma unroll
  for (int cb=0;cb<4;++cb) acc[cb] = (f32x4){0.f,0.f,0.f,0.f};
  for (int ks = 0; ks < 24; ++ks){
    bf16x8 af = *(const bf16x8*)&X[(size_t)(row0 + l16)*DD + ks*32 + quad*8];
    #pragma unroll
    for (int cb=0;cb<4;++cb){
      bf16x8 bw = *(const bf16x8*)&WT[(size_t)(col0 + cb*16 + l16)*DD + ks*32 + quad*8];
      acc[cb] = __builtin_amdgcn_mfma_f32_16x16x32_bf16(af, bw, acc[cb], 0,0,0);
    }
  }
  #pragma unroll
  for (int cb=0;cb<4;++cb){
    int col = col0 + cb*16 + l16;
    float bb = Bv[col];
    #pragma unroll
    for (int r=0;r<4;++r){
      int row = row0 + quad*4 + r;
      Y[(size_t)row*DD + col] = f_bits((acc[cb][r] + bb)*oscale);
    }
  }
}

// ================= attention: split over jt halves; QK^T via MFMA =================
__global__ __launch_bounds__(256) void k_attn_split(
    const unsigned short* __restrict__ qws, const unsigned short* __restrict__ kws,
    const unsigned short* __restrict__ vws, float* __restrict__ pws)
{
  __shared__ short kt[64*104];
  __shared__ short vt[64*104];
  __shared__ float st[32*66];
  __shared__ float lsum[32];
  const int tid = threadIdx.x;
  const int half = blockIdx.x / 192;
  const int inner = blockIdx.x % 192;
  const int b = inner / (NHH*12); int rem = inner % (NHH*12);
  const int h = rem / 12; const int qt = rem % 12; const int q0 = qt*32;
  const int wave = tid >> 6, lane = tid & 63, quad = lane >> 4, l16 = lane & 15;
  const int qp = tid >> 4, dp = tid & 15;

  // Q A-fragments (jt-invariant): mt in {0,1} row-tiles, ks in {0,1,2} k-steps.
  bf16x8 aq0_0, aq0_1, aq0_2, aq1_0, aq1_1, aq1_2;
  {
    const short* qb = (const short*)qws;
    size_t r0 = (size_t)(b*NN + q0 + l16)*DD + h*DHH;
    size_t r1 = (size_t)(b*NN + q0 + 16 + l16)*DD + h*DHH;
    aq0_0 = *(const bf16x8*)&qb[r0 + 0*32 + quad*8];
    aq0_1 = *(const bf16x8*)&qb[r0 + 1*32 + quad*8];
    aq0_2 = *(const bf16x8*)&qb[r0 + 2*32 + quad*8];
    aq1_0 = *(const bf16x8*)&qb[r1 + 0*32 + quad*8];
    aq1_1 = *(const bf16x8*)&qb[r1 + 1*32 + quad*8];
    aq1_2 = *(const bf16x8*)&qb[r1 + 2*32 + quad*8];
  }
  if (tid < 32) lsum[tid] = 0.f;
  float Oacc[2][6];
  #pragma unroll
  for (int a = 0; a < 2; ++a)
    #pragma unroll
    for (int m = 0; m < 6; ++m) Oacc[a][m] = 0.f;

  for (int jt = half*3; jt < half*3 + 3; ++jt){
    const int j0 = jt * 64;
    __syncthreads();
    for (int x = tid; x < 64*48; x += 256){
      int jl = x / 48, du = x % 48;
      size_t rowoff = (size_t)(b*NN + j0 + jl)*DD + h*DHH;
      ((unsigned*)&kt[jl*104])[du] = ((const unsigned*)(kws + rowoff))[du];
      ((unsigned*)&vt[jl*104])[du] = ((const unsigned*)(vws + rowoff))[du];
    }
    __syncthreads();
    // ---- S = Q @ K^T via MFMA: wave owns j-tile = wave (j = wave*16 + l16)
    {
      f32x4 sacc0 = (f32x4){0.f,0.f,0.f,0.f};
      f32x4 sacc1 = (f32x4){0.f,0.f,0.f,0.f};
      {
        bf16x8 bk0 = *(const bf16x8*)&kt[(wave*16 + l16)*104 + 0*32 + quad*8];
        sacc0 = __builtin_amdgcn_mfma_f32_16x16x32_bf16(aq0_0, bk0, sacc0, 0,0,0);
        sacc1 = __builtin_amdgcn_mfma_f32_16x16x32_bf16(aq1_0, bk0, sacc1, 0,0,0);
        bf16x8 bk1 = *(const bf16x8*)&kt[(wave*16 + l16)*104 + 1*32 + quad*8];
        sacc0 = __builtin_amdgcn_mfma_f32_16x16x32_bf16(aq0_1, bk1, sacc0, 0,0,0);
        sacc1 = __builtin_amdgcn_mfma_f32_16x16x32_bf16(aq1_1, bk1, sacc1, 0,0,0);
        bf16x8 bk2 = *(const bf16x8*)&kt[(wave*16 + l16)*104 + 2*32 + quad*8];
        sacc0 = __builtin_amdgcn_mfma_f32_16x16x32_bf16(aq0_2, bk2, sacc0, 0,0,0);
        sacc1 = __builtin_amdgcn_mfma_f32_16x16x32_bf16(aq1_2, bk2, sacc1, 0,0,0);
      }
      int j = wave*16 + l16;
      #pragma unroll
      for (int r = 0; r < 4; ++r){
        int q = quad*4 + r;
        float p = __expf(sacc0[r]);
        st[q*66 + j] = p;
        float pr = p;
        pr += __shfl_xor(pr,1);
        pr += __shfl_xor(pr,2);
        pr += __shfl_xor(pr,4);
        pr += __shfl_xor(pr,8);
        if (l16 == 0) atomicAdd(&lsum[q], pr);
      }
      #pragma unroll
      for (int r = 0; r < 4; ++r){
        int q = 16 + quad*4 + r;
        float p = __expf(sacc1[r]);
        st[q*66 + j] = p;
        float pr = p;
        pr += __shfl_xor(pr,1);
        pr += __shfl_xor(pr,2);
        pr += __shfl_xor(pr,4);
        pr += __shfl_xor(pr,8);
        if (l16 == 0) atomicAdd(&lsum[q], pr);
      }
    }
    __syncthreads();
    #pragma unroll 4
    for (int j = 0; j < 64; ++j){
      float p0 = st[(2*qp)*66 + j];
      float p1 = st[(2*qp+1)*66 + j];
      const unsigned* vr = (const unsigned*)&vt[j*104 + dp*6];
      #pragma unroll
      for (int m = 0; m < 3; ++m){
        unsigned vv = vr[m];
        float v0 = lo_f(vv), v1 = hi_f(vv);
        Oacc[0][2*m]   += p0*v0; Oacc[0][2*m+1] += p0*v1;
        Oacc[1][2*m]   += p1*v0; Oacc[1][2*m+1] += p1*v1;
      }
    }
  }
  __syncthreads();
  float* pb = pws + ((size_t)inner*2 + half)*3104;
  #pragma unroll
  for (int m = 0; m < 6; ++m){
    pb[(2*qp)*96 + dp*6 + m]   = Oacc[0][m];
    pb[(2*qp+1)*96 + dp*6 + m] = Oacc[1][m];
  }
  if (tid < 32) pb[3072 + tid] = lsum[tid];
}

// ================= attention finalize =================
__global__ __launch_bounds__(256) void k_attnfin(
    const float* __restrict__ pws, unsigned short* __restrict__ ows)
{
  __shared__ float ls[32];
  const int tid = threadIdx.x, inner = blockIdx.x;
  const int b = inner / (NHH*12); int rem = inner % (NHH*12);
  const int h = rem / 12; const int qt = rem % 12; const int q0 = qt*32;
  const float* p0 = pws + (size_t)inner*2*3104;
  const float* p1 = p0 + 3104;
  if (tid < 32) ls[tid] = 1.f / (p0[3072+tid] + p1[3072+tid]);
  __syncthreads();
  #pragma unroll
  for (int u = 0; u < 12; ++u){
    int e = tid + u*256;
    int q = e / 96, d = e % 96;
    float o = (p0[e] + p1[e]) * ls[q];
    ows[(size_t)(b*NN + q0 + q)*DD + h*DHH + d] = f_bits(o);
  }
}

// ================= attention fallback (single-pass) =================
__global__ __launch_bounds__(256) void k_attn_full(
    const unsigned short* __restrict__ qws, const unsigned short* __restrict__ kws,
    const unsigned short* __restrict__ vws, unsigned short* __restrict__ ows)
{
  __shared__ short kt[64*104];
  __shared__ short vt[64*104];
  __shared__ float st[32*66];
  __shared__ float lsum[32];
  const int tid = threadIdx.x;
  const int blk = blockIdx.x;
  const int b = blk / (NHH*12); int rem = blk % (NHH*12);
  const int h = rem / 12; const int qt = rem % 12; const int q0 = qt*32;
  const int sq = tid >> 3, jp = tid & 7;
  const int qp = tid >> 4, dp = tid & 15;
  unsigned qreg[48];
  {
    const unsigned* qr = (const unsigned*)(qws + (size_t)(b*NN + q0 + sq)*DD + h*DHH);
    #pragma unroll
    for (int d2 = 0; d2 < 48; ++d2) qreg[d2] = qr[d2];
  }
  if (tid < 32) lsum[tid] = 0.f;
  float Oacc[2][6];
  #pragma unroll
  for (int a = 0; a < 2; ++a)
    #pragma unroll
    for (int m = 0; m < 6; ++m) Oacc[a][m] = 0.f;
  for (int jt = 0; jt < 6; ++jt){
    const int j0 = jt * 64;
    __syncthreads();
    for (int x = tid; x < 64*48; x += 256){
      int jl = x / 48, du = x % 48;
      size_t rowoff = (size_t)(b*NN + j0 + jl)*DD + h*DHH;
      ((unsigned*)&kt[jl*104])[du] = ((const unsigned*)(kws + rowoff))[du];
      ((unsigned*)&vt[jl*104])[du] = ((const unsigned*)(vws + rowoff))[du];
    }
    __syncthreads();
    float lpart = 0.f;
    #pragma unroll
    for (int jj = 0; jj < 8; ++jj){
      int j = jp*8 + jj;
      const uint4* kr4 = (const uint4*)&kt[j*104];
      float s = 0.f;
      #pragma unroll
      for (int d4 = 0; d4 < 12; ++d4){
        uint4 kk = kr4[d4];
        unsigned q0r = qreg[4*d4], q1r = qreg[4*d4+1], q2r = qreg[4*d4+2], q3r = qreg[4*d4+3];
        s += lo_f(kk.x)*lo_f(q0r) + hi_f(kk.x)*hi_f(q0r);
        s += lo_f(kk.y)*lo_f(q1r) + hi_f(kk.y)*hi_f(q1r);
        s += lo_f(kk.z)*lo_f(q2r) + hi_f(kk.z)*hi_f(q2r);
        s += lo_f(kk.w)*lo_f(q3r) + hi_f(kk.w)*hi_f(q3r);
      }
      float p = __expf(s);
      st[sq*66 + j] = p;
      lpart += p;
    }
    lpart += __shfl_xor(lpart,1);
    lpart += __shfl_xor(lpart,2);
    lpart += __shfl_xor(lpart,4);
    if (jp == 0) lsum[sq] += lpart;
    __syncthreads();
    #pragma unroll 4
    for (int j = 0; j < 64; ++j){
      float p0 = st[(2*qp)*66 + j];
      float p1 = st[(2*qp+1)*66 + j];
      const unsigned* vr = (const unsigned*)&vt[j*104 + dp*6];
      #pragma unroll
      for (int m = 0; m < 3; ++m){
        unsigned vv = vr[m];
        float v0 = lo_f(vv), v1 = hi_f(vv);
        Oacc[0][2*m]   += p0*v0; Oacc[0][2*m+1] += p0*v1;
        Oacc[1][2*m]   += p1*v0; Oacc[1][2*m+1] += p1*v1;
      }
    }
  }
  __syncthreads();
  float l0 = 1.f / lsum[2*qp], l1 = 1.f / lsum[2*qp+1];
  size_t ob = (size_t)(b*NN + q0)*DD + h*DHH + dp*6;
  #pragma unroll
  for (int m = 0; m < 6; ++m){
    ows[ob + (size_t)(2*qp)*DD + m]   = f_bits(Oacc[0][m]*l0);
    ows[ob + (size_t)(2*qp+1)*DD + m] = f_bits(Oacc[1][m]*l1);
  }
}

// ================= output projection via MFMA (16-row tiles, 144 blocks) =================
__global__ __launch_bounds__(256, 4) void k_out(
    const unsigned short* __restrict__ ows, const float* __restrict__ enh,
    const short* __restrict__ woT, const float* __restrict__ bo, float* __restrict__ out)
{
  const int tid = threadIdx.x, blk = blockIdx.x;   // 144 = 48 rt * 3 ct
  const int rt = blk / 3, ct = blk % 3;
  const int wave = tid >> 6, lane = tid & 63, quad = lane >> 4, l16 = lane & 15;
  const int row0 = rt*16;
  const int col0 = ct*256 + wave*64;
  f32x4 acc[4];
  #pragma unroll
  for (int cb=0;cb<4;++cb) acc[cb] = (f32x4){0.f,0.f,0.f,0.f};
  for (int ks = 0; ks < 24; ++ks){
    bf16x8 af = *(const bf16x8*)&((const short*)ows)[(size_t)(row0 + l16)*DD + ks*32 + quad*8];
    #pragma unroll
    for (int cb=0;cb<4;++cb){
      bf16x8 bw = *(const bf16x8*)&woT[(size_t)(col0 + cb*16 + l16)*DD + ks*32 + quad*8];
      acc[cb] = __builtin_amdgcn_mfma_f32_16x16x32_bf16(af, bw, acc[cb], 0,0,0);
    }
  }
  #pragma unroll
  for (int cb=0;cb<4;++cb){
    int col = col0 + cb*16 + l16;
    float bb = bo[col];
    #pragma unroll
    for (int r=0;r<4;++r){
      size_t idx = (size_t)(row0 + quad*4 + r)*DD + col;
      out[idx] = enh[idx] + 0.5f*(acc[cb][r] + bb);
    }
  }
}

extern "C" void kernel_launch(void* const* d_in, const int* in_sizes, int n_in,
                              void* d_out, int out_size, void* d_ws, size_t ws_size,
                              hipStream_t stream) {
  const float* coord = (const float*)d_in[0];
  const float* feat  = (const float*)d_in[1];
  const int*   lab   = (const int*)d_in[2];
  const float* ge_w1 = (const float*)d_in[3];
  const float* ge_b1 = (const float*)d_in[4];
  const float* ge_g1 = (const float*)d_in[5];
  const float* ge_be1= (const float*)d_in[6];
  const float* ge_w2 = (const float*)d_in[7];
  const float* ge_b2 = (const float*)d_in[8];
  const float* ge_g2 = (const float*)d_in[9];
  const float* ge_be2= (const float*)d_in[10];
  const float* ag_w1 = (const float*)d_in[11];
  const float* ag_b1 = (const float*)d_in[12];
  const float* ag_g1 = (const float*)d_in[13];
  const float* ag_be1= (const float*)d_in[14];
  const float* ag_w2 = (const float*)d_in[15];
  const float* ag_b2 = (const float*)d_in[16];
  const float* ag_g2 = (const float*)d_in[17];
  const float* ag_be2= (const float*)d_in[18];
  const float* wq = (const float*)d_in[19];
  const float* bq = (const float*)d_in[20];
  const float* wk = (const float*)d_in[21];
  const float* bk = (const float*)d_in[22];
  const float* wv = (const float*)d_in[23];
  const float* bv = (const float*)d_in[24];
  const float* wo = (const float*)d_in[25];
  const float* bo = (const float*)d_in[26];

  char* w = (char*)d_ws;
  unsigned short* geo_bf = (unsigned short*)(w);              // 1,179,648  [ow overlay]
  float*          enh_f  = (float*)(w + 1179648);             // 2,359,296
  unsigned short* enh_bf = (unsigned short*)(w + 3538944);    // 1,179,648
  unsigned short* qw_bf  = (unsigned short*)(w + 4718592);    // 1,179,648
  unsigned short* kw_bf  = (unsigned short*)(w + 5898240);    // 1,179,648
  unsigned short* vw_bf  = (unsigned short*)(w + 7077888);    // 1,179,648
  // gv OVERLAYS qw/kw/vw + hole: alive only between k_geo and k_geofin,
  // both strictly before k_qkv writes qw/kw/vw.  768*6*258*4 = 4,755,456 B
  // spans [4718592, 9474048) < cntw @ 9842688.
  float*          gv     = (float*)(w + 4718592);
  // gmean/xmean: alive only from k_mean to k_mlp (after gv is dead);
  // overlay the dead gv region tail [8257536, 8847360).
  float*          gmean  = (float*)(w + 8257536);             //   393,216
  unsigned short* xmean  = (unsigned short*)(w + 8650752);    //   196,608
  float*          cntw   = (float*)(w + 9842688);             //       512
  float*          comb   = (float*)(w + 9843200);             //   393,216
  short*          w2T    = (short*)(w + 10236416);            //   393,216
  short*          w2r    = (short*)(w + 10629632);            //   393,216
  short*          w1t    = (short*)(w + 11022848);            //    16,384
  short*          Gm     = (short*)(w + 11039232);            //   147,456 (fragment layout)
  float*          g1s    = (float*)(w + 11186688);            //       512
  float*          gscal  = (float*)(w + 11187200);            //       256
  short*          wqT    = (short*)(w + 11187456);            // 1,179,648
  short*          wkT    = (short*)(w + 12367104);            // 1,179,648
  short*          wvT    = (short*)(w + 13546752);            // 1,179,648
  short*          woT    = (short*)(w + 14726400);            // 1,179,648
  short*          agw1T  = (short*)(w + 15906048);            //   393,216
  short*          agw2T  = (short*)(w + 16299264);            //   393,216
  float*          pws    = (float*)(w + 16692480);            // 4,767,744 (optional)
  unsigned short* ow_bf  = geo_bf;
  const bool split_attn = (ws_size >= 21460224);

  hipLaunchKernelGGL(k_prep,    dim3(1520),  dim3(256), 0, stream,
                     ge_w2, ge_w1, wq, wk, wv, wo, ag_w1, ag_w2,
                     w2T, w2r, wqT, wkT, wvT, woT, w1t, agw1T, agw2T);
  hipLaunchKernelGGL(k_gprep,   dim3(66),    dim3(256), 0, stream,
                     w2r, ge_b2, w1t, ge_b1, Gm, gscal, g1s);
  hipLaunchKernelGGL(k_geo,     dim3(4608),  dim3(256), 0, stream,
                     coord, w1t, ge_b1, ge_g1, ge_be1, Gm, gscal, g1s, gv);
  hipLaunchKernelGGL(k_geofin,  dim3(192),   dim3(256), 0, stream,
                     gv, w2r, ge_b2, ge_g2, ge_be2, geo_bf);
  hipLaunchKernelGGL(k_mean,    dim3(128),   dim3(256), 0, stream,
                     lab, feat, geo_bf, cntw, xmean, gmean);
  hipLaunchKernelGGL(k_mlp,     dim3(8),     dim3(256), 0, stream,
                     xmean, gmean, agw1T, ag_b1, ag_g1, ag_be1,
                     agw2T, ag_b2, ag_g2, ag_be2, comb);
  hipLaunchKernelGGL(k_enhance, dim3(2304),  dim3(256), 0, stream,
                     feat, lab, cntw, comb, enh_f, enh_bf);
  hipLaunchKernelGGL(k_qkv,     dim3(432),   dim3(256), 0, stream,
                     enh_bf, geo_bf, wqT, wkT, wvT, bq, bk, bv, qw_bf, kw_bf, vw_bf);
  if (split_attn){
    hipLaunchKernelGGL(k_attn_split, dim3(384), dim3(256), 0, stream,
                       qw_bf, kw_bf, vw_bf, pws);
    hipLaunchKernelGGL(k_attnfin,    dim3(192), dim3(256), 0, stream,
                       pws, ow_bf);
  } else {
    hipLaunchKernelGGL(k_attn_full,  dim3(192), dim3(256), 0, stream,
                       qw_bf, kw_bf, vw_bf, ow_bf);
  }
  hipLaunchKernelGGL(k_out,     dim3(144),   dim3(256), 0, stream,
                     ow_bf, enh_f, woT, bo, (float*)d_out);
}